// Round 1
// baseline (1069.997 us; speedup 1.0000x reference)
//
#include <hip/hip_runtime.h>
#include <cstdint>
#include <cstddef>

#define NGRAPHS 512

static inline size_t align_up(size_t x, size_t a){ return (x + a - 1) & ~(a - 1); }

// ---------------- degree histograms ----------------
__global__ void k_degrees(const int* __restrict__ src, const int* __restrict__ dst,
                          int* __restrict__ dout_i, int* __restrict__ din_i, int n_edges){
  int e = blockIdx.x * blockDim.x + threadIdx.x;
  if (e < n_edges){
    atomicAdd(&dout_i[src[e]], 1);
    atomicAdd(&din_i[dst[e]], 1);
  }
}

// ---------------- degree^-1/2 scales ----------------
__global__ void k_scales(const int* __restrict__ dout_i, const int* __restrict__ din_i,
                         float* __restrict__ dout_s, float* __restrict__ din_s, int n){
  int i = blockIdx.x * blockDim.x + threadIdx.x;
  if (i < n){
    dout_s[i] = 1.0f / sqrtf((float)max(dout_i[i], 1));
    din_s[i]  = 1.0f / sqrtf((float)max(din_i[i], 1));
  }
}

// ---------------- single-block exclusive scan of deg_in -> CSR offsets + cursor ----------------
__global__ __launch_bounds__(1024) void k_scan(const int* __restrict__ deg, int* __restrict__ offs,
                                               int* __restrict__ cursor, int n){
  __shared__ int smem[1024];
  int tid = threadIdx.x;
  int per = (n + 1023) / 1024;
  int beg = tid * per;
  int endd = min(beg + per, n);
  int s = 0;
  for (int i = beg; i < endd; ++i) s += deg[i];
  smem[tid] = s;
  __syncthreads();
  for (int off = 1; off < 1024; off <<= 1){
    int t = (tid >= off) ? smem[tid - off] : 0;
    __syncthreads();
    smem[tid] += t;
    __syncthreads();
  }
  int run = smem[tid] - s;   // exclusive prefix of this thread's chunk
  for (int i = beg; i < endd; ++i){ offs[i] = run; cursor[i] = run; run += deg[i]; }
  if (tid == 1023) offs[n] = run;   // total (= n_edges)
}

// ---------------- counting-sort fill: edges grouped by dst ----------------
__global__ void k_fill(const int* __restrict__ src, const int* __restrict__ dst,
                       int* __restrict__ cursor, int* __restrict__ csr_src, int n_edges){
  int e = blockIdx.x * blockDim.x + threadIdx.x;
  if (e < n_edges){
    int p = atomicAdd(&cursor[dst[e]], 1);
    csr_src[p] = src[e];
  }
}

// ---------------- SpMM layer1: agg[n,128] = sum_{s in in(n)} x[s,:]*dout_s[s] ----------------
__global__ __launch_bounds__(256) void k_spmm1(const float* __restrict__ x,
    const int* __restrict__ offs, const int* __restrict__ csr_src,
    const float* __restrict__ dout_s, float* __restrict__ agg, int n_nodes){
  int node = (blockIdx.x * blockDim.x + threadIdx.x) >> 6;
  int lane = threadIdx.x & 63;
  if (node >= n_nodes) return;
  int j0 = offs[node], j1 = offs[node + 1];
  float2 acc = make_float2(0.f, 0.f);
  const float2* xp = (const float2*)x;
  for (int j = j0; j < j1; ++j){
    int s = csr_src[j];
    float sc = dout_s[s];
    float2 v = xp[(size_t)s * 64 + lane];
    acc.x = fmaf(v.x, sc, acc.x);
    acc.y = fmaf(v.y, sc, acc.y);
  }
  ((float2*)agg)[(size_t)node * 64 + lane] = acc;
}

// ---------------- SpMM layer2 + epilogue: h2 = relu(Agg(t2)*din + b2) ----------------
__global__ __launch_bounds__(256) void k_spmm2(const float* __restrict__ t2,
    const int* __restrict__ offs, const int* __restrict__ csr_src,
    const float* __restrict__ din_s, const float* __restrict__ b2,
    float* __restrict__ h2, int n_nodes){
  int node = (blockIdx.x * blockDim.x + threadIdx.x) >> 6;
  int lane = threadIdx.x & 63;
  if (node >= n_nodes) return;
  int j0 = offs[node], j1 = offs[node + 1];
  float acc = 0.f;
  for (int j = j0; j < j1; ++j) acc += t2[(size_t)csr_src[j] * 64 + lane];
  h2[(size_t)node * 64 + lane] = fmaxf(fmaf(acc, din_s[node], b2[lane]), 0.f);
}

// ---------------- tiled fp32 GEMM, optional A-row-scale on load, optional relu(x*rowscale+bias) epilogue ----
template<int BM, int BN, int BK, int TM, int TN, bool SCALE_A, bool EPI>
__global__ __launch_bounds__(256) void gemm_fused(
    const float* __restrict__ A, const float* __restrict__ B, float* __restrict__ C,
    int M, int N, int K,
    const float* __restrict__ rowScaleA,
    const float* __restrict__ rowScaleC, const float* __restrict__ bias){
  constexpr int THREADS = (BM / TM) * (BN / TN);
  static_assert(THREADS == 256, "block must be 256");
  __shared__ float As[BK][BM + 4];
  __shared__ float Bs[BK][BN + 4];
  int tid = threadIdx.x;
  int bm0 = blockIdx.x * BM;
  int bn0 = blockIdx.y * BN;
  int tx = tid % (BN / TN);
  int ty = tid / (BN / TN);
  float acc[TM][TN] = {};
  constexpr int A_LOADS = BM * BK / (4 * THREADS);
  constexpr int B_LOADS = BN * BK / (4 * THREADS);
  for (int k0 = 0; k0 < K; k0 += BK){
#pragma unroll
    for (int l = 0; l < A_LOADS; ++l){
      int i = tid + l * THREADS;
      int row = i / (BK / 4);
      int k4  = i % (BK / 4);
      float4 v = make_float4(0.f, 0.f, 0.f, 0.f);
      int gr = bm0 + row;
      if (gr < M){
        v = *(const float4*)(A + (size_t)gr * K + k0 + k4 * 4);
        if constexpr (SCALE_A){
          float s = rowScaleA[gr];
          v.x *= s; v.y *= s; v.z *= s; v.w *= s;
        }
      }
      As[k4 * 4 + 0][row] = v.x;
      As[k4 * 4 + 1][row] = v.y;
      As[k4 * 4 + 2][row] = v.z;
      As[k4 * 4 + 3][row] = v.w;
    }
#pragma unroll
    for (int l = 0; l < B_LOADS; ++l){
      int i = tid + l * THREADS;
      int k  = i / (BN / 4);
      int n4 = i % (BN / 4);
      float4 v = *(const float4*)(B + (size_t)(k0 + k) * N + bn0 + n4 * 4);
      *(float4*)&Bs[k][n4 * 4] = v;
    }
    __syncthreads();
#pragma unroll
    for (int k = 0; k < BK; ++k){
      float a[TM], b[TN];
#pragma unroll
      for (int i = 0; i < TM; ++i) a[i] = As[k][ty * TM + i];
#pragma unroll
      for (int j = 0; j < TN; ++j) b[j] = Bs[k][tx * TN + j];
#pragma unroll
      for (int i = 0; i < TM; ++i)
#pragma unroll
        for (int j = 0; j < TN; ++j)
          acc[i][j] = fmaf(a[i], b[j], acc[i][j]);
    }
    __syncthreads();
  }
#pragma unroll
  for (int i = 0; i < TM; ++i){
    int gr = bm0 + ty * TM + i;
    if (gr >= M) break;
    float rs = 1.0f;
    if constexpr (EPI) rs = rowScaleC[gr];
#pragma unroll
    for (int j = 0; j < TN; ++j){
      int gc = bn0 + tx * TN + j;
      float cv = acc[i][j];
      if constexpr (EPI) cv = fmaxf(fmaf(cv, rs, bias[gc]), 0.f);
      C[(size_t)gr * N + gc] = cv;
    }
  }
}

// ---------------- per-graph mean-pool (sorted graph ids): segmented accumulate + atomic flush ----
__global__ __launch_bounds__(256) void k_pool(const float* __restrict__ h2, const int* __restrict__ gids,
                                              float* __restrict__ sums, int* __restrict__ cnts, int n_nodes){
  int wave = (blockIdx.x * blockDim.x + threadIdx.x) >> 6;
  int lane = threadIdx.x & 63;
  int base = wave * 64;
  if (base >= n_nodes) return;
  int endn = min(base + 64, n_nodes);
  float acc = 0.f;
  int cur = -1, len = 0;
  for (int i = base; i < endn; ++i){
    int g = gids[i];                         // wave-uniform
    float v = h2[(size_t)i * 64 + lane];
    if (g != cur){
      if (cur >= 0){
        atomicAdd(&sums[(size_t)cur * 64 + lane], acc);
        if (lane == 0) atomicAdd(&cnts[cur], len);
      }
      cur = g; acc = 0.f; len = 0;
    }
    acc += v; len++;
  }
  atomicAdd(&sums[(size_t)cur * 64 + lane], acc);
  if (lane == 0) atomicAdd(&cnts[cur], len);
}

// ---------------- classifier: hg = sums/cnt; 4 linear layers; out 512x2 ----------------
__global__ __launch_bounds__(256) void k_classifier(const float* __restrict__ sums, const int* __restrict__ cnts,
    const float* __restrict__ Wc1, const float* __restrict__ bc1,
    const float* __restrict__ Wc2, const float* __restrict__ bc2,
    const float* __restrict__ Wc3, const float* __restrict__ bc3,
    const float* __restrict__ Wc4, const float* __restrict__ bc4,
    float* __restrict__ out){
  __shared__ float w1[64 * 18], w2[18 * 12], w3[12 * 6], w4[6 * 2];
  __shared__ float B1[18], B2[12], B3[6], B4[2];
  int tid = threadIdx.x;
  for (int i = tid; i < 64 * 18; i += 256) w1[i] = Wc1[i];
  for (int i = tid; i < 18 * 12; i += 256) w2[i] = Wc2[i];
  for (int i = tid; i < 12 * 6;  i += 256) w3[i] = Wc3[i];
  for (int i = tid; i < 6 * 2;   i += 256) w4[i] = Wc4[i];
  if (tid < 18) B1[tid] = bc1[tid];
  if (tid < 12) B2[tid] = bc2[tid];
  if (tid < 6)  B3[tid] = bc3[tid];
  if (tid < 2)  B4[tid] = bc4[tid];
  __syncthreads();
  int g = blockIdx.x * 256 + tid;
  float cnt = fmaxf((float)cnts[g], 1.0f);
  float h[64];
#pragma unroll
  for (int f = 0; f < 64; ++f) h[f] = sums[(size_t)g * 64 + f] / cnt;
  float t1[18];
#pragma unroll
  for (int j = 0; j < 18; ++j){
    float s = B1[j];
    for (int f = 0; f < 64; ++f) s = fmaf(h[f], w1[f * 18 + j], s);
    t1[j] = s;
  }
  float t2[12];
#pragma unroll
  for (int j = 0; j < 12; ++j){
    float s = B2[j];
    for (int f = 0; f < 18; ++f) s = fmaf(t1[f], w2[f * 12 + j], s);
    t2[j] = s;
  }
  float t3[6];
#pragma unroll
  for (int j = 0; j < 6; ++j){
    float s = B3[j];
    for (int f = 0; f < 12; ++f) s = fmaf(t2[f], w3[f * 6 + j], s);
    t3[j] = s;
  }
#pragma unroll
  for (int j = 0; j < 2; ++j){
    float s = B4[j];
    for (int f = 0; f < 6; ++f) s = fmaf(t3[f], w4[f * 2 + j], s);
    out[(size_t)g * 2 + j] = s;
  }
}

extern "C" void kernel_launch(void* const* d_in, const int* in_sizes, int n_in,
                              void* d_out, int out_size, void* d_ws, size_t ws_size,
                              hipStream_t stream){
  const float* x   = (const float*)d_in[0];
  const int*   src = (const int*)d_in[1];
  const int*   dst = (const int*)d_in[2];
  const int*   gid = (const int*)d_in[3];
  const float* W1  = (const float*)d_in[4];
  const float* b1  = (const float*)d_in[5];
  const float* W2  = (const float*)d_in[6];
  const float* b2  = (const float*)d_in[7];
  const float* Wc1 = (const float*)d_in[8];
  const float* bc1 = (const float*)d_in[9];
  const float* Wc2 = (const float*)d_in[10];
  const float* bc2 = (const float*)d_in[11];
  const float* Wc3 = (const float*)d_in[12];
  const float* bc3 = (const float*)d_in[13];
  const float* Wc4 = (const float*)d_in[14];
  const float* bc4 = (const float*)d_in[15];
  float* out = (float*)d_out;

  const int n_nodes = in_sizes[3];
  const int n_edges = in_sizes[1];
  const int F1 = 256, F2 = 64;

  // workspace layout
  char* w = (char*)d_ws;
  size_t o = 0;
  auto alloc = [&](size_t bytes) -> char* {
    char* p = w + o;
    o = align_up(o + bytes, 256);
    return p;
  };
  int*   deg_out_i = (int*)  alloc((size_t)n_nodes * 4);
  int*   deg_in_i  = (int*)  alloc((size_t)n_nodes * 4);
  float* sums      = (float*)alloc((size_t)NGRAPHS * F2 * 4);
  int*   cnts      = (int*)  alloc((size_t)NGRAPHS * 4);
  size_t zero_bytes = o;                       // everything above must start at 0
  float* dout_s    = (float*)alloc((size_t)n_nodes * 4);
  float* din_s     = (float*)alloc((size_t)n_nodes * 4);
  int*   offs      = (int*)  alloc((size_t)(n_nodes + 1) * 4);
  int*   cursor    = (int*)  alloc((size_t)n_nodes * 4);
  int*   csr_src   = (int*)  alloc((size_t)n_edges * 4);
  float* agg       = (float*)alloc((size_t)n_nodes * 128 * 4);   // layer1 aggregation (K=128)
  float* h1        = (float*)alloc((size_t)n_nodes * F1 * 4);    // layer1 output (256)
  float* t2buf = agg;   // reuse: GEMM2 output (64 wide) after agg is consumed
  float* h2    = h1;    // reuse: layer2 output after h1 is consumed

  hipMemsetAsync(d_ws, 0, zero_bytes, stream);

  k_degrees<<<(n_edges + 255) / 256, 256, 0, stream>>>(src, dst, deg_out_i, deg_in_i, n_edges);
  k_scales <<<(n_nodes + 255) / 256, 256, 0, stream>>>(deg_out_i, deg_in_i, dout_s, din_s, n_nodes);
  k_scan   <<<1, 1024, 0, stream>>>(deg_in_i, offs, cursor, n_nodes);
  k_fill   <<<(n_edges + 255) / 256, 256, 0, stream>>>(src, dst, cursor, csr_src, n_edges);

  // layer 1: agg = Agg(x * dout); h1 = relu((agg @ W1) * din + b1)
  {
    long long threads = (long long)n_nodes * 64;
    k_spmm1<<<(int)((threads + 255) / 256), 256, 0, stream>>>(x, offs, csr_src, dout_s, agg, n_nodes);
    dim3 g1((n_nodes + 127) / 128, F1 / 128);
    gemm_fused<128, 128, 16, 8, 8, false, true><<<g1, 256, 0, stream>>>(
        agg, W1, h1, n_nodes, F1, 128, nullptr, din_s, b1);
  }
  // layer 2: t2 = (h1 * dout) @ W2; h2 = relu(Agg(t2) * din + b2)
  {
    dim3 g2((n_nodes + 127) / 128, 1);
    gemm_fused<128, 64, 16, 8, 4, true, false><<<g2, 256, 0, stream>>>(
        h1, W2, t2buf, n_nodes, F2, F1, dout_s, nullptr, nullptr);
    long long threads = (long long)n_nodes * 64;
    k_spmm2<<<(int)((threads + 255) / 256), 256, 0, stream>>>(t2buf, offs, csr_src, din_s, b2, h2, n_nodes);
  }
  // pooling + classifier
  {
    int pool_waves = (n_nodes + 63) / 64;
    long long threads = (long long)pool_waves * 64;
    k_pool<<<(int)((threads + 255) / 256), 256, 0, stream>>>(h2, gid, sums, cnts, n_nodes);
    k_classifier<<<NGRAPHS / 256, 256, 0, stream>>>(sums, cnts, Wc1, bc1, Wc2, bc2, Wc3, bc3, Wc4, bc4, out);
  }
}

// Round 2
// 867.715 us; speedup vs baseline: 1.2331x; 1.2331x over previous
//
#include <hip/hip_runtime.h>
#include <cstdint>
#include <cstddef>

#define NGRAPHS 512

static inline size_t align_up(size_t x, size_t a){ return (x + a - 1) & ~(a - 1); }

// ---------------- degree histograms ----------------
__global__ void k_degrees(const int* __restrict__ src, const int* __restrict__ dst,
                          int* __restrict__ dout_i, int* __restrict__ din_i, int n_edges){
  int e = blockIdx.x * blockDim.x + threadIdx.x;
  if (e < n_edges){
    atomicAdd(&dout_i[src[e]], 1);
    atomicAdd(&din_i[dst[e]], 1);
  }
}

// ---------------- degree^-1/2 scales ----------------
__global__ void k_scales(const int* __restrict__ dout_i, const int* __restrict__ din_i,
                         float* __restrict__ dout_s, float* __restrict__ din_s, int n){
  int i = blockIdx.x * blockDim.x + threadIdx.x;
  if (i < n){
    dout_s[i] = 1.0f / sqrtf((float)max(dout_i[i], 1));
    din_s[i]  = 1.0f / sqrtf((float)max(din_i[i], 1));
  }
}

// ---------------- 3-phase device-wide exclusive scan (coalesced) ----------------
// phase A: per-block (4096 elems) sums
__global__ __launch_bounds__(256) void k_scan_partial(const int* __restrict__ deg,
                                                      int* __restrict__ bs, int n){
  __shared__ int sm[256];
  int base = blockIdx.x * 4096;
  int s = 0;
#pragma unroll
  for (int it = 0; it < 16; ++it){
    int i = base + it * 256 + threadIdx.x;
    if (i < n) s += deg[i];
  }
  sm[threadIdx.x] = s;
  __syncthreads();
  for (int off = 128; off > 0; off >>= 1){
    if (threadIdx.x < off) sm[threadIdx.x] += sm[threadIdx.x + off];
    __syncthreads();
  }
  if (threadIdx.x == 0) bs[blockIdx.x] = sm[0];
}

// phase B: scan the block sums (nb <= 64), write offs[n] = total
__global__ __launch_bounds__(64) void k_scan_blocksums(int* __restrict__ bs, int nb,
                                                       int* __restrict__ offs, int n){
  __shared__ int sm[64];
  int tid = threadIdx.x;
  int v = (tid < nb) ? bs[tid] : 0;
  sm[tid] = v;
  __syncthreads();
  for (int off = 1; off < 64; off <<= 1){
    int t = (tid >= off) ? sm[tid - off] : 0;
    __syncthreads();
    sm[tid] += t;
    __syncthreads();
  }
  if (tid < nb) bs[tid] = sm[tid] - v;   // exclusive
  if (tid == 63) offs[n] = sm[63];       // grand total (= n_edges)
}

// phase C: re-scan each 4096-chunk with its offset; coalesced writes of offs+cursor
__global__ __launch_bounds__(256) void k_scan_write(const int* __restrict__ deg,
    const int* __restrict__ bs, int* __restrict__ offs, int* __restrict__ cursor, int n){
  __shared__ int vals[4096];
  __shared__ int tsum[256];
  int base = blockIdx.x * 4096;
#pragma unroll
  for (int it = 0; it < 16; ++it){
    int i = base + it * 256 + threadIdx.x;
    vals[it * 256 + threadIdx.x] = (i < n) ? deg[i] : 0;
  }
  __syncthreads();
  int t0 = threadIdx.x * 16;
  int loc[16];
  int s = 0;
#pragma unroll
  for (int k = 0; k < 16; ++k){ loc[k] = s; s += vals[t0 + k]; }
  tsum[threadIdx.x] = s;
  __syncthreads();
  for (int off = 1; off < 256; off <<= 1){
    int t = (threadIdx.x >= off) ? tsum[threadIdx.x - off] : 0;
    __syncthreads();
    tsum[threadIdx.x] += t;
    __syncthreads();
  }
  int pre = tsum[threadIdx.x] - s + bs[blockIdx.x];
  __syncthreads();
#pragma unroll
  for (int k = 0; k < 16; ++k) vals[t0 + k] = pre + loc[k];
  __syncthreads();
#pragma unroll
  for (int it = 0; it < 16; ++it){
    int i = base + it * 256 + threadIdx.x;
    if (i < n){
      int v = vals[it * 256 + threadIdx.x];
      offs[i] = v; cursor[i] = v;
    }
  }
}

// ---------------- counting-sort fill: edges grouped by dst ----------------
__global__ void k_fill(const int* __restrict__ src, const int* __restrict__ dst,
                       int* __restrict__ cursor, int* __restrict__ csr_src, int n_edges){
  int e = blockIdx.x * blockDim.x + threadIdx.x;
  if (e < n_edges){
    int p = atomicAdd(&cursor[dst[e]], 1);
    csr_src[p] = src[e];
  }
}

// ---------------- SpMM layer1: agg[n,128] = sum_{s in in(n)} x[s,:]*dout_s[s] ----------------
__global__ __launch_bounds__(256) void k_spmm1(const float* __restrict__ x,
    const int* __restrict__ offs, const int* __restrict__ csr_src,
    const float* __restrict__ dout_s, float* __restrict__ agg, int n_nodes){
  int node = (blockIdx.x * blockDim.x + threadIdx.x) >> 6;
  int lane = threadIdx.x & 63;
  if (node >= n_nodes) return;
  int j0 = offs[node], j1 = offs[node + 1];
  float2 acc = make_float2(0.f, 0.f);
  const float2* xp = (const float2*)x;
  for (int j = j0; j < j1; ++j){
    int s = csr_src[j];
    float sc = dout_s[s];
    float2 v = xp[(size_t)s * 64 + lane];
    acc.x = fmaf(v.x, sc, acc.x);
    acc.y = fmaf(v.y, sc, acc.y);
  }
  ((float2*)agg)[(size_t)node * 64 + lane] = acc;
}

// ---------------- SpMM layer2 + epilogue: h2 = relu(Agg(t2)*din + b2) ----------------
__global__ __launch_bounds__(256) void k_spmm2(const float* __restrict__ t2,
    const int* __restrict__ offs, const int* __restrict__ csr_src,
    const float* __restrict__ din_s, const float* __restrict__ b2,
    float* __restrict__ h2, int n_nodes){
  int node = (blockIdx.x * blockDim.x + threadIdx.x) >> 6;
  int lane = threadIdx.x & 63;
  if (node >= n_nodes) return;
  int j0 = offs[node], j1 = offs[node + 1];
  float acc = 0.f;
  for (int j = j0; j < j1; ++j) acc += t2[(size_t)csr_src[j] * 64 + lane];
  h2[(size_t)node * 64 + lane] = fmaxf(fmaf(acc, din_s[node], b2[lane]), 0.f);
}

// ---------------- tiled fp32 GEMM, optional A-row-scale on load, optional relu(x*rowscale+bias) epilogue ----
template<int BM, int BN, int BK, int TM, int TN, bool SCALE_A, bool EPI>
__global__ __launch_bounds__(256) void gemm_fused(
    const float* __restrict__ A, const float* __restrict__ B, float* __restrict__ C,
    int M, int N, int K,
    const float* __restrict__ rowScaleA,
    const float* __restrict__ rowScaleC, const float* __restrict__ bias){
  constexpr int THREADS = (BM / TM) * (BN / TN);
  static_assert(THREADS == 256, "block must be 256");
  __shared__ float As[BK][BM + 4];
  __shared__ float Bs[BK][BN + 4];
  int tid = threadIdx.x;
  int bm0 = blockIdx.x * BM;
  int bn0 = blockIdx.y * BN;
  int tx = tid % (BN / TN);
  int ty = tid / (BN / TN);
  float acc[TM][TN] = {};
  constexpr int A_LOADS = BM * BK / (4 * THREADS);
  constexpr int B_LOADS = BN * BK / (4 * THREADS);
  for (int k0 = 0; k0 < K; k0 += BK){
#pragma unroll
    for (int l = 0; l < A_LOADS; ++l){
      int i = tid + l * THREADS;
      int row = i / (BK / 4);
      int k4  = i % (BK / 4);
      float4 v = make_float4(0.f, 0.f, 0.f, 0.f);
      int gr = bm0 + row;
      if (gr < M){
        v = *(const float4*)(A + (size_t)gr * K + k0 + k4 * 4);
        if constexpr (SCALE_A){
          float s = rowScaleA[gr];
          v.x *= s; v.y *= s; v.z *= s; v.w *= s;
        }
      }
      As[k4 * 4 + 0][row] = v.x;
      As[k4 * 4 + 1][row] = v.y;
      As[k4 * 4 + 2][row] = v.z;
      As[k4 * 4 + 3][row] = v.w;
    }
#pragma unroll
    for (int l = 0; l < B_LOADS; ++l){
      int i = tid + l * THREADS;
      int k  = i / (BN / 4);
      int n4 = i % (BN / 4);
      float4 v = *(const float4*)(B + (size_t)(k0 + k) * N + bn0 + n4 * 4);
      *(float4*)&Bs[k][n4 * 4] = v;
    }
    __syncthreads();
#pragma unroll
    for (int k = 0; k < BK; ++k){
      float a[TM], b[TN];
#pragma unroll
      for (int i = 0; i < TM; ++i) a[i] = As[k][ty * TM + i];
#pragma unroll
      for (int j = 0; j < TN; ++j) b[j] = Bs[k][tx * TN + j];
#pragma unroll
      for (int i = 0; i < TM; ++i)
#pragma unroll
        for (int j = 0; j < TN; ++j)
          acc[i][j] = fmaf(a[i], b[j], acc[i][j]);
    }
    __syncthreads();
  }
#pragma unroll
  for (int i = 0; i < TM; ++i){
    int gr = bm0 + ty * TM + i;
    if (gr >= M) break;
    float rs = 1.0f;
    if constexpr (EPI) rs = rowScaleC[gr];
#pragma unroll
    for (int j = 0; j < TN; ++j){
      int gc = bn0 + tx * TN + j;
      float cv = acc[i][j];
      if constexpr (EPI) cv = fmaxf(fmaf(cv, rs, bias[gc]), 0.f);
      C[(size_t)gr * N + gc] = cv;
    }
  }
}

// ---------------- per-graph mean-pool (sorted graph ids): segmented accumulate + atomic flush ----
__global__ __launch_bounds__(256) void k_pool(const float* __restrict__ h2, const int* __restrict__ gids,
                                              float* __restrict__ sums, int* __restrict__ cnts, int n_nodes){
  int wave = (blockIdx.x * blockDim.x + threadIdx.x) >> 6;
  int lane = threadIdx.x & 63;
  int base = wave * 64;
  if (base >= n_nodes) return;
  int endn = min(base + 64, n_nodes);
  float acc = 0.f;
  int cur = -1, len = 0;
  for (int i = base; i < endn; ++i){
    int g = gids[i];                         // wave-uniform
    float v = h2[(size_t)i * 64 + lane];
    if (g != cur){
      if (cur >= 0){
        atomicAdd(&sums[(size_t)cur * 64 + lane], acc);
        if (lane == 0) atomicAdd(&cnts[cur], len);
      }
      cur = g; acc = 0.f; len = 0;
    }
    acc += v; len++;
  }
  atomicAdd(&sums[(size_t)cur * 64 + lane], acc);
  if (lane == 0) atomicAdd(&cnts[cur], len);
}

// ---------------- classifier: hg = sums/cnt; 4 linear layers; out 512x2 ----------------
__global__ __launch_bounds__(256) void k_classifier(const float* __restrict__ sums, const int* __restrict__ cnts,
    const float* __restrict__ Wc1, const float* __restrict__ bc1,
    const float* __restrict__ Wc2, const float* __restrict__ bc2,
    const float* __restrict__ Wc3, const float* __restrict__ bc3,
    const float* __restrict__ Wc4, const float* __restrict__ bc4,
    float* __restrict__ out){
  __shared__ float w1[64 * 18], w2[18 * 12], w3[12 * 6], w4[6 * 2];
  __shared__ float B1[18], B2[12], B3[6], B4[2];
  int tid = threadIdx.x;
  for (int i = tid; i < 64 * 18; i += 256) w1[i] = Wc1[i];
  for (int i = tid; i < 18 * 12; i += 256) w2[i] = Wc2[i];
  for (int i = tid; i < 12 * 6;  i += 256) w3[i] = Wc3[i];
  for (int i = tid; i < 6 * 2;   i += 256) w4[i] = Wc4[i];
  if (tid < 18) B1[tid] = bc1[tid];
  if (tid < 12) B2[tid] = bc2[tid];
  if (tid < 6)  B3[tid] = bc3[tid];
  if (tid < 2)  B4[tid] = bc4[tid];
  __syncthreads();
  int g = blockIdx.x * 256 + tid;
  float cnt = fmaxf((float)cnts[g], 1.0f);
  float h[64];
#pragma unroll
  for (int f = 0; f < 64; ++f) h[f] = sums[(size_t)g * 64 + f] / cnt;
  float t1[18];
#pragma unroll
  for (int j = 0; j < 18; ++j){
    float s = B1[j];
    for (int f = 0; f < 64; ++f) s = fmaf(h[f], w1[f * 18 + j], s);
    t1[j] = s;
  }
  float t2[12];
#pragma unroll
  for (int j = 0; j < 12; ++j){
    float s = B2[j];
    for (int f = 0; f < 18; ++f) s = fmaf(t1[f], w2[f * 12 + j], s);
    t2[j] = s;
  }
  float t3[6];
#pragma unroll
  for (int j = 0; j < 6; ++j){
    float s = B3[j];
    for (int f = 0; f < 12; ++f) s = fmaf(t2[f], w3[f * 6 + j], s);
    t3[j] = s;
  }
#pragma unroll
  for (int j = 0; j < 2; ++j){
    float s = B4[j];
    for (int f = 0; f < 6; ++f) s = fmaf(t3[f], w4[f * 2 + j], s);
    out[(size_t)g * 2 + j] = s;
  }
}

extern "C" void kernel_launch(void* const* d_in, const int* in_sizes, int n_in,
                              void* d_out, int out_size, void* d_ws, size_t ws_size,
                              hipStream_t stream){
  const float* x   = (const float*)d_in[0];
  const int*   src = (const int*)d_in[1];
  const int*   dst = (const int*)d_in[2];
  const int*   gid = (const int*)d_in[3];
  const float* W1  = (const float*)d_in[4];
  const float* b1  = (const float*)d_in[5];
  const float* W2  = (const float*)d_in[6];
  const float* b2  = (const float*)d_in[7];
  const float* Wc1 = (const float*)d_in[8];
  const float* bc1 = (const float*)d_in[9];
  const float* Wc2 = (const float*)d_in[10];
  const float* bc2 = (const float*)d_in[11];
  const float* Wc3 = (const float*)d_in[12];
  const float* bc3 = (const float*)d_in[13];
  const float* Wc4 = (const float*)d_in[14];
  const float* bc4 = (const float*)d_in[15];
  float* out = (float*)d_out;

  const int n_nodes = in_sizes[3];
  const int n_edges = in_sizes[1];
  const int F1 = 256, F2 = 64;

  // workspace layout
  char* w = (char*)d_ws;
  size_t o = 0;
  auto alloc = [&](size_t bytes) -> char* {
    char* p = w + o;
    o = align_up(o + bytes, 256);
    return p;
  };
  int*   deg_out_i = (int*)  alloc((size_t)n_nodes * 4);
  int*   deg_in_i  = (int*)  alloc((size_t)n_nodes * 4);
  float* sums      = (float*)alloc((size_t)NGRAPHS * F2 * 4);
  int*   cnts      = (int*)  alloc((size_t)NGRAPHS * 4);
  size_t zero_bytes = o;                       // everything above must start at 0
  float* dout_s    = (float*)alloc((size_t)n_nodes * 4);
  float* din_s     = (float*)alloc((size_t)n_nodes * 4);
  int*   offs      = (int*)  alloc((size_t)(n_nodes + 1) * 4);
  int*   cursor    = (int*)  alloc((size_t)n_nodes * 4);
  int*   block_sums= (int*)  alloc((size_t)64 * 4);
  int*   csr_src   = (int*)  alloc((size_t)n_edges * 4);
  float* agg       = (float*)alloc((size_t)n_nodes * 128 * 4);   // layer1 aggregation (K=128)
  float* h1        = (float*)alloc((size_t)n_nodes * F1 * 4);    // layer1 output (256)
  float* t2buf = agg;   // reuse: GEMM2 output (64 wide) after agg is consumed
  float* h2    = h1;    // reuse: layer2 output after h1 is consumed

  hipMemsetAsync(d_ws, 0, zero_bytes, stream);

  k_degrees<<<(n_edges + 255) / 256, 256, 0, stream>>>(src, dst, deg_out_i, deg_in_i, n_edges);
  k_scales <<<(n_nodes + 255) / 256, 256, 0, stream>>>(deg_out_i, deg_in_i, dout_s, din_s, n_nodes);

  // 3-phase device-wide exclusive scan of deg_in -> offs + cursor
  int nscan_blocks = (n_nodes + 4095) / 4096;   // 25 for n=100000 (<=64 supported)
  k_scan_partial  <<<nscan_blocks, 256, 0, stream>>>(deg_in_i, block_sums, n_nodes);
  k_scan_blocksums<<<1, 64, 0, stream>>>(block_sums, nscan_blocks, offs, n_nodes);
  k_scan_write    <<<nscan_blocks, 256, 0, stream>>>(deg_in_i, block_sums, offs, cursor, n_nodes);

  k_fill   <<<(n_edges + 255) / 256, 256, 0, stream>>>(src, dst, cursor, csr_src, n_edges);

  // layer 1: agg = Agg(x * dout); h1 = relu((agg @ W1) * din + b1)
  {
    long long threads = (long long)n_nodes * 64;
    k_spmm1<<<(int)((threads + 255) / 256), 256, 0, stream>>>(x, offs, csr_src, dout_s, agg, n_nodes);
    dim3 g1((n_nodes + 127) / 128, F1 / 128);
    gemm_fused<128, 128, 16, 8, 8, false, true><<<g1, 256, 0, stream>>>(
        agg, W1, h1, n_nodes, F1, 128, nullptr, din_s, b1);
  }
  // layer 2: t2 = (h1 * dout) @ W2; h2 = relu(Agg(t2) * din + b2)
  {
    dim3 g2((n_nodes + 127) / 128, 1);
    gemm_fused<128, 64, 16, 8, 4, true, false><<<g2, 256, 0, stream>>>(
        h1, W2, t2buf, n_nodes, F2, F1, dout_s, nullptr, nullptr);
    long long threads = (long long)n_nodes * 64;
    k_spmm2<<<(int)((threads + 255) / 256), 256, 0, stream>>>(t2buf, offs, csr_src, din_s, b2, h2, n_nodes);
  }
  // pooling + classifier
  {
    int pool_waves = (n_nodes + 63) / 64;
    long long threads = (long long)pool_waves * 64;
    k_pool<<<(int)((threads + 255) / 256), 256, 0, stream>>>(h2, gid, sums, cnts, n_nodes);
    k_classifier<<<NGRAPHS / 256, 256, 0, stream>>>(sums, cnts, Wc1, bc1, Wc2, bc2, Wc3, bc3, Wc4, bc4, out);
  }
}

// Round 3
// 738.633 us; speedup vs baseline: 1.4486x; 1.1748x over previous
//
#include <hip/hip_runtime.h>
#include <cstdint>
#include <cstddef>

#define NGRAPHS 512

static inline size_t align_up(size_t x, size_t a){ return (x + a - 1) & ~(a - 1); }

// ---------------- degree histograms ----------------
__global__ void k_degrees(const int* __restrict__ src, const int* __restrict__ dst,
                          int* __restrict__ dout_i, int* __restrict__ din_i, int n_edges){
  int e = blockIdx.x * blockDim.x + threadIdx.x;
  if (e < n_edges){
    atomicAdd(&dout_i[src[e]], 1);
    atomicAdd(&din_i[dst[e]], 1);
  }
}

// ---------------- degree^-1/2 scales ----------------
__global__ void k_scales(const int* __restrict__ dout_i, const int* __restrict__ din_i,
                         float* __restrict__ dout_s, float* __restrict__ din_s, int n){
  int i = blockIdx.x * blockDim.x + threadIdx.x;
  if (i < n){
    dout_s[i] = 1.0f / sqrtf((float)max(dout_i[i], 1));
    din_s[i]  = 1.0f / sqrtf((float)max(din_i[i], 1));
  }
}

// ---------------- 3-phase device-wide exclusive scan (coalesced) ----------------
__global__ __launch_bounds__(256) void k_scan_partial(const int* __restrict__ deg,
                                                      int* __restrict__ bs, int n){
  __shared__ int sm[256];
  int base = blockIdx.x * 4096;
  int s = 0;
#pragma unroll
  for (int it = 0; it < 16; ++it){
    int i = base + it * 256 + threadIdx.x;
    if (i < n) s += deg[i];
  }
  sm[threadIdx.x] = s;
  __syncthreads();
  for (int off = 128; off > 0; off >>= 1){
    if (threadIdx.x < off) sm[threadIdx.x] += sm[threadIdx.x + off];
    __syncthreads();
  }
  if (threadIdx.x == 0) bs[blockIdx.x] = sm[0];
}

__global__ __launch_bounds__(64) void k_scan_blocksums(int* __restrict__ bs, int nb,
                                                       int* __restrict__ offs, int n){
  __shared__ int sm[64];
  int tid = threadIdx.x;
  int v = (tid < nb) ? bs[tid] : 0;
  sm[tid] = v;
  __syncthreads();
  for (int off = 1; off < 64; off <<= 1){
    int t = (tid >= off) ? sm[tid - off] : 0;
    __syncthreads();
    sm[tid] += t;
    __syncthreads();
  }
  if (tid < nb) bs[tid] = sm[tid] - v;   // exclusive
  if (tid == 63) offs[n] = sm[63];       // grand total (= n_edges)
}

__global__ __launch_bounds__(256) void k_scan_write(const int* __restrict__ deg,
    const int* __restrict__ bs, int* __restrict__ offs, int* __restrict__ cursor, int n){
  __shared__ int vals[4096];
  __shared__ int tsum[256];
  int base = blockIdx.x * 4096;
#pragma unroll
  for (int it = 0; it < 16; ++it){
    int i = base + it * 256 + threadIdx.x;
    vals[it * 256 + threadIdx.x] = (i < n) ? deg[i] : 0;
  }
  __syncthreads();
  int t0 = threadIdx.x * 16;
  int loc[16];
  int s = 0;
#pragma unroll
  for (int k = 0; k < 16; ++k){ loc[k] = s; s += vals[t0 + k]; }
  tsum[threadIdx.x] = s;
  __syncthreads();
  for (int off = 1; off < 256; off <<= 1){
    int t = (threadIdx.x >= off) ? tsum[threadIdx.x - off] : 0;
    __syncthreads();
    tsum[threadIdx.x] += t;
    __syncthreads();
  }
  int pre = tsum[threadIdx.x] - s + bs[blockIdx.x];
  __syncthreads();
#pragma unroll
  for (int k = 0; k < 16; ++k) vals[t0 + k] = pre + loc[k];
  __syncthreads();
#pragma unroll
  for (int it = 0; it < 16; ++it){
    int i = base + it * 256 + threadIdx.x;
    if (i < n){
      int v = vals[it * 256 + threadIdx.x];
      offs[i] = v; cursor[i] = v;
    }
  }
}

// ---------------- counting-sort fill: edges grouped by dst ----------------
__global__ void k_fill(const int* __restrict__ src, const int* __restrict__ dst,
                       int* __restrict__ cursor, int* __restrict__ csr_src, int n_edges){
  int e = blockIdx.x * blockDim.x + threadIdx.x;
  if (e < n_edges){
    int p = atomicAdd(&cursor[dst[e]], 1);
    csr_src[p] = src[e];
  }
}

// ---------------- SpMM layer1 (unroll x4 for MLP): agg[n,128] = sum x[s,:]*dout_s[s] ----
__global__ __launch_bounds__(256) void k_spmm1(const float* __restrict__ x,
    const int* __restrict__ offs, const int* __restrict__ csr_src,
    const float* __restrict__ dout_s, float* __restrict__ agg, int n_nodes){
  int node = (blockIdx.x * blockDim.x + threadIdx.x) >> 6;
  int lane = threadIdx.x & 63;
  if (node >= n_nodes) return;
  int j0 = offs[node], j1 = offs[node + 1];
  const float2* xp = (const float2*)x;
  float2 acc = make_float2(0.f, 0.f);
  int j = j0;
  for (; j + 4 <= j1; j += 4){
    int s0 = csr_src[j + 0];
    int s1 = csr_src[j + 1];
    int s2 = csr_src[j + 2];
    int s3 = csr_src[j + 3];
    float c0 = dout_s[s0];
    float c1 = dout_s[s1];
    float c2 = dout_s[s2];
    float c3 = dout_s[s3];
    float2 v0 = xp[(size_t)s0 * 64 + lane];
    float2 v1 = xp[(size_t)s1 * 64 + lane];
    float2 v2 = xp[(size_t)s2 * 64 + lane];
    float2 v3 = xp[(size_t)s3 * 64 + lane];
    acc.x = fmaf(v0.x, c0, acc.x); acc.y = fmaf(v0.y, c0, acc.y);
    acc.x = fmaf(v1.x, c1, acc.x); acc.y = fmaf(v1.y, c1, acc.y);
    acc.x = fmaf(v2.x, c2, acc.x); acc.y = fmaf(v2.y, c2, acc.y);
    acc.x = fmaf(v3.x, c3, acc.x); acc.y = fmaf(v3.y, c3, acc.y);
  }
  for (; j < j1; ++j){
    int s = csr_src[j];
    float sc = dout_s[s];
    float2 v = xp[(size_t)s * 64 + lane];
    acc.x = fmaf(v.x, sc, acc.x);
    acc.y = fmaf(v.y, sc, acc.y);
  }
  ((float2*)agg)[(size_t)node * 64 + lane] = acc;
}

// ---------------- SpMM layer2 (unroll x4) + epilogue: h2 = relu(Agg(t2)*din + b2) ----
__global__ __launch_bounds__(256) void k_spmm2(const float* __restrict__ t2,
    const int* __restrict__ offs, const int* __restrict__ csr_src,
    const float* __restrict__ din_s, const float* __restrict__ b2,
    float* __restrict__ h2, int n_nodes){
  int node = (blockIdx.x * blockDim.x + threadIdx.x) >> 6;
  int lane = threadIdx.x & 63;
  if (node >= n_nodes) return;
  int j0 = offs[node], j1 = offs[node + 1];
  float acc = 0.f;
  int j = j0;
  for (; j + 4 <= j1; j += 4){
    int s0 = csr_src[j + 0];
    int s1 = csr_src[j + 1];
    int s2 = csr_src[j + 2];
    int s3 = csr_src[j + 3];
    float v0 = t2[(size_t)s0 * 64 + lane];
    float v1 = t2[(size_t)s1 * 64 + lane];
    float v2 = t2[(size_t)s2 * 64 + lane];
    float v3 = t2[(size_t)s3 * 64 + lane];
    acc += v0 + v1 + v2 + v3;
  }
  for (; j < j1; ++j) acc += t2[(size_t)csr_src[j] * 64 + lane];
  h2[(size_t)node * 64 + lane] = fmaxf(fmaf(acc, din_s[node], b2[lane]), 0.f);
}

// ---------------- tiled fp32 GEMM, optional A-row-scale on load, optional relu(x*rowscale+bias) epilogue ----
template<int BM, int BN, int BK, int TM, int TN, bool SCALE_A, bool EPI>
__global__ __launch_bounds__(256) void gemm_fused(
    const float* __restrict__ A, const float* __restrict__ B, float* __restrict__ C,
    int M, int N, int K,
    const float* __restrict__ rowScaleA,
    const float* __restrict__ rowScaleC, const float* __restrict__ bias){
  constexpr int THREADS = (BM / TM) * (BN / TN);
  static_assert(THREADS == 256, "block must be 256");
  __shared__ float As[BK][BM + 4];
  __shared__ float Bs[BK][BN + 4];
  int tid = threadIdx.x;
  int bm0 = blockIdx.x * BM;
  int bn0 = blockIdx.y * BN;
  int tx = tid % (BN / TN);
  int ty = tid / (BN / TN);
  float acc[TM][TN] = {};
  constexpr int A_LOADS = BM * BK / (4 * THREADS);
  constexpr int B_LOADS = BN * BK / (4 * THREADS);
  for (int k0 = 0; k0 < K; k0 += BK){
#pragma unroll
    for (int l = 0; l < A_LOADS; ++l){
      int i = tid + l * THREADS;
      int row = i / (BK / 4);
      int k4  = i % (BK / 4);
      float4 v = make_float4(0.f, 0.f, 0.f, 0.f);
      int gr = bm0 + row;
      if (gr < M){
        v = *(const float4*)(A + (size_t)gr * K + k0 + k4 * 4);
        if constexpr (SCALE_A){
          float s = rowScaleA[gr];
          v.x *= s; v.y *= s; v.z *= s; v.w *= s;
        }
      }
      As[k4 * 4 + 0][row] = v.x;
      As[k4 * 4 + 1][row] = v.y;
      As[k4 * 4 + 2][row] = v.z;
      As[k4 * 4 + 3][row] = v.w;
    }
#pragma unroll
    for (int l = 0; l < B_LOADS; ++l){
      int i = tid + l * THREADS;
      int k  = i / (BN / 4);
      int n4 = i % (BN / 4);
      float4 v = *(const float4*)(B + (size_t)(k0 + k) * N + bn0 + n4 * 4);
      *(float4*)&Bs[k][n4 * 4] = v;
    }
    __syncthreads();
#pragma unroll
    for (int k = 0; k < BK; ++k){
      float a[TM], b[TN];
#pragma unroll
      for (int i = 0; i < TM; ++i) a[i] = As[k][ty * TM + i];
#pragma unroll
      for (int j = 0; j < TN; ++j) b[j] = Bs[k][tx * TN + j];
#pragma unroll
      for (int i = 0; i < TM; ++i)
#pragma unroll
        for (int j = 0; j < TN; ++j)
          acc[i][j] = fmaf(a[i], b[j], acc[i][j]);
    }
    __syncthreads();
  }
#pragma unroll
  for (int i = 0; i < TM; ++i){
    int gr = bm0 + ty * TM + i;
    if (gr >= M) break;
    float rs = 1.0f;
    if constexpr (EPI) rs = rowScaleC[gr];
#pragma unroll
    for (int j = 0; j < TN; ++j){
      int gc = bn0 + tx * TN + j;
      float cv = acc[i][j];
      if constexpr (EPI) cv = fmaxf(fmaf(cv, rs, bias[gc]), 0.f);
      C[(size_t)gr * N + gc] = cv;
    }
  }
}

// ---------------- per-graph mean-pool (sorted graph ids): segmented accumulate + atomic flush ----
__global__ __launch_bounds__(256) void k_pool(const float* __restrict__ h2, const int* __restrict__ gids,
                                              float* __restrict__ sums, int* __restrict__ cnts, int n_nodes){
  int wave = (blockIdx.x * blockDim.x + threadIdx.x) >> 6;
  int lane = threadIdx.x & 63;
  int base = wave * 64;
  if (base >= n_nodes) return;
  int endn = min(base + 64, n_nodes);
  float acc = 0.f;
  int cur = -1, len = 0;
  for (int i = base; i < endn; ++i){
    int g = gids[i];                         // wave-uniform
    float v = h2[(size_t)i * 64 + lane];
    if (g != cur){
      if (cur >= 0){
        atomicAdd(&sums[(size_t)cur * 64 + lane], acc);
        if (lane == 0) atomicAdd(&cnts[cur], len);
      }
      cur = g; acc = 0.f; len = 0;
    }
    acc += v; len++;
  }
  atomicAdd(&sums[(size_t)cur * 64 + lane], acc);
  if (lane == 0) atomicAdd(&cnts[cur], len);
}

// ---------------- classifier: hg = sums/cnt; 4 linear layers; out 512x2 ----------------
__global__ __launch_bounds__(256) void k_classifier(const float* __restrict__ sums, const int* __restrict__ cnts,
    const float* __restrict__ Wc1, const float* __restrict__ bc1,
    const float* __restrict__ Wc2, const float* __restrict__ bc2,
    const float* __restrict__ Wc3, const float* __restrict__ bc3,
    const float* __restrict__ Wc4, const float* __restrict__ bc4,
    float* __restrict__ out){
  __shared__ float w1[64 * 18], w2[18 * 12], w3[12 * 6], w4[6 * 2];
  __shared__ float B1[18], B2[12], B3[6], B4[2];
  int tid = threadIdx.x;
  for (int i = tid; i < 64 * 18; i += 256) w1[i] = Wc1[i];
  for (int i = tid; i < 18 * 12; i += 256) w2[i] = Wc2[i];
  for (int i = tid; i < 12 * 6;  i += 256) w3[i] = Wc3[i];
  for (int i = tid; i < 6 * 2;   i += 256) w4[i] = Wc4[i];
  if (tid < 18) B1[tid] = bc1[tid];
  if (tid < 12) B2[tid] = bc2[tid];
  if (tid < 6)  B3[tid] = bc3[tid];
  if (tid < 2)  B4[tid] = bc4[tid];
  __syncthreads();
  int g = blockIdx.x * 256 + tid;
  float cnt = fmaxf((float)cnts[g], 1.0f);
  float h[64];
#pragma unroll
  for (int f = 0; f < 64; ++f) h[f] = sums[(size_t)g * 64 + f] / cnt;
  float t1[18];
#pragma unroll
  for (int j = 0; j < 18; ++j){
    float s = B1[j];
    for (int f = 0; f < 64; ++f) s = fmaf(h[f], w1[f * 18 + j], s);
    t1[j] = s;
  }
  float t2[12];
#pragma unroll
  for (int j = 0; j < 12; ++j){
    float s = B2[j];
    for (int f = 0; f < 18; ++f) s = fmaf(t1[f], w2[f * 12 + j], s);
    t2[j] = s;
  }
  float t3[6];
#pragma unroll
  for (int j = 0; j < 6; ++j){
    float s = B3[j];
    for (int f = 0; f < 12; ++f) s = fmaf(t2[f], w3[f * 6 + j], s);
    t3[j] = s;
  }
#pragma unroll
  for (int j = 0; j < 2; ++j){
    float s = B4[j];
    for (int f = 0; f < 6; ++f) s = fmaf(t3[f], w4[f * 2 + j], s);
    out[(size_t)g * 2 + j] = s;
  }
}

extern "C" void kernel_launch(void* const* d_in, const int* in_sizes, int n_in,
                              void* d_out, int out_size, void* d_ws, size_t ws_size,
                              hipStream_t stream){
  const float* x   = (const float*)d_in[0];
  const int*   src = (const int*)d_in[1];
  const int*   dst = (const int*)d_in[2];
  const int*   gid = (const int*)d_in[3];
  const float* W1  = (const float*)d_in[4];
  const float* b1  = (const float*)d_in[5];
  const float* W2  = (const float*)d_in[6];
  const float* b2  = (const float*)d_in[7];
  const float* Wc1 = (const float*)d_in[8];
  const float* bc1 = (const float*)d_in[9];
  const float* Wc2 = (const float*)d_in[10];
  const float* bc2 = (const float*)d_in[11];
  const float* Wc3 = (const float*)d_in[12];
  const float* bc3 = (const float*)d_in[13];
  const float* Wc4 = (const float*)d_in[14];
  const float* bc4 = (const float*)d_in[15];
  float* out = (float*)d_out;

  const int n_nodes = in_sizes[3];
  const int n_edges = in_sizes[1];
  const int F1 = 256, F2 = 64;

  // workspace layout
  char* w = (char*)d_ws;
  size_t o = 0;
  auto alloc = [&](size_t bytes) -> char* {
    char* p = w + o;
    o = align_up(o + bytes, 256);
    return p;
  };
  int*   deg_out_i = (int*)  alloc((size_t)n_nodes * 4);
  int*   deg_in_i  = (int*)  alloc((size_t)n_nodes * 4);
  float* sums      = (float*)alloc((size_t)NGRAPHS * F2 * 4);
  int*   cnts      = (int*)  alloc((size_t)NGRAPHS * 4);
  size_t zero_bytes = o;                       // everything above must start at 0
  float* dout_s    = (float*)alloc((size_t)n_nodes * 4);
  float* din_s     = (float*)alloc((size_t)n_nodes * 4);
  int*   offs      = (int*)  alloc((size_t)(n_nodes + 1) * 4);
  int*   cursor    = (int*)  alloc((size_t)n_nodes * 4);
  int*   block_sums= (int*)  alloc((size_t)64 * 4);
  int*   csr_src   = (int*)  alloc((size_t)n_edges * 4);
  float* agg       = (float*)alloc((size_t)n_nodes * 128 * 4);   // layer1 aggregation (K=128)
  float* h1        = (float*)alloc((size_t)n_nodes * F1 * 4);    // layer1 output (256)
  float* t2buf = agg;   // reuse: GEMM2 output (64 wide) after agg is consumed
  float* h2    = h1;    // reuse: layer2 output after h1 is consumed

  hipMemsetAsync(d_ws, 0, zero_bytes, stream);

  k_degrees<<<(n_edges + 255) / 256, 256, 0, stream>>>(src, dst, deg_out_i, deg_in_i, n_edges);
  k_scales <<<(n_nodes + 255) / 256, 256, 0, stream>>>(deg_out_i, deg_in_i, dout_s, din_s, n_nodes);

  // 3-phase device-wide exclusive scan of deg_in -> offs + cursor
  int nscan_blocks = (n_nodes + 4095) / 4096;   // 25 for n=100000 (<=64 supported)
  k_scan_partial  <<<nscan_blocks, 256, 0, stream>>>(deg_in_i, block_sums, n_nodes);
  k_scan_blocksums<<<1, 64, 0, stream>>>(block_sums, nscan_blocks, offs, n_nodes);
  k_scan_write    <<<nscan_blocks, 256, 0, stream>>>(deg_in_i, block_sums, offs, cursor, n_nodes);

  k_fill   <<<(n_edges + 255) / 256, 256, 0, stream>>>(src, dst, cursor, csr_src, n_edges);

  // layer 1: agg = Agg(x * dout); h1 = relu((agg @ W1) * din + b1)
  {
    long long threads = (long long)n_nodes * 64;
    k_spmm1<<<(int)((threads + 255) / 256), 256, 0, stream>>>(x, offs, csr_src, dout_s, agg, n_nodes);
    dim3 g1((n_nodes + 127) / 128, F1 / 128);
    gemm_fused<128, 128, 16, 8, 8, false, true><<<g1, 256, 0, stream>>>(
        agg, W1, h1, n_nodes, F1, 128, nullptr, din_s, b1);
  }
  // layer 2: t2 = (h1 * dout) @ W2; h2 = relu(Agg(t2) * din + b2)
  {
    dim3 g2((n_nodes + 127) / 128, 1);
    gemm_fused<128, 64, 16, 8, 4, true, false><<<g2, 256, 0, stream>>>(
        h1, W2, t2buf, n_nodes, F2, F1, dout_s, nullptr, nullptr);
    long long threads = (long long)n_nodes * 64;
    k_spmm2<<<(int)((threads + 255) / 256), 256, 0, stream>>>(t2buf, offs, csr_src, din_s, b2, h2, n_nodes);
  }
  // pooling + classifier
  {
    int pool_waves = (n_nodes + 63) / 64;
    long long threads = (long long)pool_waves * 64;
    k_pool<<<(int)((threads + 255) / 256), 256, 0, stream>>>(h2, gid, sums, cnts, n_nodes);
    k_classifier<<<NGRAPHS / 256, 256, 0, stream>>>(sums, cnts, Wc1, bc1, Wc2, bc2, Wc3, bc3, Wc4, bc4, out);
  }
}

// Round 4
// 690.015 us; speedup vs baseline: 1.5507x; 1.0705x over previous
//
#include <hip/hip_runtime.h>
#include <cstdint>
#include <cstddef>

#define NGRAPHS 512

static inline size_t align_up(size_t x, size_t a){ return (x + a - 1) & ~(a - 1); }

// ---------------- degree histograms ----------------
__global__ void k_degrees(const int* __restrict__ src, const int* __restrict__ dst,
                          int* __restrict__ dout_i, int* __restrict__ din_i, int n_edges){
  int e = blockIdx.x * blockDim.x + threadIdx.x;
  if (e < n_edges){
    atomicAdd(&dout_i[src[e]], 1);
    atomicAdd(&din_i[dst[e]], 1);
  }
}

// ---------------- degree^-1/2 scales ----------------
__global__ void k_scales(const int* __restrict__ dout_i, const int* __restrict__ din_i,
                         float* __restrict__ dout_s, float* __restrict__ din_s, int n){
  int i = blockIdx.x * blockDim.x + threadIdx.x;
  if (i < n){
    dout_s[i] = 1.0f / sqrtf((float)max(dout_i[i], 1));
    din_s[i]  = 1.0f / sqrtf((float)max(din_i[i], 1));
  }
}

// ---------------- 3-phase device-wide exclusive scan (coalesced) ----------------
__global__ __launch_bounds__(256) void k_scan_partial(const int* __restrict__ deg,
                                                      int* __restrict__ bs, int n){
  __shared__ int sm[256];
  int base = blockIdx.x * 4096;
  int s = 0;
#pragma unroll
  for (int it = 0; it < 16; ++it){
    int i = base + it * 256 + threadIdx.x;
    if (i < n) s += deg[i];
  }
  sm[threadIdx.x] = s;
  __syncthreads();
  for (int off = 128; off > 0; off >>= 1){
    if (threadIdx.x < off) sm[threadIdx.x] += sm[threadIdx.x + off];
    __syncthreads();
  }
  if (threadIdx.x == 0) bs[blockIdx.x] = sm[0];
}

__global__ __launch_bounds__(64) void k_scan_blocksums(int* __restrict__ bs, int nb,
                                                       int* __restrict__ offs, int n){
  __shared__ int sm[64];
  int tid = threadIdx.x;
  int v = (tid < nb) ? bs[tid] : 0;
  sm[tid] = v;
  __syncthreads();
  for (int off = 1; off < 64; off <<= 1){
    int t = (tid >= off) ? sm[tid - off] : 0;
    __syncthreads();
    sm[tid] += t;
    __syncthreads();
  }
  if (tid < nb) bs[tid] = sm[tid] - v;   // exclusive
  if (tid == 63) offs[n] = sm[63];       // grand total (= n_edges)
}

__global__ __launch_bounds__(256) void k_scan_write(const int* __restrict__ deg,
    const int* __restrict__ bs, int* __restrict__ offs, int n){
  __shared__ int vals[4096];
  __shared__ int tsum[256];
  int base = blockIdx.x * 4096;
#pragma unroll
  for (int it = 0; it < 16; ++it){
    int i = base + it * 256 + threadIdx.x;
    vals[it * 256 + threadIdx.x] = (i < n) ? deg[i] : 0;
  }
  __syncthreads();
  int t0 = threadIdx.x * 16;
  int loc[16];
  int s = 0;
#pragma unroll
  for (int k = 0; k < 16; ++k){ loc[k] = s; s += vals[t0 + k]; }
  tsum[threadIdx.x] = s;
  __syncthreads();
  for (int off = 1; off < 256; off <<= 1){
    int t = (threadIdx.x >= off) ? tsum[threadIdx.x - off] : 0;
    __syncthreads();
    tsum[threadIdx.x] += t;
    __syncthreads();
  }
  int pre = tsum[threadIdx.x] - s + bs[blockIdx.x];
  __syncthreads();
#pragma unroll
  for (int k = 0; k < 16; ++k) vals[t0 + k] = pre + loc[k];
  __syncthreads();
#pragma unroll
  for (int it = 0; it < 16; ++it){
    int i = base + it * 256 + threadIdx.x;
    if (i < n) offs[i] = vals[it * 256 + threadIdx.x];
  }
}

// ---------------- bucketed CSR build ----------------
// bucket b = contiguous node range [b*512,(b+1)*512); its CSR region is offs[b*512]..offs[(b+1)*512]
__global__ void k_rsv_init(const int* __restrict__ offs, int* __restrict__ rsv, int NB, int n){
  int b = blockIdx.x * blockDim.x + threadIdx.x;
  if (b < NB) rsv[b] = offs[min(b << 9, n)];
}

// phase 1: scatter (src,dst) pairs into their bucket's CSR region (position within bucket arbitrary)
__global__ __launch_bounds__(256) void k_binfill(const int* __restrict__ src, const int* __restrict__ dst,
                                                 int* __restrict__ rsv, int2* __restrict__ pair,
                                                 int n_edges, int chunk){
  __shared__ int cnt[256];
  __shared__ int cur[256];
  int e0 = blockIdx.x * chunk;
  int e1 = min(e0 + chunk, n_edges);
  cnt[threadIdx.x] = 0;
  __syncthreads();
  for (int e = e0 + threadIdx.x; e < e1; e += 256)
    atomicAdd(&cnt[dst[e] >> 9], 1);
  __syncthreads();
  int c = cnt[threadIdx.x];
  cur[threadIdx.x] = (c > 0) ? atomicAdd(&rsv[threadIdx.x], c) : 0;  // rsv index < NB whenever c>0
  __syncthreads();
  for (int e = e0 + threadIdx.x; e < e1; e += 256){
    int d = dst[e];
    int p = atomicAdd(&cur[d >> 9], 1);
    pair[p] = make_int2(src[e], d);
  }
}

// phase 2: within one bucket, counting-sort by exact dst using LDS cursors (no global atomics)
__global__ __launch_bounds__(256) void k_csrfill(const int2* __restrict__ pair, const int* __restrict__ offs,
                                                 int* __restrict__ csr_src, int n){
  __shared__ int cur[512];
  int node0 = blockIdx.x << 9;
  int nn = min(512, n - node0);
  for (int i = threadIdx.x; i < nn; i += 256) cur[i] = offs[node0 + i];
  __syncthreads();
  int j0 = offs[node0];
  int j1 = offs[min(node0 + 512, n)];
  for (int j = j0 + threadIdx.x; j < j1; j += 256){
    int2 e = pair[j];
    int p = atomicAdd(&cur[e.y - node0], 1);
    csr_src[p] = e.x;
  }
}

// ---------------- SpMM layer1 (unroll x4 for MLP): agg[n,128] = sum x[s,:]*dout_s[s] ----
__global__ __launch_bounds__(256) void k_spmm1(const float* __restrict__ x,
    const int* __restrict__ offs, const int* __restrict__ csr_src,
    const float* __restrict__ dout_s, float* __restrict__ agg, int n_nodes){
  int node = (blockIdx.x * blockDim.x + threadIdx.x) >> 6;
  int lane = threadIdx.x & 63;
  if (node >= n_nodes) return;
  int j0 = offs[node], j1 = offs[node + 1];
  const float2* xp = (const float2*)x;
  float2 acc = make_float2(0.f, 0.f);
  int j = j0;
  for (; j + 4 <= j1; j += 4){
    int s0 = csr_src[j + 0];
    int s1 = csr_src[j + 1];
    int s2 = csr_src[j + 2];
    int s3 = csr_src[j + 3];
    float c0 = dout_s[s0];
    float c1 = dout_s[s1];
    float c2 = dout_s[s2];
    float c3 = dout_s[s3];
    float2 v0 = xp[(size_t)s0 * 64 + lane];
    float2 v1 = xp[(size_t)s1 * 64 + lane];
    float2 v2 = xp[(size_t)s2 * 64 + lane];
    float2 v3 = xp[(size_t)s3 * 64 + lane];
    acc.x = fmaf(v0.x, c0, acc.x); acc.y = fmaf(v0.y, c0, acc.y);
    acc.x = fmaf(v1.x, c1, acc.x); acc.y = fmaf(v1.y, c1, acc.y);
    acc.x = fmaf(v2.x, c2, acc.x); acc.y = fmaf(v2.y, c2, acc.y);
    acc.x = fmaf(v3.x, c3, acc.x); acc.y = fmaf(v3.y, c3, acc.y);
  }
  for (; j < j1; ++j){
    int s = csr_src[j];
    float sc = dout_s[s];
    float2 v = xp[(size_t)s * 64 + lane];
    acc.x = fmaf(v.x, sc, acc.x);
    acc.y = fmaf(v.y, sc, acc.y);
  }
  ((float2*)agg)[(size_t)node * 64 + lane] = acc;
}

// ---------------- SpMM layer2 (unroll x4) + epilogue: h2 = relu(Agg(t2)*din + b2) ----
__global__ __launch_bounds__(256) void k_spmm2(const float* __restrict__ t2,
    const int* __restrict__ offs, const int* __restrict__ csr_src,
    const float* __restrict__ din_s, const float* __restrict__ b2,
    float* __restrict__ h2, int n_nodes){
  int node = (blockIdx.x * blockDim.x + threadIdx.x) >> 6;
  int lane = threadIdx.x & 63;
  if (node >= n_nodes) return;
  int j0 = offs[node], j1 = offs[node + 1];
  float acc = 0.f;
  int j = j0;
  for (; j + 4 <= j1; j += 4){
    int s0 = csr_src[j + 0];
    int s1 = csr_src[j + 1];
    int s2 = csr_src[j + 2];
    int s3 = csr_src[j + 3];
    float v0 = t2[(size_t)s0 * 64 + lane];
    float v1 = t2[(size_t)s1 * 64 + lane];
    float v2 = t2[(size_t)s2 * 64 + lane];
    float v3 = t2[(size_t)s3 * 64 + lane];
    acc += v0 + v1 + v2 + v3;
  }
  for (; j < j1; ++j) acc += t2[(size_t)csr_src[j] * 64 + lane];
  h2[(size_t)node * 64 + lane] = fmaxf(fmaf(acc, din_s[node], b2[lane]), 0.f);
}

// ---------------- tiled fp32 GEMM, optional A-row-scale on load, optional relu(x*rowscale+bias) epilogue ----
template<int BM, int BN, int BK, int TM, int TN, bool SCALE_A, bool EPI>
__global__ __launch_bounds__(256) void gemm_fused(
    const float* __restrict__ A, const float* __restrict__ B, float* __restrict__ C,
    int M, int N, int K,
    const float* __restrict__ rowScaleA,
    const float* __restrict__ rowScaleC, const float* __restrict__ bias){
  constexpr int THREADS = (BM / TM) * (BN / TN);
  static_assert(THREADS == 256, "block must be 256");
  __shared__ float As[BK][BM + 4];
  __shared__ float Bs[BK][BN + 4];
  int tid = threadIdx.x;
  int bm0 = blockIdx.x * BM;
  int bn0 = blockIdx.y * BN;
  int tx = tid % (BN / TN);
  int ty = tid / (BN / TN);
  float acc[TM][TN] = {};
  constexpr int A_LOADS = BM * BK / (4 * THREADS);
  constexpr int B_LOADS = BN * BK / (4 * THREADS);
  for (int k0 = 0; k0 < K; k0 += BK){
#pragma unroll
    for (int l = 0; l < A_LOADS; ++l){
      int i = tid + l * THREADS;
      int row = i / (BK / 4);
      int k4  = i % (BK / 4);
      float4 v = make_float4(0.f, 0.f, 0.f, 0.f);
      int gr = bm0 + row;
      if (gr < M){
        v = *(const float4*)(A + (size_t)gr * K + k0 + k4 * 4);
        if constexpr (SCALE_A){
          float s = rowScaleA[gr];
          v.x *= s; v.y *= s; v.z *= s; v.w *= s;
        }
      }
      As[k4 * 4 + 0][row] = v.x;
      As[k4 * 4 + 1][row] = v.y;
      As[k4 * 4 + 2][row] = v.z;
      As[k4 * 4 + 3][row] = v.w;
    }
#pragma unroll
    for (int l = 0; l < B_LOADS; ++l){
      int i = tid + l * THREADS;
      int k  = i / (BN / 4);
      int n4 = i % (BN / 4);
      float4 v = *(const float4*)(B + (size_t)(k0 + k) * N + bn0 + n4 * 4);
      *(float4*)&Bs[k][n4 * 4] = v;
    }
    __syncthreads();
#pragma unroll
    for (int k = 0; k < BK; ++k){
      float a[TM], b[TN];
#pragma unroll
      for (int i = 0; i < TM; ++i) a[i] = As[k][ty * TM + i];
#pragma unroll
      for (int j = 0; j < TN; ++j) b[j] = Bs[k][tx * TN + j];
#pragma unroll
      for (int i = 0; i < TM; ++i)
#pragma unroll
        for (int j = 0; j < TN; ++j)
          acc[i][j] = fmaf(a[i], b[j], acc[i][j]);
    }
    __syncthreads();
  }
#pragma unroll
  for (int i = 0; i < TM; ++i){
    int gr = bm0 + ty * TM + i;
    if (gr >= M) break;
    float rs = 1.0f;
    if constexpr (EPI) rs = rowScaleC[gr];
#pragma unroll
    for (int j = 0; j < TN; ++j){
      int gc = bn0 + tx * TN + j;
      float cv = acc[i][j];
      if constexpr (EPI) cv = fmaxf(fmaf(cv, rs, bias[gc]), 0.f);
      C[(size_t)gr * N + gc] = cv;
    }
  }
}

// ---------------- per-graph mean-pool (sorted graph ids): segmented accumulate + atomic flush ----
__global__ __launch_bounds__(256) void k_pool(const float* __restrict__ h2, const int* __restrict__ gids,
                                              float* __restrict__ sums, int* __restrict__ cnts, int n_nodes){
  int wave = (blockIdx.x * blockDim.x + threadIdx.x) >> 6;
  int lane = threadIdx.x & 63;
  int base = wave * 64;
  if (base >= n_nodes) return;
  int endn = min(base + 64, n_nodes);
  float acc = 0.f;
  int cur = -1, len = 0;
  for (int i = base; i < endn; ++i){
    int g = gids[i];                         // wave-uniform
    float v = h2[(size_t)i * 64 + lane];
    if (g != cur){
      if (cur >= 0){
        atomicAdd(&sums[(size_t)cur * 64 + lane], acc);
        if (lane == 0) atomicAdd(&cnts[cur], len);
      }
      cur = g; acc = 0.f; len = 0;
    }
    acc += v; len++;
  }
  atomicAdd(&sums[(size_t)cur * 64 + lane], acc);
  if (lane == 0) atomicAdd(&cnts[cur], len);
}

// ---------------- classifier: hg = sums/cnt; 4 linear layers; out 512x2 ----------------
__global__ __launch_bounds__(256) void k_classifier(const float* __restrict__ sums, const int* __restrict__ cnts,
    const float* __restrict__ Wc1, const float* __restrict__ bc1,
    const float* __restrict__ Wc2, const float* __restrict__ bc2,
    const float* __restrict__ Wc3, const float* __restrict__ bc3,
    const float* __restrict__ Wc4, const float* __restrict__ bc4,
    float* __restrict__ out){
  __shared__ float w1[64 * 18], w2[18 * 12], w3[12 * 6], w4[6 * 2];
  __shared__ float B1[18], B2[12], B3[6], B4[2];
  int tid = threadIdx.x;
  for (int i = tid; i < 64 * 18; i += 256) w1[i] = Wc1[i];
  for (int i = tid; i < 18 * 12; i += 256) w2[i] = Wc2[i];
  for (int i = tid; i < 12 * 6;  i += 256) w3[i] = Wc3[i];
  for (int i = tid; i < 6 * 2;   i += 256) w4[i] = Wc4[i];
  if (tid < 18) B1[tid] = bc1[tid];
  if (tid < 12) B2[tid] = bc2[tid];
  if (tid < 6)  B3[tid] = bc3[tid];
  if (tid < 2)  B4[tid] = bc4[tid];
  __syncthreads();
  int g = blockIdx.x * 256 + tid;
  float cnt = fmaxf((float)cnts[g], 1.0f);
  float h[64];
#pragma unroll
  for (int f = 0; f < 64; ++f) h[f] = sums[(size_t)g * 64 + f] / cnt;
  float t1[18];
#pragma unroll
  for (int j = 0; j < 18; ++j){
    float s = B1[j];
    for (int f = 0; f < 64; ++f) s = fmaf(h[f], w1[f * 18 + j], s);
    t1[j] = s;
  }
  float t2[12];
#pragma unroll
  for (int j = 0; j < 12; ++j){
    float s = B2[j];
    for (int f = 0; f < 18; ++f) s = fmaf(t1[f], w2[f * 12 + j], s);
    t2[j] = s;
  }
  float t3[6];
#pragma unroll
  for (int j = 0; j < 6; ++j){
    float s = B3[j];
    for (int f = 0; f < 12; ++f) s = fmaf(t2[f], w3[f * 6 + j], s);
    t3[j] = s;
  }
#pragma unroll
  for (int j = 0; j < 2; ++j){
    float s = B4[j];
    for (int f = 0; f < 6; ++f) s = fmaf(t3[f], w4[f * 2 + j], s);
    out[(size_t)g * 2 + j] = s;
  }
}

extern "C" void kernel_launch(void* const* d_in, const int* in_sizes, int n_in,
                              void* d_out, int out_size, void* d_ws, size_t ws_size,
                              hipStream_t stream){
  const float* x   = (const float*)d_in[0];
  const int*   src = (const int*)d_in[1];
  const int*   dst = (const int*)d_in[2];
  const int*   gid = (const int*)d_in[3];
  const float* W1  = (const float*)d_in[4];
  const float* b1  = (const float*)d_in[5];
  const float* W2  = (const float*)d_in[6];
  const float* b2  = (const float*)d_in[7];
  const float* Wc1 = (const float*)d_in[8];
  const float* bc1 = (const float*)d_in[9];
  const float* Wc2 = (const float*)d_in[10];
  const float* bc2 = (const float*)d_in[11];
  const float* Wc3 = (const float*)d_in[12];
  const float* bc3 = (const float*)d_in[13];
  const float* Wc4 = (const float*)d_in[14];
  const float* bc4 = (const float*)d_in[15];
  float* out = (float*)d_out;

  const int n_nodes = in_sizes[3];
  const int n_edges = in_sizes[1];
  const int F1 = 256, F2 = 64;
  const int NB = (n_nodes + 511) >> 9;   // 512-node buckets

  // workspace layout
  char* w = (char*)d_ws;
  size_t o = 0;
  auto alloc = [&](size_t bytes) -> char* {
    char* p = w + o;
    o = align_up(o + bytes, 256);
    return p;
  };
  int*   deg_out_i = (int*)  alloc((size_t)n_nodes * 4);
  int*   deg_in_i  = (int*)  alloc((size_t)n_nodes * 4);
  float* sums      = (float*)alloc((size_t)NGRAPHS * F2 * 4);
  int*   cnts      = (int*)  alloc((size_t)NGRAPHS * 4);
  size_t zero_bytes = o;                       // everything above must start at 0
  float* dout_s    = (float*)alloc((size_t)n_nodes * 4);
  float* din_s     = (float*)alloc((size_t)n_nodes * 4);
  int*   offs      = (int*)  alloc((size_t)(n_nodes + 1) * 4);
  int*   block_sums= (int*)  alloc((size_t)64 * 4);
  int*   bucket_rsv= (int*)  alloc((size_t)NB * 4);
  int*   csr_src   = (int*)  alloc((size_t)n_edges * 4);
  float* agg       = (float*)alloc((size_t)n_nodes * 128 * 4);   // layer1 aggregation (K=128)
  float* h1        = (float*)alloc((size_t)n_nodes * F1 * 4);    // layer1 output (256)
  int2*  pair_buf = (int2*)agg;  // alias: consumed by k_csrfill before spmm1 writes agg
  float* t2buf = agg;            // reuse: GEMM2 output (64 wide) after agg is consumed
  float* h2    = h1;             // reuse: layer2 output after h1 is consumed

  hipMemsetAsync(d_ws, 0, zero_bytes, stream);

  k_degrees<<<(n_edges + 255) / 256, 256, 0, stream>>>(src, dst, deg_out_i, deg_in_i, n_edges);
  k_scales <<<(n_nodes + 255) / 256, 256, 0, stream>>>(deg_out_i, deg_in_i, dout_s, din_s, n_nodes);

  // 3-phase device-wide exclusive scan of deg_in -> offs
  int nscan_blocks = (n_nodes + 4095) / 4096;   // 25 for n=100000 (<=64 supported)
  k_scan_partial  <<<nscan_blocks, 256, 0, stream>>>(deg_in_i, block_sums, n_nodes);
  k_scan_blocksums<<<1, 64, 0, stream>>>(block_sums, nscan_blocks, offs, n_nodes);
  k_scan_write    <<<nscan_blocks, 256, 0, stream>>>(deg_in_i, block_sums, offs, n_nodes);

  // bucketed CSR build (write-locality version of counting sort)
  k_rsv_init<<<(NB + 255) / 256, 256, 0, stream>>>(offs, bucket_rsv, NB, n_nodes);
  {
    int nb1 = 100;
    int chunk = (n_edges + nb1 - 1) / nb1;
    k_binfill<<<nb1, 256, 0, stream>>>(src, dst, bucket_rsv, pair_buf, n_edges, chunk);
    k_csrfill<<<NB, 256, 0, stream>>>(pair_buf, offs, csr_src, n_nodes);
  }

  // layer 1: agg = Agg(x * dout); h1 = relu((agg @ W1) * din + b1)
  {
    long long threads = (long long)n_nodes * 64;
    k_spmm1<<<(int)((threads + 255) / 256), 256, 0, stream>>>(x, offs, csr_src, dout_s, agg, n_nodes);
    dim3 g1((n_nodes + 127) / 128, F1 / 128);
    gemm_fused<128, 128, 16, 8, 8, false, true><<<g1, 256, 0, stream>>>(
        agg, W1, h1, n_nodes, F1, 128, nullptr, din_s, b1);
  }
  // layer 2: t2 = (h1 * dout) @ W2; h2 = relu(Agg(t2) * din + b2)
  {
    dim3 g2((n_nodes + 127) / 128, 1);
    gemm_fused<128, 64, 16, 8, 4, true, false><<<g2, 256, 0, stream>>>(
        h1, W2, t2buf, n_nodes, F2, F1, dout_s, nullptr, nullptr);
    long long threads = (long long)n_nodes * 64;
    k_spmm2<<<(int)((threads + 255) / 256), 256, 0, stream>>>(t2buf, offs, csr_src, din_s, b2, h2, n_nodes);
  }
  // pooling + classifier
  {
    int pool_waves = (n_nodes + 63) / 64;
    long long threads = (long long)pool_waves * 64;
    k_pool<<<(int)((threads + 255) / 256), 256, 0, stream>>>(h2, gid, sums, cnts, n_nodes);
    k_classifier<<<NGRAPHS / 256, 256, 0, stream>>>(sums, cnts, Wc1, bc1, Wc2, bc2, Wc3, bc3, Wc4, bc4, out);
  }
}

// Round 5
// 607.073 us; speedup vs baseline: 1.7625x; 1.1366x over previous
//
#include <hip/hip_runtime.h>
#include <cstdint>
#include <cstddef>

#define NGRAPHS 512

static inline size_t align_up(size_t x, size_t a){ return (x + a - 1) & ~(a - 1); }

// ================= bucketed graph preprocessing =================
// buckets = contiguous 512-node ranges; NB = ceil(n/512) must be <= 256.

// count edges per bucket for src and dst sides (LDS histograms, tiny global flush)
__global__ __launch_bounds__(256) void k_bincount(const int* __restrict__ src, const int* __restrict__ dst,
                                                  int* __restrict__ bcnt_src, int* __restrict__ bcnt_dst,
                                                  int n_edges, int NB){
  __shared__ int cs[256], cd[256];
  cs[threadIdx.x] = 0; cd[threadIdx.x] = 0;
  __syncthreads();
  int stride = gridDim.x * 256;
  for (int e = blockIdx.x * 256 + threadIdx.x; e < n_edges; e += stride){
    atomicAdd(&cs[src[e] >> 9], 1);
    atomicAdd(&cd[dst[e] >> 9], 1);
  }
  __syncthreads();
  if (threadIdx.x < NB){
    int a = cs[threadIdx.x], b = cd[threadIdx.x];
    if (a) atomicAdd(&bcnt_src[threadIdx.x], a);
    if (b) atomicAdd(&bcnt_dst[threadIdx.x], b);
  }
}

// single-block scan of bucket counts -> bases + scatter cursors (both sides)
__global__ __launch_bounds__(256) void k_bucket_scan(const int* __restrict__ bcnt_src, const int* __restrict__ bcnt_dst,
                                                     int* __restrict__ base_src, int* __restrict__ cur_src,
                                                     int* __restrict__ base_dst, int* __restrict__ cur_dst, int NB){
  __shared__ int s1[256], s2[256];
  int tid = threadIdx.x;
  int v1 = (tid < NB) ? bcnt_src[tid] : 0;
  int v2 = (tid < NB) ? bcnt_dst[tid] : 0;
  s1[tid] = v1; s2[tid] = v2;
  __syncthreads();
  for (int off = 1; off < 256; off <<= 1){
    int t1 = (tid >= off) ? s1[tid - off] : 0;
    int t2 = (tid >= off) ? s2[tid - off] : 0;
    __syncthreads();
    s1[tid] += t1; s2[tid] += t2;
    __syncthreads();
  }
  if (tid < NB){
    base_src[tid] = s1[tid] - v1; cur_src[tid] = s1[tid] - v1;
    base_dst[tid] = s2[tid] - v2; cur_dst[tid] = s2[tid] - v2;
  }
}

// scatter (src,dst) pairs by dst-bucket and bare src by src-bucket (bucket-frontier-local writes)
__global__ __launch_bounds__(256) void k_binscatter(const int* __restrict__ src, const int* __restrict__ dst,
                                                    int* __restrict__ rsv_d, int* __restrict__ rsv_s,
                                                    int2* __restrict__ pairD, int* __restrict__ srcS,
                                                    int n_edges, int chunk){
  __shared__ int cntd[256], curd[256], cnts_[256], curs[256];
  int e0 = blockIdx.x * chunk;
  int e1 = min(e0 + chunk, n_edges);
  cntd[threadIdx.x] = 0; cnts_[threadIdx.x] = 0;
  __syncthreads();
  for (int e = e0 + threadIdx.x; e < e1; e += 256){
    atomicAdd(&cntd[dst[e] >> 9], 1);
    atomicAdd(&cnts_[src[e] >> 9], 1);
  }
  __syncthreads();
  int cd = cntd[threadIdx.x], cs = cnts_[threadIdx.x];
  curd[threadIdx.x] = cd ? atomicAdd(&rsv_d[threadIdx.x], cd) : 0;
  curs[threadIdx.x] = cs ? atomicAdd(&rsv_s[threadIdx.x], cs) : 0;
  __syncthreads();
  for (int e = e0 + threadIdx.x; e < e1; e += 256){
    int s = src[e], d = dst[e];
    int pd = atomicAdd(&curd[d >> 9], 1);
    pairD[pd] = make_int2(s, d);
    int ps = atomicAdd(&curs[s >> 9], 1);
    srcS[ps] = s;
  }
}

// per-bucket exact dst histogram (LDS counters) -> deg_in + din_s, coalesced writes
__global__ __launch_bounds__(256) void k_bucket_hist_dst(const int2* __restrict__ pairD, const int* __restrict__ base_dst,
                                                         int* __restrict__ deg_in, float* __restrict__ din_s,
                                                         int NB, int n, int n_edges){
  __shared__ int cnt[512];
  int b = blockIdx.x;
  int node0 = b << 9;
  int nn = min(512, n - node0);
  for (int i = threadIdx.x; i < 512; i += 256) cnt[i] = 0;
  __syncthreads();
  int j0 = base_dst[b];
  int j1 = (b + 1 < NB) ? base_dst[b + 1] : n_edges;
  for (int j = j0 + threadIdx.x; j < j1; j += 256)
    atomicAdd(&cnt[pairD[j].y - node0], 1);
  __syncthreads();
  for (int i = threadIdx.x; i < nn; i += 256){
    int c = cnt[i];
    deg_in[node0 + i] = c;
    din_s[node0 + i] = 1.0f / sqrtf((float)max(c, 1));
  }
}

// per-bucket exact src histogram -> dout_s, coalesced writes
__global__ __launch_bounds__(256) void k_bucket_hist_src(const int* __restrict__ srcS, const int* __restrict__ base_src,
                                                         float* __restrict__ dout_s, int NB, int n, int n_edges){
  __shared__ int cnt[512];
  int b = blockIdx.x;
  int node0 = b << 9;
  int nn = min(512, n - node0);
  for (int i = threadIdx.x; i < 512; i += 256) cnt[i] = 0;
  __syncthreads();
  int j0 = base_src[b];
  int j1 = (b + 1 < NB) ? base_src[b + 1] : n_edges;
  for (int j = j0 + threadIdx.x; j < j1; j += 256)
    atomicAdd(&cnt[srcS[j] - node0], 1);
  __syncthreads();
  for (int i = threadIdx.x; i < nn; i += 256)
    dout_s[node0 + i] = 1.0f / sqrtf((float)max(cnt[i], 1));
}

// ---------------- 3-phase device-wide exclusive scan (coalesced) ----------------
__global__ __launch_bounds__(256) void k_scan_partial(const int* __restrict__ deg,
                                                      int* __restrict__ bs, int n){
  __shared__ int sm[256];
  int base = blockIdx.x * 4096;
  int s = 0;
#pragma unroll
  for (int it = 0; it < 16; ++it){
    int i = base + it * 256 + threadIdx.x;
    if (i < n) s += deg[i];
  }
  sm[threadIdx.x] = s;
  __syncthreads();
  for (int off = 128; off > 0; off >>= 1){
    if (threadIdx.x < off) sm[threadIdx.x] += sm[threadIdx.x + off];
    __syncthreads();
  }
  if (threadIdx.x == 0) bs[blockIdx.x] = sm[0];
}

__global__ __launch_bounds__(64) void k_scan_blocksums(int* __restrict__ bs, int nb,
                                                       int* __restrict__ offs, int n){
  __shared__ int sm[64];
  int tid = threadIdx.x;
  int v = (tid < nb) ? bs[tid] : 0;
  sm[tid] = v;
  __syncthreads();
  for (int off = 1; off < 64; off <<= 1){
    int t = (tid >= off) ? sm[tid - off] : 0;
    __syncthreads();
    sm[tid] += t;
    __syncthreads();
  }
  if (tid < nb) bs[tid] = sm[tid] - v;   // exclusive
  if (tid == 63) offs[n] = sm[63];       // grand total (= n_edges)
}

__global__ __launch_bounds__(256) void k_scan_write(const int* __restrict__ deg,
    const int* __restrict__ bs, int* __restrict__ offs, int n){
  __shared__ int vals[4096];
  __shared__ int tsum[256];
  int base = blockIdx.x * 4096;
#pragma unroll
  for (int it = 0; it < 16; ++it){
    int i = base + it * 256 + threadIdx.x;
    vals[it * 256 + threadIdx.x] = (i < n) ? deg[i] : 0;
  }
  __syncthreads();
  int t0 = threadIdx.x * 16;
  int loc[16];
  int s = 0;
#pragma unroll
  for (int k = 0; k < 16; ++k){ loc[k] = s; s += vals[t0 + k]; }
  tsum[threadIdx.x] = s;
  __syncthreads();
  for (int off = 1; off < 256; off <<= 1){
    int t = (threadIdx.x >= off) ? tsum[threadIdx.x - off] : 0;
    __syncthreads();
    tsum[threadIdx.x] += t;
    __syncthreads();
  }
  int pre = tsum[threadIdx.x] - s + bs[blockIdx.x];
  __syncthreads();
#pragma unroll
  for (int k = 0; k < 16; ++k) vals[t0 + k] = pre + loc[k];
  __syncthreads();
#pragma unroll
  for (int it = 0; it < 16; ++it){
    int i = base + it * 256 + threadIdx.x;
    if (i < n) offs[i] = vals[it * 256 + threadIdx.x];
  }
}

// phase 2 of CSR build: within one bucket, counting-sort by exact dst using LDS cursors
__global__ __launch_bounds__(256) void k_csrfill(const int2* __restrict__ pair, const int* __restrict__ offs,
                                                 int* __restrict__ csr_src, int n){
  __shared__ int cur[512];
  int node0 = blockIdx.x << 9;
  int nn = min(512, n - node0);
  for (int i = threadIdx.x; i < nn; i += 256) cur[i] = offs[node0 + i];
  __syncthreads();
  int j0 = offs[node0];
  int j1 = offs[min(node0 + 512, n)];
  for (int j = j0 + threadIdx.x; j < j1; j += 256){
    int2 e = pair[j];
    int p = atomicAdd(&cur[e.y - node0], 1);
    csr_src[p] = e.x;
  }
}

// ---------------- SpMM layer1 (unroll x4 for MLP): agg[n,128] = sum x[s,:]*dout_s[s] ----
__global__ __launch_bounds__(256) void k_spmm1(const float* __restrict__ x,
    const int* __restrict__ offs, const int* __restrict__ csr_src,
    const float* __restrict__ dout_s, float* __restrict__ agg, int n_nodes){
  int node = (blockIdx.x * blockDim.x + threadIdx.x) >> 6;
  int lane = threadIdx.x & 63;
  if (node >= n_nodes) return;
  int j0 = offs[node], j1 = offs[node + 1];
  const float2* xp = (const float2*)x;
  float2 acc = make_float2(0.f, 0.f);
  int j = j0;
  for (; j + 4 <= j1; j += 4){
    int s0 = csr_src[j + 0];
    int s1 = csr_src[j + 1];
    int s2 = csr_src[j + 2];
    int s3 = csr_src[j + 3];
    float c0 = dout_s[s0];
    float c1 = dout_s[s1];
    float c2 = dout_s[s2];
    float c3 = dout_s[s3];
    float2 v0 = xp[(size_t)s0 * 64 + lane];
    float2 v1 = xp[(size_t)s1 * 64 + lane];
    float2 v2 = xp[(size_t)s2 * 64 + lane];
    float2 v3 = xp[(size_t)s3 * 64 + lane];
    acc.x = fmaf(v0.x, c0, acc.x); acc.y = fmaf(v0.y, c0, acc.y);
    acc.x = fmaf(v1.x, c1, acc.x); acc.y = fmaf(v1.y, c1, acc.y);
    acc.x = fmaf(v2.x, c2, acc.x); acc.y = fmaf(v2.y, c2, acc.y);
    acc.x = fmaf(v3.x, c3, acc.x); acc.y = fmaf(v3.y, c3, acc.y);
  }
  for (; j < j1; ++j){
    int s = csr_src[j];
    float sc = dout_s[s];
    float2 v = xp[(size_t)s * 64 + lane];
    acc.x = fmaf(v.x, sc, acc.x);
    acc.y = fmaf(v.y, sc, acc.y);
  }
  ((float2*)agg)[(size_t)node * 64 + lane] = acc;
}

// ---------------- SpMM layer2 (unroll x4) + epilogue: h2 = relu(Agg(t2)*din + b2) ----
__global__ __launch_bounds__(256) void k_spmm2(const float* __restrict__ t2,
    const int* __restrict__ offs, const int* __restrict__ csr_src,
    const float* __restrict__ din_s, const float* __restrict__ b2,
    float* __restrict__ h2, int n_nodes){
  int node = (blockIdx.x * blockDim.x + threadIdx.x) >> 6;
  int lane = threadIdx.x & 63;
  if (node >= n_nodes) return;
  int j0 = offs[node], j1 = offs[node + 1];
  float acc = 0.f;
  int j = j0;
  for (; j + 4 <= j1; j += 4){
    int s0 = csr_src[j + 0];
    int s1 = csr_src[j + 1];
    int s2 = csr_src[j + 2];
    int s3 = csr_src[j + 3];
    float v0 = t2[(size_t)s0 * 64 + lane];
    float v1 = t2[(size_t)s1 * 64 + lane];
    float v2 = t2[(size_t)s2 * 64 + lane];
    float v3 = t2[(size_t)s3 * 64 + lane];
    acc += v0 + v1 + v2 + v3;
  }
  for (; j < j1; ++j) acc += t2[(size_t)csr_src[j] * 64 + lane];
  h2[(size_t)node * 64 + lane] = fmaxf(fmaf(acc, din_s[node], b2[lane]), 0.f);
}

// ---------------- tiled fp32 GEMM, optional A-row-scale on load, optional relu(x*rowscale+bias) epilogue ----
template<int BM, int BN, int BK, int TM, int TN, bool SCALE_A, bool EPI>
__global__ __launch_bounds__(256) void gemm_fused(
    const float* __restrict__ A, const float* __restrict__ B, float* __restrict__ C,
    int M, int N, int K,
    const float* __restrict__ rowScaleA,
    const float* __restrict__ rowScaleC, const float* __restrict__ bias){
  constexpr int THREADS = (BM / TM) * (BN / TN);
  static_assert(THREADS == 256, "block must be 256");
  __shared__ float As[BK][BM + 4];
  __shared__ float Bs[BK][BN + 4];
  int tid = threadIdx.x;
  int bm0 = blockIdx.x * BM;
  int bn0 = blockIdx.y * BN;
  int tx = tid % (BN / TN);
  int ty = tid / (BN / TN);
  float acc[TM][TN] = {};
  constexpr int A_LOADS = BM * BK / (4 * THREADS);
  constexpr int B_LOADS = BN * BK / (4 * THREADS);
  for (int k0 = 0; k0 < K; k0 += BK){
#pragma unroll
    for (int l = 0; l < A_LOADS; ++l){
      int i = tid + l * THREADS;
      int row = i / (BK / 4);
      int k4  = i % (BK / 4);
      float4 v = make_float4(0.f, 0.f, 0.f, 0.f);
      int gr = bm0 + row;
      if (gr < M){
        v = *(const float4*)(A + (size_t)gr * K + k0 + k4 * 4);
        if constexpr (SCALE_A){
          float s = rowScaleA[gr];
          v.x *= s; v.y *= s; v.z *= s; v.w *= s;
        }
      }
      As[k4 * 4 + 0][row] = v.x;
      As[k4 * 4 + 1][row] = v.y;
      As[k4 * 4 + 2][row] = v.z;
      As[k4 * 4 + 3][row] = v.w;
    }
#pragma unroll
    for (int l = 0; l < B_LOADS; ++l){
      int i = tid + l * THREADS;
      int k  = i / (BN / 4);
      int n4 = i % (BN / 4);
      float4 v = *(const float4*)(B + (size_t)(k0 + k) * N + bn0 + n4 * 4);
      *(float4*)&Bs[k][n4 * 4] = v;
    }
    __syncthreads();
#pragma unroll
    for (int k = 0; k < BK; ++k){
      float a[TM], b[TN];
#pragma unroll
      for (int i = 0; i < TM; ++i) a[i] = As[k][ty * TM + i];
#pragma unroll
      for (int j = 0; j < TN; ++j) b[j] = Bs[k][tx * TN + j];
#pragma unroll
      for (int i = 0; i < TM; ++i)
#pragma unroll
        for (int j = 0; j < TN; ++j)
          acc[i][j] = fmaf(a[i], b[j], acc[i][j]);
    }
    __syncthreads();
  }
#pragma unroll
  for (int i = 0; i < TM; ++i){
    int gr = bm0 + ty * TM + i;
    if (gr >= M) break;
    float rs = 1.0f;
    if constexpr (EPI) rs = rowScaleC[gr];
#pragma unroll
    for (int j = 0; j < TN; ++j){
      int gc = bn0 + tx * TN + j;
      float cv = acc[i][j];
      if constexpr (EPI) cv = fmaxf(fmaf(cv, rs, bias[gc]), 0.f);
      C[(size_t)gr * N + gc] = cv;
    }
  }
}

// ---------------- per-graph mean-pool (sorted graph ids): segmented accumulate + atomic flush ----
__global__ __launch_bounds__(256) void k_pool(const float* __restrict__ h2, const int* __restrict__ gids,
                                              float* __restrict__ sums, int* __restrict__ cnts, int n_nodes){
  int wave = (blockIdx.x * blockDim.x + threadIdx.x) >> 6;
  int lane = threadIdx.x & 63;
  int base = wave * 64;
  if (base >= n_nodes) return;
  int endn = min(base + 64, n_nodes);
  float acc = 0.f;
  int cur = -1, len = 0;
  for (int i = base; i < endn; ++i){
    int g = gids[i];                         // wave-uniform
    float v = h2[(size_t)i * 64 + lane];
    if (g != cur){
      if (cur >= 0){
        atomicAdd(&sums[(size_t)cur * 64 + lane], acc);
        if (lane == 0) atomicAdd(&cnts[cur], len);
      }
      cur = g; acc = 0.f; len = 0;
    }
    acc += v; len++;
  }
  atomicAdd(&sums[(size_t)cur * 64 + lane], acc);
  if (lane == 0) atomicAdd(&cnts[cur], len);
}

// ---------------- classifier: hg = sums/cnt; 4 linear layers; out 512x2 ----------------
__global__ __launch_bounds__(256) void k_classifier(const float* __restrict__ sums, const int* __restrict__ cnts,
    const float* __restrict__ Wc1, const float* __restrict__ bc1,
    const float* __restrict__ Wc2, const float* __restrict__ bc2,
    const float* __restrict__ Wc3, const float* __restrict__ bc3,
    const float* __restrict__ Wc4, const float* __restrict__ bc4,
    float* __restrict__ out){
  __shared__ float w1[64 * 18], w2[18 * 12], w3[12 * 6], w4[6 * 2];
  __shared__ float B1[18], B2[12], B3[6], B4[2];
  int tid = threadIdx.x;
  for (int i = tid; i < 64 * 18; i += 256) w1[i] = Wc1[i];
  for (int i = tid; i < 18 * 12; i += 256) w2[i] = Wc2[i];
  for (int i = tid; i < 12 * 6;  i += 256) w3[i] = Wc3[i];
  for (int i = tid; i < 6 * 2;   i += 256) w4[i] = Wc4[i];
  if (tid < 18) B1[tid] = bc1[tid];
  if (tid < 12) B2[tid] = bc2[tid];
  if (tid < 6)  B3[tid] = bc3[tid];
  if (tid < 2)  B4[tid] = bc4[tid];
  __syncthreads();
  int g = blockIdx.x * 256 + tid;
  float cnt = fmaxf((float)cnts[g], 1.0f);
  float h[64];
#pragma unroll
  for (int f = 0; f < 64; ++f) h[f] = sums[(size_t)g * 64 + f] / cnt;
  float t1[18];
#pragma unroll
  for (int j = 0; j < 18; ++j){
    float s = B1[j];
    for (int f = 0; f < 64; ++f) s = fmaf(h[f], w1[f * 18 + j], s);
    t1[j] = s;
  }
  float t2[12];
#pragma unroll
  for (int j = 0; j < 12; ++j){
    float s = B2[j];
    for (int f = 0; f < 18; ++f) s = fmaf(t1[f], w2[f * 12 + j], s);
    t2[j] = s;
  }
  float t3[6];
#pragma unroll
  for (int j = 0; j < 6; ++j){
    float s = B3[j];
    for (int f = 0; f < 12; ++f) s = fmaf(t2[f], w3[f * 6 + j], s);
    t3[j] = s;
  }
#pragma unroll
  for (int j = 0; j < 2; ++j){
    float s = B4[j];
    for (int f = 0; f < 6; ++f) s = fmaf(t3[f], w4[f * 2 + j], s);
    out[(size_t)g * 2 + j] = s;
  }
}

extern "C" void kernel_launch(void* const* d_in, const int* in_sizes, int n_in,
                              void* d_out, int out_size, void* d_ws, size_t ws_size,
                              hipStream_t stream){
  const float* x   = (const float*)d_in[0];
  const int*   src = (const int*)d_in[1];
  const int*   dst = (const int*)d_in[2];
  const int*   gid = (const int*)d_in[3];
  const float* W1  = (const float*)d_in[4];
  const float* b1  = (const float*)d_in[5];
  const float* W2  = (const float*)d_in[6];
  const float* b2  = (const float*)d_in[7];
  const float* Wc1 = (const float*)d_in[8];
  const float* bc1 = (const float*)d_in[9];
  const float* Wc2 = (const float*)d_in[10];
  const float* bc2 = (const float*)d_in[11];
  const float* Wc3 = (const float*)d_in[12];
  const float* bc3 = (const float*)d_in[13];
  const float* Wc4 = (const float*)d_in[14];
  const float* bc4 = (const float*)d_in[15];
  float* out = (float*)d_out;

  const int n_nodes = in_sizes[3];
  const int n_edges = in_sizes[1];
  const int F1 = 256, F2 = 64;
  const int NB = (n_nodes + 511) >> 9;   // 512-node buckets (must be <= 256)

  // workspace layout
  char* w = (char*)d_ws;
  size_t o = 0;
  auto alloc = [&](size_t bytes) -> char* {
    char* p = w + o;
    o = align_up(o + bytes, 256);
    return p;
  };
  // ---- zero-initialized region ----
  int*   bcnt_src  = (int*)  alloc((size_t)NB * 4);
  int*   bcnt_dst  = (int*)  alloc((size_t)NB * 4);
  float* sums      = (float*)alloc((size_t)NGRAPHS * F2 * 4);
  int*   cnts      = (int*)  alloc((size_t)NGRAPHS * 4);
  size_t zero_bytes = o;
  // ---- rest ----
  int*   base_src  = (int*)  alloc((size_t)NB * 4);
  int*   cur_src   = (int*)  alloc((size_t)NB * 4);
  int*   base_dst  = (int*)  alloc((size_t)NB * 4);
  int*   cur_dst   = (int*)  alloc((size_t)NB * 4);
  int*   deg_in    = (int*)  alloc((size_t)n_nodes * 4);
  float* dout_s    = (float*)alloc((size_t)n_nodes * 4);
  float* din_s     = (float*)alloc((size_t)n_nodes * 4);
  int*   offs      = (int*)  alloc((size_t)(n_nodes + 1) * 4);
  int*   block_sums= (int*)  alloc((size_t)64 * 4);
  int*   csr_src   = (int*)  alloc((size_t)n_edges * 4);
  float* agg       = (float*)alloc((size_t)n_nodes * 128 * 4);   // layer1 aggregation (K=128)
  float* h1        = (float*)alloc((size_t)n_nodes * F1 * 4);    // layer1 output (256)
  // aliases inside agg (consumed before spmm1 writes agg)
  int2*  pairD = (int2*)agg;                              // n_edges int2 = 12.8 MB
  int*   srcS  = (int*)(agg + (size_t)n_edges * 2);       // n_edges int  =  6.4 MB
  float* t2buf = agg;            // reuse: GEMM2 output (64 wide) after agg is consumed
  float* h2    = h1;             // reuse: layer2 output after h1 is consumed

  hipMemsetAsync(d_ws, 0, zero_bytes, stream);

  // bucketed degree + CSR preprocessing (no scattered global atomics anywhere)
  k_bincount   <<<512, 256, 0, stream>>>(src, dst, bcnt_src, bcnt_dst, n_edges, NB);
  k_bucket_scan<<<1, 256, 0, stream>>>(bcnt_src, bcnt_dst, base_src, cur_src, base_dst, cur_dst, NB);
  {
    int nb1 = 100;
    int chunk = (n_edges + nb1 - 1) / nb1;
    k_binscatter<<<nb1, 256, 0, stream>>>(src, dst, cur_dst, cur_src, pairD, srcS, n_edges, chunk);
  }
  k_bucket_hist_dst<<<NB, 256, 0, stream>>>(pairD, base_dst, deg_in, din_s, NB, n_nodes, n_edges);
  k_bucket_hist_src<<<NB, 256, 0, stream>>>(srcS, base_src, dout_s, NB, n_nodes, n_edges);

  // 3-phase device-wide exclusive scan of deg_in -> offs  (offs[b*512] == base_dst[b])
  int nscan_blocks = (n_nodes + 4095) / 4096;
  k_scan_partial  <<<nscan_blocks, 256, 0, stream>>>(deg_in, block_sums, n_nodes);
  k_scan_blocksums<<<1, 64, 0, stream>>>(block_sums, nscan_blocks, offs, n_nodes);
  k_scan_write    <<<nscan_blocks, 256, 0, stream>>>(deg_in, block_sums, offs, n_nodes);

  k_csrfill<<<NB, 256, 0, stream>>>(pairD, offs, csr_src, n_nodes);

  // layer 1: agg = Agg(x * dout); h1 = relu((agg @ W1) * din + b1)
  {
    long long threads = (long long)n_nodes * 64;
    k_spmm1<<<(int)((threads + 255) / 256), 256, 0, stream>>>(x, offs, csr_src, dout_s, agg, n_nodes);
    dim3 g1((n_nodes + 127) / 128, F1 / 128);
    gemm_fused<128, 128, 16, 8, 8, false, true><<<g1, 256, 0, stream>>>(
        agg, W1, h1, n_nodes, F1, 128, nullptr, din_s, b1);
  }
  // layer 2: t2 = (h1 * dout) @ W2; h2 = relu(Agg(t2) * din + b2)
  {
    dim3 g2((n_nodes + 127) / 128, 1);
    gemm_fused<128, 64, 16, 8, 4, true, false><<<g2, 256, 0, stream>>>(
        h1, W2, t2buf, n_nodes, F2, F1, dout_s, nullptr, nullptr);
    long long threads = (long long)n_nodes * 64;
    k_spmm2<<<(int)((threads + 255) / 256), 256, 0, stream>>>(t2buf, offs, csr_src, din_s, b2, h2, n_nodes);
  }
  // pooling + classifier
  {
    int pool_waves = (n_nodes + 63) / 64;
    long long threads = (long long)pool_waves * 64;
    k_pool<<<(int)((threads + 255) / 256), 256, 0, stream>>>(h2, gid, sums, cnts, n_nodes);
    k_classifier<<<NGRAPHS / 256, 256, 0, stream>>>(sums, cnts, Wc1, bc1, Wc2, bc2, Wc3, bc3, Wc4, bc4, out);
  }
}

// Round 6
// 595.824 us; speedup vs baseline: 1.7958x; 1.0189x over previous
//
#include <hip/hip_runtime.h>
#include <cstdint>
#include <cstddef>

#define NGRAPHS 512

static inline size_t align_up(size_t x, size_t a){ return (x + a - 1) & ~(a - 1); }

// ================= bucketed graph preprocessing =================
// buckets = contiguous 512-node ranges; NB = ceil(n/512) must be <= 256.

__global__ __launch_bounds__(256) void k_bincount(const int* __restrict__ src, const int* __restrict__ dst,
                                                  int* __restrict__ bcnt_src, int* __restrict__ bcnt_dst,
                                                  int n_edges, int NB){
  __shared__ int cs[256], cd[256];
  cs[threadIdx.x] = 0; cd[threadIdx.x] = 0;
  __syncthreads();
  int stride = gridDim.x * 256;
  for (int e = blockIdx.x * 256 + threadIdx.x; e < n_edges; e += stride){
    atomicAdd(&cs[src[e] >> 9], 1);
    atomicAdd(&cd[dst[e] >> 9], 1);
  }
  __syncthreads();
  if (threadIdx.x < NB){
    int a = cs[threadIdx.x], b = cd[threadIdx.x];
    if (a) atomicAdd(&bcnt_src[threadIdx.x], a);
    if (b) atomicAdd(&bcnt_dst[threadIdx.x], b);
  }
}

__global__ __launch_bounds__(256) void k_bucket_scan(const int* __restrict__ bcnt_src, const int* __restrict__ bcnt_dst,
                                                     int* __restrict__ base_src, int* __restrict__ cur_src,
                                                     int* __restrict__ base_dst, int* __restrict__ cur_dst, int NB){
  __shared__ int s1[256], s2[256];
  int tid = threadIdx.x;
  int v1 = (tid < NB) ? bcnt_src[tid] : 0;
  int v2 = (tid < NB) ? bcnt_dst[tid] : 0;
  s1[tid] = v1; s2[tid] = v2;
  __syncthreads();
  for (int off = 1; off < 256; off <<= 1){
    int t1 = (tid >= off) ? s1[tid - off] : 0;
    int t2 = (tid >= off) ? s2[tid - off] : 0;
    __syncthreads();
    s1[tid] += t1; s2[tid] += t2;
    __syncthreads();
  }
  if (tid < NB){
    base_src[tid] = s1[tid] - v1; cur_src[tid] = s1[tid] - v1;
    base_dst[tid] = s2[tid] - v2; cur_dst[tid] = s2[tid] - v2;
  }
}

__global__ __launch_bounds__(256) void k_binscatter(const int* __restrict__ src, const int* __restrict__ dst,
                                                    int* __restrict__ rsv_d, int* __restrict__ rsv_s,
                                                    int2* __restrict__ pairD, int* __restrict__ srcS,
                                                    int n_edges, int chunk){
  __shared__ int cntd[256], curd[256], cnts_[256], curs[256];
  int e0 = blockIdx.x * chunk;
  int e1 = min(e0 + chunk, n_edges);
  cntd[threadIdx.x] = 0; cnts_[threadIdx.x] = 0;
  __syncthreads();
  for (int e = e0 + threadIdx.x; e < e1; e += 256){
    atomicAdd(&cntd[dst[e] >> 9], 1);
    atomicAdd(&cnts_[src[e] >> 9], 1);
  }
  __syncthreads();
  int cd = cntd[threadIdx.x], cs = cnts_[threadIdx.x];
  curd[threadIdx.x] = cd ? atomicAdd(&rsv_d[threadIdx.x], cd) : 0;
  curs[threadIdx.x] = cs ? atomicAdd(&rsv_s[threadIdx.x], cs) : 0;
  __syncthreads();
  for (int e = e0 + threadIdx.x; e < e1; e += 256){
    int s = src[e], d = dst[e];
    int pd = atomicAdd(&curd[d >> 9], 1);
    pairD[pd] = make_int2(s, d);
    int ps = atomicAdd(&curs[s >> 9], 1);
    srcS[ps] = s;
  }
}

__global__ __launch_bounds__(256) void k_bucket_hist_dst(const int2* __restrict__ pairD, const int* __restrict__ base_dst,
                                                         int* __restrict__ deg_in, float* __restrict__ din_s,
                                                         int NB, int n, int n_edges){
  __shared__ int cnt[512];
  int b = blockIdx.x;
  int node0 = b << 9;
  int nn = min(512, n - node0);
  for (int i = threadIdx.x; i < 512; i += 256) cnt[i] = 0;
  __syncthreads();
  int j0 = base_dst[b];
  int j1 = (b + 1 < NB) ? base_dst[b + 1] : n_edges;
  for (int j = j0 + threadIdx.x; j < j1; j += 256)
    atomicAdd(&cnt[pairD[j].y - node0], 1);
  __syncthreads();
  for (int i = threadIdx.x; i < nn; i += 256){
    int c = cnt[i];
    deg_in[node0 + i] = c;
    din_s[node0 + i] = 1.0f / sqrtf((float)max(c, 1));
  }
}

__global__ __launch_bounds__(256) void k_bucket_hist_src(const int* __restrict__ srcS, const int* __restrict__ base_src,
                                                         float* __restrict__ dout_s, int NB, int n, int n_edges){
  __shared__ int cnt[512];
  int b = blockIdx.x;
  int node0 = b << 9;
  int nn = min(512, n - node0);
  for (int i = threadIdx.x; i < 512; i += 256) cnt[i] = 0;
  __syncthreads();
  int j0 = base_src[b];
  int j1 = (b + 1 < NB) ? base_src[b + 1] : n_edges;
  for (int j = j0 + threadIdx.x; j < j1; j += 256)
    atomicAdd(&cnt[srcS[j] - node0], 1);
  __syncthreads();
  for (int i = threadIdx.x; i < nn; i += 256)
    dout_s[node0 + i] = 1.0f / sqrtf((float)max(cnt[i], 1));
}

// ---------------- 3-phase device-wide exclusive scan (coalesced) ----------------
__global__ __launch_bounds__(256) void k_scan_partial(const int* __restrict__ deg,
                                                      int* __restrict__ bs, int n){
  __shared__ int sm[256];
  int base = blockIdx.x * 4096;
  int s = 0;
#pragma unroll
  for (int it = 0; it < 16; ++it){
    int i = base + it * 256 + threadIdx.x;
    if (i < n) s += deg[i];
  }
  sm[threadIdx.x] = s;
  __syncthreads();
  for (int off = 128; off > 0; off >>= 1){
    if (threadIdx.x < off) sm[threadIdx.x] += sm[threadIdx.x + off];
    __syncthreads();
  }
  if (threadIdx.x == 0) bs[blockIdx.x] = sm[0];
}

__global__ __launch_bounds__(64) void k_scan_blocksums(int* __restrict__ bs, int nb,
                                                       int* __restrict__ offs, int n){
  __shared__ int sm[64];
  int tid = threadIdx.x;
  int v = (tid < nb) ? bs[tid] : 0;
  sm[tid] = v;
  __syncthreads();
  for (int off = 1; off < 64; off <<= 1){
    int t = (tid >= off) ? sm[tid - off] : 0;
    __syncthreads();
    sm[tid] += t;
    __syncthreads();
  }
  if (tid < nb) bs[tid] = sm[tid] - v;   // exclusive
  if (tid == 63) offs[n] = sm[63];       // grand total (= n_edges)
}

__global__ __launch_bounds__(256) void k_scan_write(const int* __restrict__ deg,
    const int* __restrict__ bs, int* __restrict__ offs, int n){
  __shared__ int vals[4096];
  __shared__ int tsum[256];
  int base = blockIdx.x * 4096;
#pragma unroll
  for (int it = 0; it < 16; ++it){
    int i = base + it * 256 + threadIdx.x;
    vals[it * 256 + threadIdx.x] = (i < n) ? deg[i] : 0;
  }
  __syncthreads();
  int t0 = threadIdx.x * 16;
  int loc[16];
  int s = 0;
#pragma unroll
  for (int k = 0; k < 16; ++k){ loc[k] = s; s += vals[t0 + k]; }
  tsum[threadIdx.x] = s;
  __syncthreads();
  for (int off = 1; off < 256; off <<= 1){
    int t = (threadIdx.x >= off) ? tsum[threadIdx.x - off] : 0;
    __syncthreads();
    tsum[threadIdx.x] += t;
    __syncthreads();
  }
  int pre = tsum[threadIdx.x] - s + bs[blockIdx.x];
  __syncthreads();
#pragma unroll
  for (int k = 0; k < 16; ++k) vals[t0 + k] = pre + loc[k];
  __syncthreads();
#pragma unroll
  for (int it = 0; it < 16; ++it){
    int i = base + it * 256 + threadIdx.x;
    if (i < n) offs[i] = vals[it * 256 + threadIdx.x];
  }
}

// phase 2 of CSR build: within one bucket, counting-sort by exact dst using LDS cursors
__global__ __launch_bounds__(256) void k_csrfill(const int2* __restrict__ pair, const int* __restrict__ offs,
                                                 int* __restrict__ csr_src, int n){
  __shared__ int cur[512];
  int node0 = blockIdx.x << 9;
  int nn = min(512, n - node0);
  for (int i = threadIdx.x; i < nn; i += 256) cur[i] = offs[node0 + i];
  __syncthreads();
  int j0 = offs[node0];
  int j1 = offs[min(node0 + 512, n)];
  for (int j = j0 + threadIdx.x; j < j1; j += 256){
    int2 e = pair[j];
    int p = atomicAdd(&cur[e.y - node0], 1);
    csr_src[p] = e.x;
  }
}

// ---------------- SpMM layer1: 2 nodes/wave, float4 lanes (32x16B=512B row), unroll x4 ----
__global__ __launch_bounds__(256) void k_spmm1(const float* __restrict__ x,
    const int* __restrict__ offs, const int* __restrict__ csr_src,
    const float* __restrict__ dout_s, float* __restrict__ agg, int n_nodes){
  int node = (blockIdx.x * blockDim.x + threadIdx.x) >> 5;   // half-wave per node
  int lane = threadIdx.x & 31;
  if (node >= n_nodes) return;
  int j0 = offs[node], j1 = offs[node + 1];
  const float4* xp = (const float4*)x;                        // row = 32 x float4
  float4 acc = make_float4(0.f, 0.f, 0.f, 0.f);
  int j = j0;
  for (; j + 4 <= j1; j += 4){
    int s0 = csr_src[j + 0];
    int s1 = csr_src[j + 1];
    int s2 = csr_src[j + 2];
    int s3 = csr_src[j + 3];
    float c0 = dout_s[s0];
    float c1 = dout_s[s1];
    float c2 = dout_s[s2];
    float c3 = dout_s[s3];
    float4 v0 = xp[(size_t)s0 * 32 + lane];
    float4 v1 = xp[(size_t)s1 * 32 + lane];
    float4 v2 = xp[(size_t)s2 * 32 + lane];
    float4 v3 = xp[(size_t)s3 * 32 + lane];
    acc.x = fmaf(v0.x, c0, acc.x); acc.y = fmaf(v0.y, c0, acc.y);
    acc.z = fmaf(v0.z, c0, acc.z); acc.w = fmaf(v0.w, c0, acc.w);
    acc.x = fmaf(v1.x, c1, acc.x); acc.y = fmaf(v1.y, c1, acc.y);
    acc.z = fmaf(v1.z, c1, acc.z); acc.w = fmaf(v1.w, c1, acc.w);
    acc.x = fmaf(v2.x, c2, acc.x); acc.y = fmaf(v2.y, c2, acc.y);
    acc.z = fmaf(v2.z, c2, acc.z); acc.w = fmaf(v2.w, c2, acc.w);
    acc.x = fmaf(v3.x, c3, acc.x); acc.y = fmaf(v3.y, c3, acc.y);
    acc.z = fmaf(v3.z, c3, acc.z); acc.w = fmaf(v3.w, c3, acc.w);
  }
  for (; j < j1; ++j){
    int s = csr_src[j];
    float sc = dout_s[s];
    float4 v = xp[(size_t)s * 32 + lane];
    acc.x = fmaf(v.x, sc, acc.x); acc.y = fmaf(v.y, sc, acc.y);
    acc.z = fmaf(v.z, sc, acc.z); acc.w = fmaf(v.w, sc, acc.w);
  }
  ((float4*)agg)[(size_t)node * 32 + lane] = acc;
}

// ---------------- SpMM layer2: 2 nodes/wave, float2 lanes (32x8B=256B row), unroll x4 ----
__global__ __launch_bounds__(256) void k_spmm2(const float* __restrict__ t2,
    const int* __restrict__ offs, const int* __restrict__ csr_src,
    const float* __restrict__ din_s, const float* __restrict__ b2,
    float* __restrict__ h2, int n_nodes){
  int node = (blockIdx.x * blockDim.x + threadIdx.x) >> 5;
  int lane = threadIdx.x & 31;
  if (node >= n_nodes) return;
  int j0 = offs[node], j1 = offs[node + 1];
  const float2* tp = (const float2*)t2;                       // row = 32 x float2
  float2 acc = make_float2(0.f, 0.f);
  int j = j0;
  for (; j + 4 <= j1; j += 4){
    int s0 = csr_src[j + 0];
    int s1 = csr_src[j + 1];
    int s2 = csr_src[j + 2];
    int s3 = csr_src[j + 3];
    float2 v0 = tp[(size_t)s0 * 32 + lane];
    float2 v1 = tp[(size_t)s1 * 32 + lane];
    float2 v2 = tp[(size_t)s2 * 32 + lane];
    float2 v3 = tp[(size_t)s3 * 32 + lane];
    acc.x += v0.x + v1.x + v2.x + v3.x;
    acc.y += v0.y + v1.y + v2.y + v3.y;
  }
  for (; j < j1; ++j){
    float2 v = tp[(size_t)csr_src[j] * 32 + lane];
    acc.x += v.x; acc.y += v.y;
  }
  float ds = din_s[node];
  float2 bb = ((const float2*)b2)[lane];
  float2 r;
  r.x = fmaxf(fmaf(acc.x, ds, bb.x), 0.f);
  r.y = fmaxf(fmaf(acc.y, ds, bb.y), 0.f);
  ((float2*)h2)[(size_t)node * 32 + lane] = r;
}

// ---------------- tiled fp32 GEMM, optional A-row-scale on load, optional relu(x*rowscale+bias) epilogue ----
template<int BM, int BN, int BK, int TM, int TN, bool SCALE_A, bool EPI>
__global__ __launch_bounds__(256) void gemm_fused(
    const float* __restrict__ A, const float* __restrict__ B, float* __restrict__ C,
    int M, int N, int K,
    const float* __restrict__ rowScaleA,
    const float* __restrict__ rowScaleC, const float* __restrict__ bias){
  constexpr int THREADS = (BM / TM) * (BN / TN);
  static_assert(THREADS == 256, "block must be 256");
  __shared__ float As[BK][BM + 4];
  __shared__ float Bs[BK][BN + 4];
  int tid = threadIdx.x;
  int bm0 = blockIdx.x * BM;
  int bn0 = blockIdx.y * BN;
  int tx = tid % (BN / TN);
  int ty = tid / (BN / TN);
  float acc[TM][TN] = {};
  constexpr int A_LOADS = BM * BK / (4 * THREADS);
  constexpr int B_LOADS = BN * BK / (4 * THREADS);
  for (int k0 = 0; k0 < K; k0 += BK){
#pragma unroll
    for (int l = 0; l < A_LOADS; ++l){
      int i = tid + l * THREADS;
      int row = i / (BK / 4);
      int k4  = i % (BK / 4);
      float4 v = make_float4(0.f, 0.f, 0.f, 0.f);
      int gr = bm0 + row;
      if (gr < M){
        v = *(const float4*)(A + (size_t)gr * K + k0 + k4 * 4);
        if constexpr (SCALE_A){
          float s = rowScaleA[gr];
          v.x *= s; v.y *= s; v.z *= s; v.w *= s;
        }
      }
      As[k4 * 4 + 0][row] = v.x;
      As[k4 * 4 + 1][row] = v.y;
      As[k4 * 4 + 2][row] = v.z;
      As[k4 * 4 + 3][row] = v.w;
    }
#pragma unroll
    for (int l = 0; l < B_LOADS; ++l){
      int i = tid + l * THREADS;
      int k  = i / (BN / 4);
      int n4 = i % (BN / 4);
      float4 v = *(const float4*)(B + (size_t)(k0 + k) * N + bn0 + n4 * 4);
      *(float4*)&Bs[k][n4 * 4] = v;
    }
    __syncthreads();
#pragma unroll
    for (int k = 0; k < BK; ++k){
      float a[TM], b[TN];
#pragma unroll
      for (int i = 0; i < TM; ++i) a[i] = As[k][ty * TM + i];
#pragma unroll
      for (int j = 0; j < TN; ++j) b[j] = Bs[k][tx * TN + j];
#pragma unroll
      for (int i = 0; i < TM; ++i)
#pragma unroll
        for (int j = 0; j < TN; ++j)
          acc[i][j] = fmaf(a[i], b[j], acc[i][j]);
    }
    __syncthreads();
  }
#pragma unroll
  for (int i = 0; i < TM; ++i){
    int gr = bm0 + ty * TM + i;
    if (gr >= M) break;
    float rs = 1.0f;
    if constexpr (EPI) rs = rowScaleC[gr];
#pragma unroll
    for (int j = 0; j < TN; ++j){
      int gc = bn0 + tx * TN + j;
      float cv = acc[i][j];
      if constexpr (EPI) cv = fmaxf(fmaf(cv, rs, bias[gc]), 0.f);
      C[(size_t)gr * N + gc] = cv;
    }
  }
}

// ---------------- per-graph mean-pool (sorted graph ids): segmented accumulate + atomic flush ----
__global__ __launch_bounds__(256) void k_pool(const float* __restrict__ h2, const int* __restrict__ gids,
                                              float* __restrict__ sums, int* __restrict__ cnts, int n_nodes){
  int wave = (blockIdx.x * blockDim.x + threadIdx.x) >> 6;
  int lane = threadIdx.x & 63;
  int base = wave * 64;
  if (base >= n_nodes) return;
  int endn = min(base + 64, n_nodes);
  float acc = 0.f;
  int cur = -1, len = 0;
  for (int i = base; i < endn; ++i){
    int g = gids[i];                         // wave-uniform
    float v = h2[(size_t)i * 64 + lane];
    if (g != cur){
      if (cur >= 0){
        atomicAdd(&sums[(size_t)cur * 64 + lane], acc);
        if (lane == 0) atomicAdd(&cnts[cur], len);
      }
      cur = g; acc = 0.f; len = 0;
    }
    acc += v; len++;
  }
  atomicAdd(&sums[(size_t)cur * 64 + lane], acc);
  if (lane == 0) atomicAdd(&cnts[cur], len);
}

// ---------------- classifier: hg = sums/cnt; 4 linear layers; out 512x2 ----------------
__global__ __launch_bounds__(256) void k_classifier(const float* __restrict__ sums, const int* __restrict__ cnts,
    const float* __restrict__ Wc1, const float* __restrict__ bc1,
    const float* __restrict__ Wc2, const float* __restrict__ bc2,
    const float* __restrict__ Wc3, const float* __restrict__ bc3,
    const float* __restrict__ Wc4, const float* __restrict__ bc4,
    float* __restrict__ out){
  __shared__ float w1[64 * 18], w2[18 * 12], w3[12 * 6], w4[6 * 2];
  __shared__ float B1[18], B2[12], B3[6], B4[2];
  int tid = threadIdx.x;
  for (int i = tid; i < 64 * 18; i += 256) w1[i] = Wc1[i];
  for (int i = tid; i < 18 * 12; i += 256) w2[i] = Wc2[i];
  for (int i = tid; i < 12 * 6;  i += 256) w3[i] = Wc3[i];
  for (int i = tid; i < 6 * 2;   i += 256) w4[i] = Wc4[i];
  if (tid < 18) B1[tid] = bc1[tid];
  if (tid < 12) B2[tid] = bc2[tid];
  if (tid < 6)  B3[tid] = bc3[tid];
  if (tid < 2)  B4[tid] = bc4[tid];
  __syncthreads();
  int g = blockIdx.x * 256 + tid;
  float cnt = fmaxf((float)cnts[g], 1.0f);
  float h[64];
#pragma unroll
  for (int f = 0; f < 64; ++f) h[f] = sums[(size_t)g * 64 + f] / cnt;
  float t1[18];
#pragma unroll
  for (int j = 0; j < 18; ++j){
    float s = B1[j];
    for (int f = 0; f < 64; ++f) s = fmaf(h[f], w1[f * 18 + j], s);
    t1[j] = s;
  }
  float t2[12];
#pragma unroll
  for (int j = 0; j < 12; ++j){
    float s = B2[j];
    for (int f = 0; f < 18; ++f) s = fmaf(t1[f], w2[f * 12 + j], s);
    t2[j] = s;
  }
  float t3[6];
#pragma unroll
  for (int j = 0; j < 6; ++j){
    float s = B3[j];
    for (int f = 0; f < 12; ++f) s = fmaf(t2[f], w3[f * 6 + j], s);
    t3[j] = s;
  }
#pragma unroll
  for (int j = 0; j < 2; ++j){
    float s = B4[j];
    for (int f = 0; f < 6; ++f) s = fmaf(t3[f], w4[f * 2 + j], s);
    out[(size_t)g * 2 + j] = s;
  }
}

extern "C" void kernel_launch(void* const* d_in, const int* in_sizes, int n_in,
                              void* d_out, int out_size, void* d_ws, size_t ws_size,
                              hipStream_t stream){
  const float* x   = (const float*)d_in[0];
  const int*   src = (const int*)d_in[1];
  const int*   dst = (const int*)d_in[2];
  const int*   gid = (const int*)d_in[3];
  const float* W1  = (const float*)d_in[4];
  const float* b1  = (const float*)d_in[5];
  const float* W2  = (const float*)d_in[6];
  const float* b2  = (const float*)d_in[7];
  const float* Wc1 = (const float*)d_in[8];
  const float* bc1 = (const float*)d_in[9];
  const float* Wc2 = (const float*)d_in[10];
  const float* bc2 = (const float*)d_in[11];
  const float* Wc3 = (const float*)d_in[12];
  const float* bc3 = (const float*)d_in[13];
  const float* Wc4 = (const float*)d_in[14];
  const float* bc4 = (const float*)d_in[15];
  float* out = (float*)d_out;

  const int n_nodes = in_sizes[3];
  const int n_edges = in_sizes[1];
  const int F1 = 256, F2 = 64;
  const int NB = (n_nodes + 511) >> 9;   // 512-node buckets (must be <= 256)

  // workspace layout
  char* w = (char*)d_ws;
  size_t o = 0;
  auto alloc = [&](size_t bytes) -> char* {
    char* p = w + o;
    o = align_up(o + bytes, 256);
    return p;
  };
  // ---- zero-initialized region ----
  int*   bcnt_src  = (int*)  alloc((size_t)NB * 4);
  int*   bcnt_dst  = (int*)  alloc((size_t)NB * 4);
  float* sums      = (float*)alloc((size_t)NGRAPHS * F2 * 4);
  int*   cnts      = (int*)  alloc((size_t)NGRAPHS * 4);
  size_t zero_bytes = o;
  // ---- rest ----
  int*   base_src  = (int*)  alloc((size_t)NB * 4);
  int*   cur_src   = (int*)  alloc((size_t)NB * 4);
  int*   base_dst  = (int*)  alloc((size_t)NB * 4);
  int*   cur_dst   = (int*)  alloc((size_t)NB * 4);
  int*   deg_in    = (int*)  alloc((size_t)n_nodes * 4);
  float* dout_s    = (float*)alloc((size_t)n_nodes * 4);
  float* din_s     = (float*)alloc((size_t)n_nodes * 4);
  int*   offs      = (int*)  alloc((size_t)(n_nodes + 1) * 4);
  int*   block_sums= (int*)  alloc((size_t)64 * 4);
  int*   csr_src   = (int*)  alloc((size_t)n_edges * 4);
  float* agg       = (float*)alloc((size_t)n_nodes * 128 * 4);   // layer1 aggregation (K=128)
  float* h1        = (float*)alloc((size_t)n_nodes * F1 * 4);    // layer1 output (256)
  // aliases inside agg (consumed before spmm1 writes agg)
  int2*  pairD = (int2*)agg;                              // n_edges int2 = 12.8 MB
  int*   srcS  = (int*)(agg + (size_t)n_edges * 2);       // n_edges int  =  6.4 MB
  float* t2buf = agg;            // reuse: GEMM2 output (64 wide) after agg is consumed
  float* h2    = h1;             // reuse: layer2 output after h1 is consumed

  hipMemsetAsync(d_ws, 0, zero_bytes, stream);

  // bucketed degree + CSR preprocessing (no scattered global atomics anywhere)
  k_bincount   <<<512, 256, 0, stream>>>(src, dst, bcnt_src, bcnt_dst, n_edges, NB);
  k_bucket_scan<<<1, 256, 0, stream>>>(bcnt_src, bcnt_dst, base_src, cur_src, base_dst, cur_dst, NB);
  {
    int nb1 = 100;
    int chunk = (n_edges + nb1 - 1) / nb1;
    k_binscatter<<<nb1, 256, 0, stream>>>(src, dst, cur_dst, cur_src, pairD, srcS, n_edges, chunk);
  }
  k_bucket_hist_dst<<<NB, 256, 0, stream>>>(pairD, base_dst, deg_in, din_s, NB, n_nodes, n_edges);
  k_bucket_hist_src<<<NB, 256, 0, stream>>>(srcS, base_src, dout_s, NB, n_nodes, n_edges);

  // 3-phase device-wide exclusive scan of deg_in -> offs  (offs[b*512] == base_dst[b])
  int nscan_blocks = (n_nodes + 4095) / 4096;
  k_scan_partial  <<<nscan_blocks, 256, 0, stream>>>(deg_in, block_sums, n_nodes);
  k_scan_blocksums<<<1, 64, 0, stream>>>(block_sums, nscan_blocks, offs, n_nodes);
  k_scan_write    <<<nscan_blocks, 256, 0, stream>>>(deg_in, block_sums, offs, n_nodes);

  k_csrfill<<<NB, 256, 0, stream>>>(pairD, offs, csr_src, n_nodes);

  // layer 1: agg = Agg(x * dout); h1 = relu((agg @ W1) * din + b1)
  {
    long long threads = (long long)n_nodes * 32;
    k_spmm1<<<(int)((threads + 255) / 256), 256, 0, stream>>>(x, offs, csr_src, dout_s, agg, n_nodes);
    dim3 g1((n_nodes + 127) / 128, F1 / 128);
    gemm_fused<128, 128, 16, 8, 8, false, true><<<g1, 256, 0, stream>>>(
        agg, W1, h1, n_nodes, F1, 128, nullptr, din_s, b1);
  }
  // layer 2: t2 = (h1 * dout) @ W2; h2 = relu(Agg(t2) * din + b2)
  {
    dim3 g2((n_nodes + 127) / 128, 1);
    gemm_fused<128, 64, 16, 8, 4, true, false><<<g2, 256, 0, stream>>>(
        h1, W2, t2buf, n_nodes, F2, F1, dout_s, nullptr, nullptr);
    long long threads = (long long)n_nodes * 32;
    k_spmm2<<<(int)((threads + 255) / 256), 256, 0, stream>>>(t2buf, offs, csr_src, din_s, b2, h2, n_nodes);
  }
  // pooling + classifier
  {
    int pool_waves = (n_nodes + 63) / 64;
    long long threads = (long long)pool_waves * 64;
    k_pool<<<(int)((threads + 255) / 256), 256, 0, stream>>>(h2, gid, sums, cnts, n_nodes);
    k_classifier<<<NGRAPHS / 256, 256, 0, stream>>>(sums, cnts, Wc1, bc1, Wc2, bc2, Wc3, bc3, Wc4, bc4, out);
  }
}

// Round 7
// 524.813 us; speedup vs baseline: 2.0388x; 1.1353x over previous
//
#include <hip/hip_runtime.h>
#include <cstdint>
#include <cstddef>

#define NGRAPHS 512

static inline size_t align_up(size_t x, size_t a){ return (x + a - 1) & ~(a - 1); }

// ---------------- bf16 helpers ----------------
__device__ __forceinline__ unsigned short f2bf(float f){
  unsigned int u = __float_as_uint(f);
  u += 0x7FFFu + ((u >> 16) & 1u);          // round-to-nearest-even
  return (unsigned short)(u >> 16);
}
__device__ __forceinline__ float bf2f(unsigned short s){
  return __uint_as_float(((unsigned int)s) << 16);
}

typedef __attribute__((ext_vector_type(8))) short bf16x8;
typedef __attribute__((ext_vector_type(4))) float f32x4;

// ================= bucketed graph preprocessing =================
__global__ __launch_bounds__(256) void k_bincount(const int* __restrict__ src, const int* __restrict__ dst,
                                                  int* __restrict__ bcnt_src, int* __restrict__ bcnt_dst,
                                                  int n_edges, int NB){
  __shared__ int cs[256], cd[256];
  cs[threadIdx.x] = 0; cd[threadIdx.x] = 0;
  __syncthreads();
  int stride = gridDim.x * 256;
  for (int e = blockIdx.x * 256 + threadIdx.x; e < n_edges; e += stride){
    atomicAdd(&cs[src[e] >> 9], 1);
    atomicAdd(&cd[dst[e] >> 9], 1);
  }
  __syncthreads();
  if (threadIdx.x < NB){
    int a = cs[threadIdx.x], b = cd[threadIdx.x];
    if (a) atomicAdd(&bcnt_src[threadIdx.x], a);
    if (b) atomicAdd(&bcnt_dst[threadIdx.x], b);
  }
}

__global__ __launch_bounds__(256) void k_bucket_scan(const int* __restrict__ bcnt_src, const int* __restrict__ bcnt_dst,
                                                     int* __restrict__ base_src, int* __restrict__ cur_src,
                                                     int* __restrict__ base_dst, int* __restrict__ cur_dst, int NB){
  __shared__ int s1[256], s2[256];
  int tid = threadIdx.x;
  int v1 = (tid < NB) ? bcnt_src[tid] : 0;
  int v2 = (tid < NB) ? bcnt_dst[tid] : 0;
  s1[tid] = v1; s2[tid] = v2;
  __syncthreads();
  for (int off = 1; off < 256; off <<= 1){
    int t1 = (tid >= off) ? s1[tid - off] : 0;
    int t2 = (tid >= off) ? s2[tid - off] : 0;
    __syncthreads();
    s1[tid] += t1; s2[tid] += t2;
    __syncthreads();
  }
  if (tid < NB){
    base_src[tid] = s1[tid] - v1; cur_src[tid] = s1[tid] - v1;
    base_dst[tid] = s2[tid] - v2; cur_dst[tid] = s2[tid] - v2;
  }
}

__global__ __launch_bounds__(256) void k_binscatter(const int* __restrict__ src, const int* __restrict__ dst,
                                                    int* __restrict__ rsv_d, int* __restrict__ rsv_s,
                                                    int2* __restrict__ pairD, int* __restrict__ srcS,
                                                    int n_edges, int chunk){
  __shared__ int cntd[256], curd[256], cnts_[256], curs[256];
  int e0 = blockIdx.x * chunk;
  int e1 = min(e0 + chunk, n_edges);
  cntd[threadIdx.x] = 0; cnts_[threadIdx.x] = 0;
  __syncthreads();
  for (int e = e0 + threadIdx.x; e < e1; e += 256){
    atomicAdd(&cntd[dst[e] >> 9], 1);
    atomicAdd(&cnts_[src[e] >> 9], 1);
  }
  __syncthreads();
  int cd = cntd[threadIdx.x], cs = cnts_[threadIdx.x];
  curd[threadIdx.x] = cd ? atomicAdd(&rsv_d[threadIdx.x], cd) : 0;
  curs[threadIdx.x] = cs ? atomicAdd(&rsv_s[threadIdx.x], cs) : 0;
  __syncthreads();
  for (int e = e0 + threadIdx.x; e < e1; e += 256){
    int s = src[e], d = dst[e];
    int pd = atomicAdd(&curd[d >> 9], 1);
    pairD[pd] = make_int2(s, d);
    int ps = atomicAdd(&curs[s >> 9], 1);
    srcS[ps] = s;
  }
}

__global__ __launch_bounds__(256) void k_bucket_hist_dst(const int2* __restrict__ pairD, const int* __restrict__ base_dst,
                                                         int* __restrict__ deg_in, float* __restrict__ din_s,
                                                         int NB, int n, int n_edges){
  __shared__ int cnt[512];
  int b = blockIdx.x;
  int node0 = b << 9;
  int nn = min(512, n - node0);
  for (int i = threadIdx.x; i < 512; i += 256) cnt[i] = 0;
  __syncthreads();
  int j0 = base_dst[b];
  int j1 = (b + 1 < NB) ? base_dst[b + 1] : n_edges;
  for (int j = j0 + threadIdx.x; j < j1; j += 256)
    atomicAdd(&cnt[pairD[j].y - node0], 1);
  __syncthreads();
  for (int i = threadIdx.x; i < nn; i += 256){
    int c = cnt[i];
    deg_in[node0 + i] = c;
    din_s[node0 + i] = 1.0f / sqrtf((float)max(c, 1));
  }
}

__global__ __launch_bounds__(256) void k_bucket_hist_src(const int* __restrict__ srcS, const int* __restrict__ base_src,
                                                         float* __restrict__ dout_s, int NB, int n, int n_edges){
  __shared__ int cnt[512];
  int b = blockIdx.x;
  int node0 = b << 9;
  int nn = min(512, n - node0);
  for (int i = threadIdx.x; i < 512; i += 256) cnt[i] = 0;
  __syncthreads();
  int j0 = base_src[b];
  int j1 = (b + 1 < NB) ? base_src[b + 1] : n_edges;
  for (int j = j0 + threadIdx.x; j < j1; j += 256)
    atomicAdd(&cnt[srcS[j] - node0], 1);
  __syncthreads();
  for (int i = threadIdx.x; i < nn; i += 256)
    dout_s[node0 + i] = 1.0f / sqrtf((float)max(cnt[i], 1));
}

// ---------------- 3-phase device-wide exclusive scan ----------------
__global__ __launch_bounds__(256) void k_scan_partial(const int* __restrict__ deg,
                                                      int* __restrict__ bs, int n){
  __shared__ int sm[256];
  int base = blockIdx.x * 4096;
  int s = 0;
#pragma unroll
  for (int it = 0; it < 16; ++it){
    int i = base + it * 256 + threadIdx.x;
    if (i < n) s += deg[i];
  }
  sm[threadIdx.x] = s;
  __syncthreads();
  for (int off = 128; off > 0; off >>= 1){
    if (threadIdx.x < off) sm[threadIdx.x] += sm[threadIdx.x + off];
    __syncthreads();
  }
  if (threadIdx.x == 0) bs[blockIdx.x] = sm[0];
}

__global__ __launch_bounds__(64) void k_scan_blocksums(int* __restrict__ bs, int nb,
                                                       int* __restrict__ offs, int n){
  __shared__ int sm[64];
  int tid = threadIdx.x;
  int v = (tid < nb) ? bs[tid] : 0;
  sm[tid] = v;
  __syncthreads();
  for (int off = 1; off < 64; off <<= 1){
    int t = (tid >= off) ? sm[tid - off] : 0;
    __syncthreads();
    sm[tid] += t;
    __syncthreads();
  }
  if (tid < nb) bs[tid] = sm[tid] - v;
  if (tid == 63) offs[n] = sm[63];
}

__global__ __launch_bounds__(256) void k_scan_write(const int* __restrict__ deg,
    const int* __restrict__ bs, int* __restrict__ offs, int n){
  __shared__ int vals[4096];
  __shared__ int tsum[256];
  int base = blockIdx.x * 4096;
#pragma unroll
  for (int it = 0; it < 16; ++it){
    int i = base + it * 256 + threadIdx.x;
    vals[it * 256 + threadIdx.x] = (i < n) ? deg[i] : 0;
  }
  __syncthreads();
  int t0 = threadIdx.x * 16;
  int loc[16];
  int s = 0;
#pragma unroll
  for (int k = 0; k < 16; ++k){ loc[k] = s; s += vals[t0 + k]; }
  tsum[threadIdx.x] = s;
  __syncthreads();
  for (int off = 1; off < 256; off <<= 1){
    int t = (threadIdx.x >= off) ? tsum[threadIdx.x - off] : 0;
    __syncthreads();
    tsum[threadIdx.x] += t;
    __syncthreads();
  }
  int pre = tsum[threadIdx.x] - s + bs[blockIdx.x];
  __syncthreads();
#pragma unroll
  for (int k = 0; k < 16; ++k) vals[t0 + k] = pre + loc[k];
  __syncthreads();
#pragma unroll
  for (int it = 0; it < 16; ++it){
    int i = base + it * 256 + threadIdx.x;
    if (i < n) offs[i] = vals[it * 256 + threadIdx.x];
  }
}

__global__ __launch_bounds__(256) void k_csrfill(const int2* __restrict__ pair, const int* __restrict__ offs,
                                                 int* __restrict__ csr_src, int n){
  __shared__ int cur[512];
  int node0 = blockIdx.x << 9;
  int nn = min(512, n - node0);
  for (int i = threadIdx.x; i < nn; i += 256) cur[i] = offs[node0 + i];
  __syncthreads();
  int j0 = offs[node0];
  int j1 = offs[min(node0 + 512, n)];
  for (int j = j0 + threadIdx.x; j < j1; j += 256){
    int2 e = pair[j];
    int p = atomicAdd(&cur[e.y - node0], 1);
    csr_src[p] = e.x;
  }
}

// ---------------- weight prep: fp32 W[K][N] -> bf16 Wt[N][K] ----------------
__global__ void k_prepw(const float* __restrict__ W, unsigned short* __restrict__ Wt,
                        int K, int N, int total){
  int t = blockIdx.x * blockDim.x + threadIdx.x;
  if (t < total){
    int k = t / N, n = t % N;
    Wt[(size_t)n * K + k] = f2bf(W[t]);
  }
}

// ---------------- SpMM layer1: 2 nodes/wave, float4 lanes, unroll x4 ----
__global__ __launch_bounds__(256) void k_spmm1(const float* __restrict__ x,
    const int* __restrict__ offs, const int* __restrict__ csr_src,
    const float* __restrict__ dout_s, float* __restrict__ agg, int n_nodes){
  int node = (blockIdx.x * blockDim.x + threadIdx.x) >> 5;
  int lane = threadIdx.x & 31;
  if (node >= n_nodes) return;
  int j0 = offs[node], j1 = offs[node + 1];
  const float4* xp = (const float4*)x;
  float4 acc = make_float4(0.f, 0.f, 0.f, 0.f);
  int j = j0;
  for (; j + 4 <= j1; j += 4){
    int s0 = csr_src[j + 0];
    int s1 = csr_src[j + 1];
    int s2 = csr_src[j + 2];
    int s3 = csr_src[j + 3];
    float c0 = dout_s[s0];
    float c1 = dout_s[s1];
    float c2 = dout_s[s2];
    float c3 = dout_s[s3];
    float4 v0 = xp[(size_t)s0 * 32 + lane];
    float4 v1 = xp[(size_t)s1 * 32 + lane];
    float4 v2 = xp[(size_t)s2 * 32 + lane];
    float4 v3 = xp[(size_t)s3 * 32 + lane];
    acc.x = fmaf(v0.x, c0, acc.x); acc.y = fmaf(v0.y, c0, acc.y);
    acc.z = fmaf(v0.z, c0, acc.z); acc.w = fmaf(v0.w, c0, acc.w);
    acc.x = fmaf(v1.x, c1, acc.x); acc.y = fmaf(v1.y, c1, acc.y);
    acc.z = fmaf(v1.z, c1, acc.z); acc.w = fmaf(v1.w, c1, acc.w);
    acc.x = fmaf(v2.x, c2, acc.x); acc.y = fmaf(v2.y, c2, acc.y);
    acc.z = fmaf(v2.z, c2, acc.z); acc.w = fmaf(v2.w, c2, acc.w);
    acc.x = fmaf(v3.x, c3, acc.x); acc.y = fmaf(v3.y, c3, acc.y);
    acc.z = fmaf(v3.z, c3, acc.z); acc.w = fmaf(v3.w, c3, acc.w);
  }
  for (; j < j1; ++j){
    int s = csr_src[j];
    float sc = dout_s[s];
    float4 v = xp[(size_t)s * 32 + lane];
    acc.x = fmaf(v.x, sc, acc.x); acc.y = fmaf(v.y, sc, acc.y);
    acc.z = fmaf(v.z, sc, acc.z); acc.w = fmaf(v.w, sc, acc.w);
  }
  ((float4*)agg)[(size_t)node * 32 + lane] = acc;
}

// ---------------- SpMM layer2 on bf16 t2: 2 nodes/wave, uint(2xbf16) lanes ----
__global__ __launch_bounds__(256) void k_spmm2(const unsigned short* __restrict__ t2,
    const int* __restrict__ offs, const int* __restrict__ csr_src,
    const float* __restrict__ din_s, const float* __restrict__ b2,
    float* __restrict__ h2, int n_nodes){
  int node = (blockIdx.x * blockDim.x + threadIdx.x) >> 5;
  int lane = threadIdx.x & 31;
  if (node >= n_nodes) return;
  int j0 = offs[node], j1 = offs[node + 1];
  const unsigned int* tp = (const unsigned int*)t2;     // row = 32 uints = 64 bf16
  float ax = 0.f, ay = 0.f;
  int j = j0;
  for (; j + 4 <= j1; j += 4){
    int s0 = csr_src[j + 0];
    int s1 = csr_src[j + 1];
    int s2 = csr_src[j + 2];
    int s3 = csr_src[j + 3];
    unsigned int v0 = tp[(size_t)s0 * 32 + lane];
    unsigned int v1 = tp[(size_t)s1 * 32 + lane];
    unsigned int v2 = tp[(size_t)s2 * 32 + lane];
    unsigned int v3 = tp[(size_t)s3 * 32 + lane];
    ax += bf2f((unsigned short)(v0 & 0xffff)) + bf2f((unsigned short)(v1 & 0xffff))
        + bf2f((unsigned short)(v2 & 0xffff)) + bf2f((unsigned short)(v3 & 0xffff));
    ay += bf2f((unsigned short)(v0 >> 16)) + bf2f((unsigned short)(v1 >> 16))
        + bf2f((unsigned short)(v2 >> 16)) + bf2f((unsigned short)(v3 >> 16));
  }
  for (; j < j1; ++j){
    unsigned int v = tp[(size_t)csr_src[j] * 32 + lane];
    ax += bf2f((unsigned short)(v & 0xffff));
    ay += bf2f((unsigned short)(v >> 16));
  }
  float ds = din_s[node];
  float2 bb = ((const float2*)b2)[lane];
  float2 r;
  r.x = fmaxf(fmaf(ax, ds, bb.x), 0.f);
  r.y = fmaxf(fmaf(ay, ds, bb.y), 0.f);
  ((float2*)h2)[(size_t)node * 32 + lane] = r;
}

// ---------------- MFMA bf16 GEMM: C = epi( A @ Bt^T ) ----------------
// A: fp32 or bf16, row-major [M][K], optional per-row scale on load.
// Bt: bf16, n-major [N][K] (pre-transposed weights).
// Block tile 128x64, 4 waves as 2x2 (wave tile 64x32), BK=128 LDS staging.
// Layouts (v_mfma_f32_16x16x32_bf16): A[m=lane&15][k=quad*8+j], B[n=lane&15][k=quad*8+j],
// C/D: col=lane&15, row=quad*4+reg.  LDS pad: +8 shorts -> uniform 8 words/bank on b128.
template<bool A_BF16, bool C_BF16, bool SCALE_A, bool EPI>
__global__ __launch_bounds__(256) void gemm_mfma(
    const void* __restrict__ Ap, const unsigned short* __restrict__ Bt, void* __restrict__ Cp,
    int M, int N, int K,
    const float* __restrict__ rowScaleA, const float* __restrict__ rowScaleC,
    const float* __restrict__ bias){
  constexpr int BM = 128, BN = 64, BK = 128, LDA = 136;
  __shared__ __align__(16) unsigned short As[BM * LDA];
  __shared__ __align__(16) unsigned short Bs[BN * LDA];
  int tid = threadIdx.x;
  int bm0 = blockIdx.x * BM;
  int bn0 = blockIdx.y * BN;
  int wid = tid >> 6, lane = tid & 63;
  int wm = (wid >> 1) * 64, wn = (wid & 1) * 32;
  int quad = lane >> 4, l16 = lane & 15;
  f32x4 acc[4][2];
#pragma unroll
  for (int t = 0; t < 4; ++t)
#pragma unroll
    for (int u = 0; u < 2; ++u) acc[t][u] = f32x4{0.f, 0.f, 0.f, 0.f};

  for (int k0 = 0; k0 < K; k0 += BK){
    // stage A (BM x BK) -> bf16 LDS
#pragma unroll
    for (int it = 0; it < 16; ++it){
      int i = tid + it * 256;
      int m = i >> 5, c4 = i & 31;
      int gr = bm0 + m;
      uint2 pk = make_uint2(0u, 0u);
      if (gr < M){
        if constexpr (!A_BF16){
          const float* A = (const float*)Ap;
          float4 v = *(const float4*)(A + (size_t)gr * K + k0 + c4 * 4);
          if constexpr (SCALE_A){ float s = rowScaleA[gr]; v.x *= s; v.y *= s; v.z *= s; v.w *= s; }
          pk.x = (unsigned)f2bf(v.x) | ((unsigned)f2bf(v.y) << 16);
          pk.y = (unsigned)f2bf(v.z) | ((unsigned)f2bf(v.w) << 16);
        } else {
          const unsigned short* A = (const unsigned short*)Ap;
          uint2 raw = *(const uint2*)(A + (size_t)gr * K + k0 + c4 * 4);
          if constexpr (SCALE_A){
            float s = rowScaleA[gr];
            float a0 = bf2f((unsigned short)(raw.x & 0xffff)) * s;
            float a1 = bf2f((unsigned short)(raw.x >> 16)) * s;
            float a2 = bf2f((unsigned short)(raw.y & 0xffff)) * s;
            float a3 = bf2f((unsigned short)(raw.y >> 16)) * s;
            pk.x = (unsigned)f2bf(a0) | ((unsigned)f2bf(a1) << 16);
            pk.y = (unsigned)f2bf(a2) | ((unsigned)f2bf(a3) << 16);
          } else {
            pk = raw;
          }
        }
      }
      *(uint2*)&As[m * LDA + c4 * 4] = pk;
    }
    // stage B (BN x BK) from Bt[n][k] (already bf16, already n-major)
#pragma unroll
    for (int it = 0; it < 8; ++it){
      int i = tid + it * 256;
      int n = i >> 5, c4 = i & 31;
      uint2 v = *(const uint2*)(Bt + (size_t)(bn0 + n) * K + k0 + c4 * 4);
      *(uint2*)&Bs[n * LDA + c4 * 4] = v;
    }
    __syncthreads();
#pragma unroll
    for (int kc = 0; kc < 4; ++kc){
      bf16x8 af[4], bfr[2];
#pragma unroll
      for (int t = 0; t < 4; ++t)
        af[t] = *(const bf16x8*)&As[(wm + t * 16 + l16) * LDA + kc * 32 + quad * 8];
#pragma unroll
      for (int u = 0; u < 2; ++u)
        bfr[u] = *(const bf16x8*)&Bs[(wn + u * 16 + l16) * LDA + kc * 32 + quad * 8];
#pragma unroll
      for (int t = 0; t < 4; ++t)
#pragma unroll
        for (int u = 0; u < 2; ++u)
          acc[t][u] = __builtin_amdgcn_mfma_f32_16x16x32_bf16(af[t], bfr[u], acc[t][u], 0, 0, 0);
    }
    __syncthreads();
  }
  // epilogue
  float bv[2] = {0.f, 0.f};
  if constexpr (EPI){ bv[0] = bias[bn0 + wn + l16]; bv[1] = bias[bn0 + wn + 16 + l16]; }
#pragma unroll
  for (int t = 0; t < 4; ++t){
#pragma unroll
    for (int r = 0; r < 4; ++r){
      int gr = bm0 + wm + t * 16 + quad * 4 + r;
      if (gr < M){
        float rs = 1.f;
        if constexpr (EPI) rs = rowScaleC[gr];
#pragma unroll
        for (int u = 0; u < 2; ++u){
          int gc = bn0 + wn + u * 16 + l16;
          float cv = acc[t][u][r];
          if constexpr (EPI) cv = fmaxf(fmaf(cv, rs, bv[u]), 0.f);
          if constexpr (C_BF16) ((unsigned short*)Cp)[(size_t)gr * N + gc] = f2bf(cv);
          else                  ((float*)Cp)[(size_t)gr * N + gc] = cv;
        }
      }
    }
  }
}

// ---------------- per-graph mean-pool ----------------
__global__ __launch_bounds__(256) void k_pool(const float* __restrict__ h2, const int* __restrict__ gids,
                                              float* __restrict__ sums, int* __restrict__ cnts, int n_nodes){
  int wave = (blockIdx.x * blockDim.x + threadIdx.x) >> 6;
  int lane = threadIdx.x & 63;
  int base = wave * 64;
  if (base >= n_nodes) return;
  int endn = min(base + 64, n_nodes);
  float acc = 0.f;
  int cur = -1, len = 0;
  for (int i = base; i < endn; ++i){
    int g = gids[i];
    float v = h2[(size_t)i * 64 + lane];
    if (g != cur){
      if (cur >= 0){
        atomicAdd(&sums[(size_t)cur * 64 + lane], acc);
        if (lane == 0) atomicAdd(&cnts[cur], len);
      }
      cur = g; acc = 0.f; len = 0;
    }
    acc += v; len++;
  }
  atomicAdd(&sums[(size_t)cur * 64 + lane], acc);
  if (lane == 0) atomicAdd(&cnts[cur], len);
}

// ---------------- classifier ----------------
__global__ __launch_bounds__(256) void k_classifier(const float* __restrict__ sums, const int* __restrict__ cnts,
    const float* __restrict__ Wc1, const float* __restrict__ bc1,
    const float* __restrict__ Wc2, const float* __restrict__ bc2,
    const float* __restrict__ Wc3, const float* __restrict__ bc3,
    const float* __restrict__ Wc4, const float* __restrict__ bc4,
    float* __restrict__ out){
  __shared__ float w1[64 * 18], w2[18 * 12], w3[12 * 6], w4[6 * 2];
  __shared__ float B1[18], B2[12], B3[6], B4[2];
  int tid = threadIdx.x;
  for (int i = tid; i < 64 * 18; i += 256) w1[i] = Wc1[i];
  for (int i = tid; i < 18 * 12; i += 256) w2[i] = Wc2[i];
  for (int i = tid; i < 12 * 6;  i += 256) w3[i] = Wc3[i];
  for (int i = tid; i < 6 * 2;   i += 256) w4[i] = Wc4[i];
  if (tid < 18) B1[tid] = bc1[tid];
  if (tid < 12) B2[tid] = bc2[tid];
  if (tid < 6)  B3[tid] = bc3[tid];
  if (tid < 2)  B4[tid] = bc4[tid];
  __syncthreads();
  int g = blockIdx.x * 256 + tid;
  float cnt = fmaxf((float)cnts[g], 1.0f);
  float h[64];
#pragma unroll
  for (int f = 0; f < 64; ++f) h[f] = sums[(size_t)g * 64 + f] / cnt;
  float t1[18];
#pragma unroll
  for (int j = 0; j < 18; ++j){
    float s = B1[j];
    for (int f = 0; f < 64; ++f) s = fmaf(h[f], w1[f * 18 + j], s);
    t1[j] = s;
  }
  float t2[12];
#pragma unroll
  for (int j = 0; j < 12; ++j){
    float s = B2[j];
    for (int f = 0; f < 18; ++f) s = fmaf(t1[f], w2[f * 12 + j], s);
    t2[j] = s;
  }
  float t3[6];
#pragma unroll
  for (int j = 0; j < 6; ++j){
    float s = B3[j];
    for (int f = 0; f < 12; ++f) s = fmaf(t2[f], w3[f * 6 + j], s);
    t3[j] = s;
  }
#pragma unroll
  for (int j = 0; j < 2; ++j){
    float s = B4[j];
    for (int f = 0; f < 6; ++f) s = fmaf(t3[f], w4[f * 2 + j], s);
    out[(size_t)g * 2 + j] = s;
  }
}

extern "C" void kernel_launch(void* const* d_in, const int* in_sizes, int n_in,
                              void* d_out, int out_size, void* d_ws, size_t ws_size,
                              hipStream_t stream){
  const float* x   = (const float*)d_in[0];
  const int*   src = (const int*)d_in[1];
  const int*   dst = (const int*)d_in[2];
  const int*   gid = (const int*)d_in[3];
  const float* W1  = (const float*)d_in[4];
  const float* b1  = (const float*)d_in[5];
  const float* W2  = (const float*)d_in[6];
  const float* b2  = (const float*)d_in[7];
  const float* Wc1 = (const float*)d_in[8];
  const float* bc1 = (const float*)d_in[9];
  const float* Wc2 = (const float*)d_in[10];
  const float* bc2 = (const float*)d_in[11];
  const float* Wc3 = (const float*)d_in[12];
  const float* bc3 = (const float*)d_in[13];
  const float* Wc4 = (const float*)d_in[14];
  const float* bc4 = (const float*)d_in[15];
  float* out = (float*)d_out;

  const int n_nodes = in_sizes[3];
  const int n_edges = in_sizes[1];
  const int F1 = 256, F2 = 64;
  const int NB = (n_nodes + 511) >> 9;

  char* w = (char*)d_ws;
  size_t o = 0;
  auto alloc = [&](size_t bytes) -> char* {
    char* p = w + o;
    o = align_up(o + bytes, 256);
    return p;
  };
  // ---- zero-initialized region ----
  int*   bcnt_src  = (int*)  alloc((size_t)NB * 4);
  int*   bcnt_dst  = (int*)  alloc((size_t)NB * 4);
  float* sums      = (float*)alloc((size_t)NGRAPHS * F2 * 4);
  int*   cnts      = (int*)  alloc((size_t)NGRAPHS * 4);
  size_t zero_bytes = o;
  // ---- rest ----
  int*   base_src  = (int*)  alloc((size_t)NB * 4);
  int*   cur_src   = (int*)  alloc((size_t)NB * 4);
  int*   base_dst  = (int*)  alloc((size_t)NB * 4);
  int*   cur_dst   = (int*)  alloc((size_t)NB * 4);
  int*   deg_in    = (int*)  alloc((size_t)n_nodes * 4);
  float* dout_s    = (float*)alloc((size_t)n_nodes * 4);
  float* din_s     = (float*)alloc((size_t)n_nodes * 4);
  int*   offs      = (int*)  alloc((size_t)(n_nodes + 1) * 4);
  int*   block_sums= (int*)  alloc((size_t)64 * 4);
  int*   csr_src   = (int*)  alloc((size_t)n_edges * 4);
  unsigned short* Wt1 = (unsigned short*)alloc((size_t)256 * 128 * 2);  // W1^T bf16 [N=256][K=128]
  unsigned short* Wt2 = (unsigned short*)alloc((size_t)64 * 256 * 2);   // W2^T bf16 [N=64][K=256]
  float* agg       = (float*)alloc((size_t)n_nodes * 128 * 4);          // 51.2 MB
  unsigned short* h1b = (unsigned short*)alloc((size_t)n_nodes * F1 * 2); // h1 bf16, 51.2 MB
  // aliases
  int2*  pairD = (int2*)agg;                               // consumed before spmm1
  int*   srcS  = (int*)(agg + (size_t)n_edges * 2);
  unsigned short* t2b = (unsigned short*)agg;              // gemm2 out (bf16), after agg consumed
  float* h2    = (float*)h1b;                              // spmm2 out (fp32), after h1 consumed

  hipMemsetAsync(d_ws, 0, zero_bytes, stream);

  // weight prep (independent)
  k_prepw<<<(128 * 256 + 255) / 256, 256, 0, stream>>>(W1, Wt1, 128, 256, 128 * 256);
  k_prepw<<<(256 * 64 + 255) / 256, 256, 0, stream>>>(W2, Wt2, 256, 64, 256 * 64);

  // bucketed degree + CSR preprocessing
  k_bincount   <<<512, 256, 0, stream>>>(src, dst, bcnt_src, bcnt_dst, n_edges, NB);
  k_bucket_scan<<<1, 256, 0, stream>>>(bcnt_src, bcnt_dst, base_src, cur_src, base_dst, cur_dst, NB);
  {
    int nb1 = 100;
    int chunk = (n_edges + nb1 - 1) / nb1;
    k_binscatter<<<nb1, 256, 0, stream>>>(src, dst, cur_dst, cur_src, pairD, srcS, n_edges, chunk);
  }
  k_bucket_hist_dst<<<NB, 256, 0, stream>>>(pairD, base_dst, deg_in, din_s, NB, n_nodes, n_edges);
  k_bucket_hist_src<<<NB, 256, 0, stream>>>(srcS, base_src, dout_s, NB, n_nodes, n_edges);

  int nscan_blocks = (n_nodes + 4095) / 4096;
  k_scan_partial  <<<nscan_blocks, 256, 0, stream>>>(deg_in, block_sums, n_nodes);
  k_scan_blocksums<<<1, 64, 0, stream>>>(block_sums, nscan_blocks, offs, n_nodes);
  k_scan_write    <<<nscan_blocks, 256, 0, stream>>>(deg_in, block_sums, offs, n_nodes);

  k_csrfill<<<NB, 256, 0, stream>>>(pairD, offs, csr_src, n_nodes);

  int gx = (n_nodes + 127) / 128;
  // layer 1: agg = Agg(x * dout);  h1 = relu((agg @ W1) * din + b1)  [bf16 out]
  {
    long long threads = (long long)n_nodes * 32;
    k_spmm1<<<(int)((threads + 255) / 256), 256, 0, stream>>>(x, offs, csr_src, dout_s, agg, n_nodes);
    gemm_mfma<false, true, false, true><<<dim3(gx, F1 / 64), 256, 0, stream>>>(
        agg, Wt1, h1b, n_nodes, F1, 128, nullptr, din_s, b1);
  }
  // layer 2: t2 = (h1 * dout) @ W2  [bf16 out];  h2 = relu(Agg(t2) * din + b2)
  {
    gemm_mfma<true, true, true, false><<<dim3(gx, 1), 256, 0, stream>>>(
        h1b, Wt2, t2b, n_nodes, F2, F1, dout_s, nullptr, nullptr);
    long long threads = (long long)n_nodes * 32;
    k_spmm2<<<(int)((threads + 255) / 256), 256, 0, stream>>>(t2b, offs, csr_src, din_s, b2, h2, n_nodes);
  }
  // pooling + classifier
  {
    int pool_waves = (n_nodes + 63) / 64;
    long long threads = (long long)pool_waves * 64;
    k_pool<<<(int)((threads + 255) / 256), 256, 0, stream>>>(h2, gid, sums, cnts, n_nodes);
    k_classifier<<<NGRAPHS / 256, 256, 0, stream>>>(sums, cnts, Wc1, bc1, Wc2, bc2, Wc3, bc3, Wc4, bc4, out);
  }
}

// Round 8
// 472.333 us; speedup vs baseline: 2.2653x; 1.1111x over previous
//
#include <hip/hip_runtime.h>
#include <cstdint>
#include <cstddef>

#define NGRAPHS 512

static inline size_t align_up(size_t x, size_t a){ return (x + a - 1) & ~(a - 1); }

// ---------------- bf16 helpers ----------------
__device__ __forceinline__ unsigned short f2bf(float f){
  unsigned int u = __float_as_uint(f);
  u += 0x7FFFu + ((u >> 16) & 1u);          // round-to-nearest-even
  return (unsigned short)(u >> 16);
}
__device__ __forceinline__ float bf2f(unsigned short s){
  return __uint_as_float(((unsigned int)s) << 16);
}
__device__ __forceinline__ float bflo(unsigned int u){ return __uint_as_float(u << 16); }
__device__ __forceinline__ float bfhi(unsigned int u){ return __uint_as_float(u & 0xffff0000u); }
__device__ __forceinline__ unsigned int pack2(float a, float b){
  return (unsigned)f2bf(a) | ((unsigned)f2bf(b) << 16);
}

typedef __attribute__((ext_vector_type(8))) short bf16x8;
typedef __attribute__((ext_vector_type(4))) float f32x4;

// ================= bucketed graph preprocessing =================
__global__ __launch_bounds__(256) void k_bincount(const int* __restrict__ src, const int* __restrict__ dst,
                                                  int* __restrict__ bcnt_src, int* __restrict__ bcnt_dst,
                                                  int n_edges, int NB){
  __shared__ int cs[256], cd[256];
  cs[threadIdx.x] = 0; cd[threadIdx.x] = 0;
  __syncthreads();
  int stride = gridDim.x * 256;
  for (int e = blockIdx.x * 256 + threadIdx.x; e < n_edges; e += stride){
    atomicAdd(&cs[src[e] >> 9], 1);
    atomicAdd(&cd[dst[e] >> 9], 1);
  }
  __syncthreads();
  if (threadIdx.x < NB){
    int a = cs[threadIdx.x], b = cd[threadIdx.x];
    if (a) atomicAdd(&bcnt_src[threadIdx.x], a);
    if (b) atomicAdd(&bcnt_dst[threadIdx.x], b);
  }
}

__global__ __launch_bounds__(256) void k_bucket_scan(const int* __restrict__ bcnt_src, const int* __restrict__ bcnt_dst,
                                                     int* __restrict__ base_src, int* __restrict__ cur_src,
                                                     int* __restrict__ base_dst, int* __restrict__ cur_dst, int NB){
  __shared__ int s1[256], s2[256];
  int tid = threadIdx.x;
  int v1 = (tid < NB) ? bcnt_src[tid] : 0;
  int v2 = (tid < NB) ? bcnt_dst[tid] : 0;
  s1[tid] = v1; s2[tid] = v2;
  __syncthreads();
  for (int off = 1; off < 256; off <<= 1){
    int t1 = (tid >= off) ? s1[tid - off] : 0;
    int t2 = (tid >= off) ? s2[tid - off] : 0;
    __syncthreads();
    s1[tid] += t1; s2[tid] += t2;
    __syncthreads();
  }
  if (tid < NB){
    base_src[tid] = s1[tid] - v1; cur_src[tid] = s1[tid] - v1;
    base_dst[tid] = s2[tid] - v2; cur_dst[tid] = s2[tid] - v2;
  }
}

__global__ __launch_bounds__(256) void k_binscatter(const int* __restrict__ src, const int* __restrict__ dst,
                                                    int* __restrict__ rsv_d, int* __restrict__ rsv_s,
                                                    int2* __restrict__ pairD, int* __restrict__ srcS,
                                                    int n_edges, int chunk){
  __shared__ int cntd[256], curd[256], cnts_[256], curs[256];
  int e0 = blockIdx.x * chunk;
  int e1 = min(e0 + chunk, n_edges);
  cntd[threadIdx.x] = 0; cnts_[threadIdx.x] = 0;
  __syncthreads();
  for (int e = e0 + threadIdx.x; e < e1; e += 256){
    atomicAdd(&cntd[dst[e] >> 9], 1);
    atomicAdd(&cnts_[src[e] >> 9], 1);
  }
  __syncthreads();
  int cd = cntd[threadIdx.x], cs = cnts_[threadIdx.x];
  curd[threadIdx.x] = cd ? atomicAdd(&rsv_d[threadIdx.x], cd) : 0;
  curs[threadIdx.x] = cs ? atomicAdd(&rsv_s[threadIdx.x], cs) : 0;
  __syncthreads();
  for (int e = e0 + threadIdx.x; e < e1; e += 256){
    int s = src[e], d = dst[e];
    int pd = atomicAdd(&curd[d >> 9], 1);
    pairD[pd] = make_int2(s, d);
    int ps = atomicAdd(&curs[s >> 9], 1);
    srcS[ps] = s;
  }
}

__global__ __launch_bounds__(256) void k_bucket_hist_dst(const int2* __restrict__ pairD, const int* __restrict__ base_dst,
                                                         int* __restrict__ deg_in, float* __restrict__ din_s,
                                                         int NB, int n, int n_edges){
  __shared__ int cnt[512];
  int b = blockIdx.x;
  int node0 = b << 9;
  int nn = min(512, n - node0);
  for (int i = threadIdx.x; i < 512; i += 256) cnt[i] = 0;
  __syncthreads();
  int j0 = base_dst[b];
  int j1 = (b + 1 < NB) ? base_dst[b + 1] : n_edges;
  for (int j = j0 + threadIdx.x; j < j1; j += 256)
    atomicAdd(&cnt[pairD[j].y - node0], 1);
  __syncthreads();
  for (int i = threadIdx.x; i < nn; i += 256){
    int c = cnt[i];
    deg_in[node0 + i] = c;
    din_s[node0 + i] = 1.0f / sqrtf((float)max(c, 1));
  }
}

__global__ __launch_bounds__(256) void k_bucket_hist_src(const int* __restrict__ srcS, const int* __restrict__ base_src,
                                                         float* __restrict__ dout_s, int NB, int n, int n_edges){
  __shared__ int cnt[512];
  int b = blockIdx.x;
  int node0 = b << 9;
  int nn = min(512, n - node0);
  for (int i = threadIdx.x; i < 512; i += 256) cnt[i] = 0;
  __syncthreads();
  int j0 = base_src[b];
  int j1 = (b + 1 < NB) ? base_src[b + 1] : n_edges;
  for (int j = j0 + threadIdx.x; j < j1; j += 256)
    atomicAdd(&cnt[srcS[j] - node0], 1);
  __syncthreads();
  for (int i = threadIdx.x; i < nn; i += 256)
    dout_s[node0 + i] = 1.0f / sqrtf((float)max(cnt[i], 1));
}

// ---------------- 3-phase device-wide exclusive scan ----------------
__global__ __launch_bounds__(256) void k_scan_partial(const int* __restrict__ deg,
                                                      int* __restrict__ bs, int n){
  __shared__ int sm[256];
  int base = blockIdx.x * 4096;
  int s = 0;
#pragma unroll
  for (int it = 0; it < 16; ++it){
    int i = base + it * 256 + threadIdx.x;
    if (i < n) s += deg[i];
  }
  sm[threadIdx.x] = s;
  __syncthreads();
  for (int off = 128; off > 0; off >>= 1){
    if (threadIdx.x < off) sm[threadIdx.x] += sm[threadIdx.x + off];
    __syncthreads();
  }
  if (threadIdx.x == 0) bs[blockIdx.x] = sm[0];
}

__global__ __launch_bounds__(64) void k_scan_blocksums(int* __restrict__ bs, int nb,
                                                       int* __restrict__ offs, int n){
  __shared__ int sm[64];
  int tid = threadIdx.x;
  int v = (tid < nb) ? bs[tid] : 0;
  sm[tid] = v;
  __syncthreads();
  for (int off = 1; off < 64; off <<= 1){
    int t = (tid >= off) ? sm[tid - off] : 0;
    __syncthreads();
    sm[tid] += t;
    __syncthreads();
  }
  if (tid < nb) bs[tid] = sm[tid] - v;
  if (tid == 63) offs[n] = sm[63];
}

__global__ __launch_bounds__(256) void k_scan_write(const int* __restrict__ deg,
    const int* __restrict__ bs, int* __restrict__ offs, int n){
  __shared__ int vals[4096];
  __shared__ int tsum[256];
  int base = blockIdx.x * 4096;
#pragma unroll
  for (int it = 0; it < 16; ++it){
    int i = base + it * 256 + threadIdx.x;
    vals[it * 256 + threadIdx.x] = (i < n) ? deg[i] : 0;
  }
  __syncthreads();
  int t0 = threadIdx.x * 16;
  int loc[16];
  int s = 0;
#pragma unroll
  for (int k = 0; k < 16; ++k){ loc[k] = s; s += vals[t0 + k]; }
  tsum[threadIdx.x] = s;
  __syncthreads();
  for (int off = 1; off < 256; off <<= 1){
    int t = (threadIdx.x >= off) ? tsum[threadIdx.x - off] : 0;
    __syncthreads();
    tsum[threadIdx.x] += t;
    __syncthreads();
  }
  int pre = tsum[threadIdx.x] - s + bs[blockIdx.x];
  __syncthreads();
#pragma unroll
  for (int k = 0; k < 16; ++k) vals[t0 + k] = pre + loc[k];
  __syncthreads();
#pragma unroll
  for (int it = 0; it < 16; ++it){
    int i = base + it * 256 + threadIdx.x;
    if (i < n) offs[i] = vals[it * 256 + threadIdx.x];
  }
}

__global__ __launch_bounds__(256) void k_csrfill(const int2* __restrict__ pair, const int* __restrict__ offs,
                                                 int* __restrict__ csr_src, int n){
  __shared__ int cur[512];
  int node0 = blockIdx.x << 9;
  int nn = min(512, n - node0);
  for (int i = threadIdx.x; i < nn; i += 256) cur[i] = offs[node0 + i];
  __syncthreads();
  int j0 = offs[node0];
  int j1 = offs[min(node0 + 512, n)];
  for (int j = j0 + threadIdx.x; j < j1; j += 256){
    int2 e = pair[j];
    int p = atomicAdd(&cur[e.y - node0], 1);
    csr_src[p] = e.x;
  }
}

// ---------------- weight prep: fp32 W[K][N] -> bf16 Wt[N][K] ----------------
__global__ void k_prepw(const float* __restrict__ W, unsigned short* __restrict__ Wt,
                        int K, int N, int total){
  int t = blockIdx.x * blockDim.x + threadIdx.x;
  if (t < total){
    int k = t / N, n = t % N;
    Wt[(size_t)n * K + k] = f2bf(W[t]);
  }
}

// ---------------- x fp32 -> bf16 (packed), 4 elems/thread ----------------
__global__ __launch_bounds__(256) void k_prepx(const float* __restrict__ x, unsigned int* __restrict__ xb,
                                               long long total4){
  long long t = (long long)blockIdx.x * blockDim.x + threadIdx.x;
  if (t < total4){
    float4 v = ((const float4*)x)[t];
    xb[t * 2 + 0] = pack2(v.x, v.y);
    xb[t * 2 + 1] = pack2(v.z, v.w);
  }
}

// ---------------- SpMM layer1 on bf16 x: 2 nodes/wave, uint2 lanes (32x8B=256B row) ----
// accumulates fp32, writes agg as bf16 (it would be rounded at GEMM staging anyway)
__global__ __launch_bounds__(256) void k_spmm1(const unsigned int* __restrict__ xb,
    const int* __restrict__ offs, const int* __restrict__ csr_src,
    const float* __restrict__ dout_s, unsigned int* __restrict__ aggb, int n_nodes){
  int node = (blockIdx.x * blockDim.x + threadIdx.x) >> 5;
  int lane = threadIdx.x & 31;
  if (node >= n_nodes) return;
  int j0 = offs[node], j1 = offs[node + 1];
  const uint2* xp = (const uint2*)xb;                 // row = 32 x uint2 (4 bf16 each)
  float4 acc = make_float4(0.f, 0.f, 0.f, 0.f);
  int j = j0;
  for (; j + 4 <= j1; j += 4){
    int s0 = csr_src[j + 0];
    int s1 = csr_src[j + 1];
    int s2 = csr_src[j + 2];
    int s3 = csr_src[j + 3];
    float c0 = dout_s[s0];
    float c1 = dout_s[s1];
    float c2 = dout_s[s2];
    float c3 = dout_s[s3];
    uint2 v0 = xp[(size_t)s0 * 32 + lane];
    uint2 v1 = xp[(size_t)s1 * 32 + lane];
    uint2 v2 = xp[(size_t)s2 * 32 + lane];
    uint2 v3 = xp[(size_t)s3 * 32 + lane];
    acc.x = fmaf(bflo(v0.x), c0, acc.x); acc.y = fmaf(bfhi(v0.x), c0, acc.y);
    acc.z = fmaf(bflo(v0.y), c0, acc.z); acc.w = fmaf(bfhi(v0.y), c0, acc.w);
    acc.x = fmaf(bflo(v1.x), c1, acc.x); acc.y = fmaf(bfhi(v1.x), c1, acc.y);
    acc.z = fmaf(bflo(v1.y), c1, acc.z); acc.w = fmaf(bfhi(v1.y), c1, acc.w);
    acc.x = fmaf(bflo(v2.x), c2, acc.x); acc.y = fmaf(bfhi(v2.x), c2, acc.y);
    acc.z = fmaf(bflo(v2.y), c2, acc.z); acc.w = fmaf(bfhi(v2.y), c2, acc.w);
    acc.x = fmaf(bflo(v3.x), c3, acc.x); acc.y = fmaf(bfhi(v3.x), c3, acc.y);
    acc.z = fmaf(bflo(v3.y), c3, acc.z); acc.w = fmaf(bfhi(v3.y), c3, acc.w);
  }
  for (; j < j1; ++j){
    int s = csr_src[j];
    float sc = dout_s[s];
    uint2 v = xp[(size_t)s * 32 + lane];
    acc.x = fmaf(bflo(v.x), sc, acc.x); acc.y = fmaf(bfhi(v.x), sc, acc.y);
    acc.z = fmaf(bflo(v.y), sc, acc.z); acc.w = fmaf(bfhi(v.y), sc, acc.w);
  }
  uint2 pk;
  pk.x = pack2(acc.x, acc.y);
  pk.y = pack2(acc.z, acc.w);
  ((uint2*)aggb)[(size_t)node * 32 + lane] = pk;
}

// ---------------- SpMM layer2 on bf16 t2: 2 nodes/wave, uint(2xbf16) lanes ----
__global__ __launch_bounds__(256) void k_spmm2(const unsigned short* __restrict__ t2,
    const int* __restrict__ offs, const int* __restrict__ csr_src,
    const float* __restrict__ din_s, const float* __restrict__ b2,
    float* __restrict__ h2, int n_nodes){
  int node = (blockIdx.x * blockDim.x + threadIdx.x) >> 5;
  int lane = threadIdx.x & 31;
  if (node >= n_nodes) return;
  int j0 = offs[node], j1 = offs[node + 1];
  const unsigned int* tp = (const unsigned int*)t2;     // row = 32 uints = 64 bf16
  float ax = 0.f, ay = 0.f;
  int j = j0;
  for (; j + 4 <= j1; j += 4){
    int s0 = csr_src[j + 0];
    int s1 = csr_src[j + 1];
    int s2 = csr_src[j + 2];
    int s3 = csr_src[j + 3];
    unsigned int v0 = tp[(size_t)s0 * 32 + lane];
    unsigned int v1 = tp[(size_t)s1 * 32 + lane];
    unsigned int v2 = tp[(size_t)s2 * 32 + lane];
    unsigned int v3 = tp[(size_t)s3 * 32 + lane];
    ax += bflo(v0) + bflo(v1) + bflo(v2) + bflo(v3);
    ay += bfhi(v0) + bfhi(v1) + bfhi(v2) + bfhi(v3);
  }
  for (; j < j1; ++j){
    unsigned int v = tp[(size_t)csr_src[j] * 32 + lane];
    ax += bflo(v);
    ay += bfhi(v);
  }
  float ds = din_s[node];
  float2 bb = ((const float2*)b2)[lane];
  float2 r;
  r.x = fmaxf(fmaf(ax, ds, bb.x), 0.f);
  r.y = fmaxf(fmaf(ay, ds, bb.y), 0.f);
  ((float2*)h2)[(size_t)node * 32 + lane] = r;
}

// ---------------- MFMA bf16 GEMM: C = epi( A @ Bt^T ) ----------------
// A: bf16 row-major [M][K]. Bt: bf16 n-major [N][K].
// EPI:  cv = relu(cv*rowScaleC[m] + bias[n]);  EPI2: cv *= rowScaleC2[m] afterwards.
template<bool C_BF16, bool EPI, bool EPI2>
__global__ __launch_bounds__(256) void gemm_mfma(
    const unsigned short* __restrict__ A, const unsigned short* __restrict__ Bt, void* __restrict__ Cp,
    int M, int N, int K,
    const float* __restrict__ rowScaleC, const float* __restrict__ rowScaleC2,
    const float* __restrict__ bias){
  constexpr int BM = 128, BN = 64, BK = 128, LDA = 136;
  __shared__ __align__(16) unsigned short As[BM * LDA];
  __shared__ __align__(16) unsigned short Bs[BN * LDA];
  int tid = threadIdx.x;
  int bm0 = blockIdx.x * BM;
  int bn0 = blockIdx.y * BN;
  int wid = tid >> 6, lane = tid & 63;
  int wm = (wid >> 1) * 64, wn = (wid & 1) * 32;
  int quad = lane >> 4, l16 = lane & 15;
  f32x4 acc[4][2];
#pragma unroll
  for (int t = 0; t < 4; ++t)
#pragma unroll
    for (int u = 0; u < 2; ++u) acc[t][u] = f32x4{0.f, 0.f, 0.f, 0.f};

  for (int k0 = 0; k0 < K; k0 += BK){
    // stage A (BM x BK bf16) -> LDS (pure copy)
#pragma unroll
    for (int it = 0; it < 16; ++it){
      int i = tid + it * 256;
      int m = i >> 5, c4 = i & 31;
      int gr = bm0 + m;
      uint2 pk = make_uint2(0u, 0u);
      if (gr < M) pk = *(const uint2*)(A + (size_t)gr * K + k0 + c4 * 4);
      *(uint2*)&As[m * LDA + c4 * 4] = pk;
    }
    // stage B (BN x BK)
#pragma unroll
    for (int it = 0; it < 8; ++it){
      int i = tid + it * 256;
      int n = i >> 5, c4 = i & 31;
      uint2 v = *(const uint2*)(Bt + (size_t)(bn0 + n) * K + k0 + c4 * 4);
      *(uint2*)&Bs[n * LDA + c4 * 4] = v;
    }
    __syncthreads();
#pragma unroll
    for (int kc = 0; kc < 4; ++kc){
      bf16x8 af[4], bfr[2];
#pragma unroll
      for (int t = 0; t < 4; ++t)
        af[t] = *(const bf16x8*)&As[(wm + t * 16 + l16) * LDA + kc * 32 + quad * 8];
#pragma unroll
      for (int u = 0; u < 2; ++u)
        bfr[u] = *(const bf16x8*)&Bs[(wn + u * 16 + l16) * LDA + kc * 32 + quad * 8];
#pragma unroll
      for (int t = 0; t < 4; ++t)
#pragma unroll
        for (int u = 0; u < 2; ++u)
          acc[t][u] = __builtin_amdgcn_mfma_f32_16x16x32_bf16(af[t], bfr[u], acc[t][u], 0, 0, 0);
    }
    __syncthreads();
  }
  // epilogue
  float bv[2] = {0.f, 0.f};
  if constexpr (EPI){ bv[0] = bias[bn0 + wn + l16]; bv[1] = bias[bn0 + wn + 16 + l16]; }
#pragma unroll
  for (int t = 0; t < 4; ++t){
#pragma unroll
    for (int r = 0; r < 4; ++r){
      int gr = bm0 + wm + t * 16 + quad * 4 + r;
      if (gr < M){
        float rs = 1.f, rs2 = 1.f;
        if constexpr (EPI)  rs  = rowScaleC[gr];
        if constexpr (EPI2) rs2 = rowScaleC2[gr];
#pragma unroll
        for (int u = 0; u < 2; ++u){
          int gc = bn0 + wn + u * 16 + l16;
          float cv = acc[t][u][r];
          if constexpr (EPI)  cv = fmaxf(fmaf(cv, rs, bv[u]), 0.f);
          if constexpr (EPI2) cv *= rs2;
          if constexpr (C_BF16) ((unsigned short*)Cp)[(size_t)gr * N + gc] = f2bf(cv);
          else                  ((float*)Cp)[(size_t)gr * N + gc] = cv;
        }
      }
    }
  }
}

// ---------------- per-graph mean-pool ----------------
__global__ __launch_bounds__(256) void k_pool(const float* __restrict__ h2, const int* __restrict__ gids,
                                              float* __restrict__ sums, int* __restrict__ cnts, int n_nodes){
  int wave = (blockIdx.x * blockDim.x + threadIdx.x) >> 6;
  int lane = threadIdx.x & 63;
  int base = wave * 64;
  if (base >= n_nodes) return;
  int endn = min(base + 64, n_nodes);
  float acc = 0.f;
  int cur = -1, len = 0;
  for (int i = base; i < endn; ++i){
    int g = gids[i];
    float v = h2[(size_t)i * 64 + lane];
    if (g != cur){
      if (cur >= 0){
        atomicAdd(&sums[(size_t)cur * 64 + lane], acc);
        if (lane == 0) atomicAdd(&cnts[cur], len);
      }
      cur = g; acc = 0.f; len = 0;
    }
    acc += v; len++;
  }
  atomicAdd(&sums[(size_t)cur * 64 + lane], acc);
  if (lane == 0) atomicAdd(&cnts[cur], len);
}

// ---------------- classifier ----------------
__global__ __launch_bounds__(256) void k_classifier(const float* __restrict__ sums, const int* __restrict__ cnts,
    const float* __restrict__ Wc1, const float* __restrict__ bc1,
    const float* __restrict__ Wc2, const float* __restrict__ bc2,
    const float* __restrict__ Wc3, const float* __restrict__ bc3,
    const float* __restrict__ Wc4, const float* __restrict__ bc4,
    float* __restrict__ out){
  __shared__ float w1[64 * 18], w2[18 * 12], w3[12 * 6], w4[6 * 2];
  __shared__ float B1[18], B2[12], B3[6], B4[2];
  int tid = threadIdx.x;
  for (int i = tid; i < 64 * 18; i += 256) w1[i] = Wc1[i];
  for (int i = tid; i < 18 * 12; i += 256) w2[i] = Wc2[i];
  for (int i = tid; i < 12 * 6;  i += 256) w3[i] = Wc3[i];
  for (int i = tid; i < 6 * 2;   i += 256) w4[i] = Wc4[i];
  if (tid < 18) B1[tid] = bc1[tid];
  if (tid < 12) B2[tid] = bc2[tid];
  if (tid < 6)  B3[tid] = bc3[tid];
  if (tid < 2)  B4[tid] = bc4[tid];
  __syncthreads();
  int g = blockIdx.x * 256 + tid;
  float cnt = fmaxf((float)cnts[g], 1.0f);
  float h[64];
#pragma unroll
  for (int f = 0; f < 64; ++f) h[f] = sums[(size_t)g * 64 + f] / cnt;
  float t1[18];
#pragma unroll
  for (int j = 0; j < 18; ++j){
    float s = B1[j];
    for (int f = 0; f < 64; ++f) s = fmaf(h[f], w1[f * 18 + j], s);
    t1[j] = s;
  }
  float t2[12];
#pragma unroll
  for (int j = 0; j < 12; ++j){
    float s = B2[j];
    for (int f = 0; f < 18; ++f) s = fmaf(t1[f], w2[f * 12 + j], s);
    t2[j] = s;
  }
  float t3[6];
#pragma unroll
  for (int j = 0; j < 6; ++j){
    float s = B3[j];
    for (int f = 0; f < 12; ++f) s = fmaf(t2[f], w3[f * 6 + j], s);
    t3[j] = s;
  }
#pragma unroll
  for (int j = 0; j < 2; ++j){
    float s = B4[j];
    for (int f = 0; f < 6; ++f) s = fmaf(t3[f], w4[f * 2 + j], s);
    out[(size_t)g * 2 + j] = s;
  }
}

extern "C" void kernel_launch(void* const* d_in, const int* in_sizes, int n_in,
                              void* d_out, int out_size, void* d_ws, size_t ws_size,
                              hipStream_t stream){
  const float* x   = (const float*)d_in[0];
  const int*   src = (const int*)d_in[1];
  const int*   dst = (const int*)d_in[2];
  const int*   gid = (const int*)d_in[3];
  const float* W1  = (const float*)d_in[4];
  const float* b1  = (const float*)d_in[5];
  const float* W2  = (const float*)d_in[6];
  const float* b2  = (const float*)d_in[7];
  const float* Wc1 = (const float*)d_in[8];
  const float* bc1 = (const float*)d_in[9];
  const float* Wc2 = (const float*)d_in[10];
  const float* bc2 = (const float*)d_in[11];
  const float* Wc3 = (const float*)d_in[12];
  const float* bc3 = (const float*)d_in[13];
  const float* Wc4 = (const float*)d_in[14];
  const float* bc4 = (const float*)d_in[15];
  float* out = (float*)d_out;

  const int n_nodes = in_sizes[3];
  const int n_edges = in_sizes[1];
  const int F1 = 256, F2 = 64;
  const int NB = (n_nodes + 511) >> 9;

  char* w = (char*)d_ws;
  size_t o = 0;
  auto alloc = [&](size_t bytes) -> char* {
    char* p = w + o;
    o = align_up(o + bytes, 256);
    return p;
  };
  // ---- zero-initialized region ----
  int*   bcnt_src  = (int*)  alloc((size_t)NB * 4);
  int*   bcnt_dst  = (int*)  alloc((size_t)NB * 4);
  float* sums      = (float*)alloc((size_t)NGRAPHS * F2 * 4);
  int*   cnts      = (int*)  alloc((size_t)NGRAPHS * 4);
  size_t zero_bytes = o;
  // ---- rest ----
  int*   base_src  = (int*)  alloc((size_t)NB * 4);
  int*   cur_src   = (int*)  alloc((size_t)NB * 4);
  int*   base_dst  = (int*)  alloc((size_t)NB * 4);
  int*   cur_dst   = (int*)  alloc((size_t)NB * 4);
  int*   deg_in    = (int*)  alloc((size_t)n_nodes * 4);
  float* dout_s    = (float*)alloc((size_t)n_nodes * 4);
  float* din_s     = (float*)alloc((size_t)n_nodes * 4);
  int*   offs      = (int*)  alloc((size_t)(n_nodes + 1) * 4);
  int*   block_sums= (int*)  alloc((size_t)64 * 4);
  int*   csr_src   = (int*)  alloc((size_t)n_edges * 4);
  unsigned short* Wt1 = (unsigned short*)alloc((size_t)256 * 128 * 2);  // W1^T bf16 [N=256][K=128]
  unsigned short* Wt2 = (unsigned short*)alloc((size_t)64 * 256 * 2);   // W2^T bf16 [N=64][K=256]
  unsigned int*   xb  = (unsigned int*)  alloc((size_t)n_nodes * 128 * 2); // x bf16, 25.6 MB
  unsigned short* aggb= (unsigned short*)alloc((size_t)n_nodes * 128 * 2); // agg bf16, 25.6 MB
  unsigned short* h1b = (unsigned short*)alloc((size_t)n_nodes * F1 * 2);  // h1*dout bf16, 51.2 MB
  // aliases inside aggb region (consumed before spmm1 writes aggb)
  int2*  pairD = (int2*)aggb;                              // 12.8 MB
  int*   srcS  = (int*)((char*)aggb + (size_t)n_edges * 8);// 6.4 MB  (total 19.2 <= 25.6)
  unsigned short* t2b = aggb;                              // gemm2 out (bf16), after aggb consumed
  float* h2    = (float*)h1b;                              // spmm2 out (fp32), after h1b consumed

  hipMemsetAsync(d_ws, 0, zero_bytes, stream);

  // input prep (independent)
  k_prepw<<<(128 * 256 + 255) / 256, 256, 0, stream>>>(W1, Wt1, 128, 256, 128 * 256);
  k_prepw<<<(256 * 64 + 255) / 256, 256, 0, stream>>>(W2, Wt2, 256, 64, 256 * 64);
  {
    long long total4 = (long long)n_nodes * 32;   // 4 floats per thread
    k_prepx<<<(int)((total4 + 255) / 256), 256, 0, stream>>>(x, xb, total4);
  }

  // bucketed degree + CSR preprocessing
  k_bincount   <<<512, 256, 0, stream>>>(src, dst, bcnt_src, bcnt_dst, n_edges, NB);
  k_bucket_scan<<<1, 256, 0, stream>>>(bcnt_src, bcnt_dst, base_src, cur_src, base_dst, cur_dst, NB);
  {
    int nb1 = 100;
    int chunk = (n_edges + nb1 - 1) / nb1;
    k_binscatter<<<nb1, 256, 0, stream>>>(src, dst, cur_dst, cur_src, pairD, srcS, n_edges, chunk);
  }
  k_bucket_hist_dst<<<NB, 256, 0, stream>>>(pairD, base_dst, deg_in, din_s, NB, n_nodes, n_edges);
  k_bucket_hist_src<<<NB, 256, 0, stream>>>(srcS, base_src, dout_s, NB, n_nodes, n_edges);

  int nscan_blocks = (n_nodes + 4095) / 4096;
  k_scan_partial  <<<nscan_blocks, 256, 0, stream>>>(deg_in, block_sums, n_nodes);
  k_scan_blocksums<<<1, 64, 0, stream>>>(block_sums, nscan_blocks, offs, n_nodes);
  k_scan_write    <<<nscan_blocks, 256, 0, stream>>>(deg_in, block_sums, offs, n_nodes);

  k_csrfill<<<NB, 256, 0, stream>>>(pairD, offs, csr_src, n_nodes);

  int gx = (n_nodes + 127) / 128;
  // layer 1: aggb = Agg(xb * dout) [bf16];  h1b = relu((aggb @ W1) * din + b1) * dout  [bf16]
  {
    long long threads = (long long)n_nodes * 32;
    k_spmm1<<<(int)((threads + 255) / 256), 256, 0, stream>>>(xb, offs, csr_src, dout_s, (unsigned int*)aggb, n_nodes);
    gemm_mfma<true, true, true><<<dim3(gx, F1 / 64), 256, 0, stream>>>(
        aggb, Wt1, h1b, n_nodes, F1, 128, din_s, dout_s, b1);
  }
  // layer 2: t2 = h1b @ W2  [bf16, dout already folded];  h2 = relu(Agg(t2) * din + b2)
  {
    gemm_mfma<true, false, false><<<dim3(gx, 1), 256, 0, stream>>>(
        h1b, Wt2, t2b, n_nodes, F2, F1, nullptr, nullptr, nullptr);
    long long threads = (long long)n_nodes * 32;
    k_spmm2<<<(int)((threads + 255) / 256), 256, 0, stream>>>(t2b, offs, csr_src, din_s, b2, h2, n_nodes);
  }
  // pooling + classifier
  {
    int pool_waves = (n_nodes + 63) / 64;
    long long threads = (long long)pool_waves * 64;
    k_pool<<<(int)((threads + 255) / 256), 256, 0, stream>>>(h2, gid, sums, cnts, n_nodes);
    k_classifier<<<NGRAPHS / 256, 256, 0, stream>>>(sums, cnts, Wc1, bc1, Wc2, bc2, Wc3, bc3, Wc4, bc4, out);
  }
}

// Round 9
// 451.053 us; speedup vs baseline: 2.3722x; 1.0472x over previous
//
#include <hip/hip_runtime.h>
#include <cstdint>
#include <cstddef>

#define NGRAPHS 512

static inline size_t align_up(size_t x, size_t a){ return (x + a - 1) & ~(a - 1); }

// ---------------- bf16 helpers ----------------
__device__ __forceinline__ unsigned short f2bf(float f){
  unsigned int u = __float_as_uint(f);
  u += 0x7FFFu + ((u >> 16) & 1u);          // round-to-nearest-even
  return (unsigned short)(u >> 16);
}
__device__ __forceinline__ float bf2f(unsigned short s){
  return __uint_as_float(((unsigned int)s) << 16);
}
__device__ __forceinline__ float bflo(unsigned int u){ return __uint_as_float(u << 16); }
__device__ __forceinline__ float bfhi(unsigned int u){ return __uint_as_float(u & 0xffff0000u); }
__device__ __forceinline__ unsigned int pack2(float a, float b){
  return (unsigned)f2bf(a) | ((unsigned)f2bf(b) << 16);
}

typedef __attribute__((ext_vector_type(8))) short bf16x8;
typedef __attribute__((ext_vector_type(4))) float f32x4;

// ================= bucketed graph preprocessing =================
__global__ __launch_bounds__(256) void k_bincount(const int* __restrict__ src, const int* __restrict__ dst,
                                                  int* __restrict__ bcnt_src, int* __restrict__ bcnt_dst,
                                                  int n_edges, int NB){
  __shared__ int cs[256], cd[256];
  cs[threadIdx.x] = 0; cd[threadIdx.x] = 0;
  __syncthreads();
  int stride = gridDim.x * 256;
  for (int e = blockIdx.x * 256 + threadIdx.x; e < n_edges; e += stride){
    atomicAdd(&cs[src[e] >> 9], 1);
    atomicAdd(&cd[dst[e] >> 9], 1);
  }
  __syncthreads();
  if (threadIdx.x < NB){
    int a = cs[threadIdx.x], b = cd[threadIdx.x];
    if (a) atomicAdd(&bcnt_src[threadIdx.x], a);
    if (b) atomicAdd(&bcnt_dst[threadIdx.x], b);
  }
}

__global__ __launch_bounds__(256) void k_bucket_scan(const int* __restrict__ bcnt_src, const int* __restrict__ bcnt_dst,
                                                     int* __restrict__ base_src, int* __restrict__ cur_src,
                                                     int* __restrict__ base_dst, int* __restrict__ cur_dst, int NB){
  __shared__ int s1[256], s2[256];
  int tid = threadIdx.x;
  int v1 = (tid < NB) ? bcnt_src[tid] : 0;
  int v2 = (tid < NB) ? bcnt_dst[tid] : 0;
  s1[tid] = v1; s2[tid] = v2;
  __syncthreads();
  for (int off = 1; off < 256; off <<= 1){
    int t1 = (tid >= off) ? s1[tid - off] : 0;
    int t2 = (tid >= off) ? s2[tid - off] : 0;
    __syncthreads();
    s1[tid] += t1; s2[tid] += t2;
    __syncthreads();
  }
  if (tid < NB){
    base_src[tid] = s1[tid] - v1; cur_src[tid] = s1[tid] - v1;
    base_dst[tid] = s2[tid] - v2; cur_dst[tid] = s2[tid] - v2;
  }
}

// scatter with 2048-edge blocks, edges register-cached (one global read pass)
__global__ __launch_bounds__(256) void k_binscatter(const int* __restrict__ src, const int* __restrict__ dst,
                                                    int* __restrict__ rsv_d, int* __restrict__ rsv_s,
                                                    int2* __restrict__ pairD, int* __restrict__ srcS,
                                                    int n_edges){
  __shared__ int cntd[256], curd[256], cnts_[256], curs[256];
  int tid = threadIdx.x;
  int e0 = blockIdx.x * 2048;
  cntd[tid] = 0; cnts_[tid] = 0;
  __syncthreads();
  int2 er[8];
  int ne = 0;
#pragma unroll
  for (int it = 0; it < 8; ++it){
    int e = e0 + it * 256 + tid;
    if (e < n_edges){
      int s = src[e], d = dst[e];
      er[it] = make_int2(s, d);
      atomicAdd(&cnts_[s >> 9], 1);
      atomicAdd(&cntd[d >> 9], 1);
      ne = it + 1;
    }
  }
  __syncthreads();
  int cd = cntd[tid], cs = cnts_[tid];
  curd[tid] = cd ? atomicAdd(&rsv_d[tid], cd) : 0;
  curs[tid] = cs ? atomicAdd(&rsv_s[tid], cs) : 0;
  __syncthreads();
#pragma unroll
  for (int it = 0; it < 8; ++it){
    if (it < ne){
      int s = er[it].x, d = er[it].y;
      int pd = atomicAdd(&curd[d >> 9], 1);
      pairD[pd] = make_int2(s, d);
      int ps = atomicAdd(&curs[s >> 9], 1);
      srcS[ps] = s;
    }
  }
}

__global__ __launch_bounds__(256) void k_bucket_hist_dst(const int2* __restrict__ pairD, const int* __restrict__ base_dst,
                                                         int* __restrict__ deg_in, float* __restrict__ din_s,
                                                         int NB, int n, int n_edges){
  __shared__ int cnt[512];
  int b = blockIdx.x;
  int node0 = b << 9;
  int nn = min(512, n - node0);
  for (int i = threadIdx.x; i < 512; i += 256) cnt[i] = 0;
  __syncthreads();
  int j0 = base_dst[b];
  int j1 = (b + 1 < NB) ? base_dst[b + 1] : n_edges;
  for (int j = j0 + threadIdx.x; j < j1; j += 256)
    atomicAdd(&cnt[pairD[j].y - node0], 1);
  __syncthreads();
  for (int i = threadIdx.x; i < nn; i += 256){
    int c = cnt[i];
    deg_in[node0 + i] = c;
    din_s[node0 + i] = 1.0f / sqrtf((float)max(c, 1));
  }
}

__global__ __launch_bounds__(256) void k_bucket_hist_src(const int* __restrict__ srcS, const int* __restrict__ base_src,
                                                         float* __restrict__ dout_s, int NB, int n, int n_edges){
  __shared__ int cnt[512];
  int b = blockIdx.x;
  int node0 = b << 9;
  int nn = min(512, n - node0);
  for (int i = threadIdx.x; i < 512; i += 256) cnt[i] = 0;
  __syncthreads();
  int j0 = base_src[b];
  int j1 = (b + 1 < NB) ? base_src[b + 1] : n_edges;
  for (int j = j0 + threadIdx.x; j < j1; j += 256)
    atomicAdd(&cnt[srcS[j] - node0], 1);
  __syncthreads();
  for (int i = threadIdx.x; i < nn; i += 256)
    dout_s[node0 + i] = 1.0f / sqrtf((float)max(cnt[i], 1));
}

// ---------------- 3-phase device-wide exclusive scan ----------------
__global__ __launch_bounds__(256) void k_scan_partial(const int* __restrict__ deg,
                                                      int* __restrict__ bs, int n){
  __shared__ int sm[256];
  int base = blockIdx.x * 4096;
  int s = 0;
#pragma unroll
  for (int it = 0; it < 16; ++it){
    int i = base + it * 256 + threadIdx.x;
    if (i < n) s += deg[i];
  }
  sm[threadIdx.x] = s;
  __syncthreads();
  for (int off = 128; off > 0; off >>= 1){
    if (threadIdx.x < off) sm[threadIdx.x] += sm[threadIdx.x + off];
    __syncthreads();
  }
  if (threadIdx.x == 0) bs[blockIdx.x] = sm[0];
}

__global__ __launch_bounds__(64) void k_scan_blocksums(int* __restrict__ bs, int nb,
                                                       int* __restrict__ offs, int n){
  __shared__ int sm[64];
  int tid = threadIdx.x;
  int v = (tid < nb) ? bs[tid] : 0;
  sm[tid] = v;
  __syncthreads();
  for (int off = 1; off < 64; off <<= 1){
    int t = (tid >= off) ? sm[tid - off] : 0;
    __syncthreads();
    sm[tid] += t;
    __syncthreads();
  }
  if (tid < nb) bs[tid] = sm[tid] - v;
  if (tid == 63) offs[n] = sm[63];
}

__global__ __launch_bounds__(256) void k_scan_write(const int* __restrict__ deg,
    const int* __restrict__ bs, int* __restrict__ offs, int n){
  __shared__ int vals[4096];
  __shared__ int tsum[256];
  int base = blockIdx.x * 4096;
#pragma unroll
  for (int it = 0; it < 16; ++it){
    int i = base + it * 256 + threadIdx.x;
    vals[it * 256 + threadIdx.x] = (i < n) ? deg[i] : 0;
  }
  __syncthreads();
  int t0 = threadIdx.x * 16;
  int loc[16];
  int s = 0;
#pragma unroll
  for (int k = 0; k < 16; ++k){ loc[k] = s; s += vals[t0 + k]; }
  tsum[threadIdx.x] = s;
  __syncthreads();
  for (int off = 1; off < 256; off <<= 1){
    int t = (threadIdx.x >= off) ? tsum[threadIdx.x - off] : 0;
    __syncthreads();
    tsum[threadIdx.x] += t;
    __syncthreads();
  }
  int pre = tsum[threadIdx.x] - s + bs[blockIdx.x];
  __syncthreads();
#pragma unroll
  for (int k = 0; k < 16; ++k) vals[t0 + k] = pre + loc[k];
  __syncthreads();
#pragma unroll
  for (int it = 0; it < 16; ++it){
    int i = base + it * 256 + threadIdx.x;
    if (i < n) offs[i] = vals[it * 256 + threadIdx.x];
  }
}

__global__ __launch_bounds__(256) void k_csrfill(const int2* __restrict__ pair, const int* __restrict__ offs,
                                                 int* __restrict__ csr_src, int n){
  __shared__ int cur[512];
  int node0 = blockIdx.x << 9;
  int nn = min(512, n - node0);
  for (int i = threadIdx.x; i < nn; i += 256) cur[i] = offs[node0 + i];
  __syncthreads();
  int j0 = offs[node0];
  int j1 = offs[min(node0 + 512, n)];
  for (int j = j0 + threadIdx.x; j < j1; j += 256){
    int2 e = pair[j];
    int p = atomicAdd(&cur[e.y - node0], 1);
    csr_src[p] = e.x;
  }
}

// ---------------- weight prep: fp32 W[K][N] -> bf16 Wt[N][K] ----------------
__global__ void k_prepw(const float* __restrict__ W, unsigned short* __restrict__ Wt,
                        int K, int N, int total){
  int t = blockIdx.x * blockDim.x + threadIdx.x;
  if (t < total){
    int k = t / N, n = t % N;
    Wt[(size_t)n * K + k] = f2bf(W[t]);
  }
}

// ---------------- x fp32 -> bf16 (packed), 4 elems/thread ----------------
__global__ __launch_bounds__(256) void k_prepx(const float* __restrict__ x, unsigned int* __restrict__ xb,
                                               long long total4){
  long long t = (long long)blockIdx.x * blockDim.x + threadIdx.x;
  if (t < total4){
    float4 v = ((const float4*)x)[t];
    xb[t * 2 + 0] = pack2(v.x, v.y);
    xb[t * 2 + 1] = pack2(v.z, v.w);
  }
}

// ---------------- SpMM layer1 on bf16 x: 2 nodes/wave, uint2 lanes (32x8B=256B row) ----
__global__ __launch_bounds__(256) void k_spmm1(const unsigned int* __restrict__ xb,
    const int* __restrict__ offs, const int* __restrict__ csr_src,
    const float* __restrict__ dout_s, unsigned int* __restrict__ aggb, int n_nodes){
  int node = (blockIdx.x * blockDim.x + threadIdx.x) >> 5;
  int lane = threadIdx.x & 31;
  if (node >= n_nodes) return;
  int j0 = offs[node], j1 = offs[node + 1];
  const uint2* xp = (const uint2*)xb;                 // row = 32 x uint2 (4 bf16 each)
  float4 acc = make_float4(0.f, 0.f, 0.f, 0.f);
  int j = j0;
  for (; j + 4 <= j1; j += 4){
    int s0 = csr_src[j + 0];
    int s1 = csr_src[j + 1];
    int s2 = csr_src[j + 2];
    int s3 = csr_src[j + 3];
    float c0 = dout_s[s0];
    float c1 = dout_s[s1];
    float c2 = dout_s[s2];
    float c3 = dout_s[s3];
    uint2 v0 = xp[(size_t)s0 * 32 + lane];
    uint2 v1 = xp[(size_t)s1 * 32 + lane];
    uint2 v2 = xp[(size_t)s2 * 32 + lane];
    uint2 v3 = xp[(size_t)s3 * 32 + lane];
    acc.x = fmaf(bflo(v0.x), c0, acc.x); acc.y = fmaf(bfhi(v0.x), c0, acc.y);
    acc.z = fmaf(bflo(v0.y), c0, acc.z); acc.w = fmaf(bfhi(v0.y), c0, acc.w);
    acc.x = fmaf(bflo(v1.x), c1, acc.x); acc.y = fmaf(bfhi(v1.x), c1, acc.y);
    acc.z = fmaf(bflo(v1.y), c1, acc.z); acc.w = fmaf(bfhi(v1.y), c1, acc.w);
    acc.x = fmaf(bflo(v2.x), c2, acc.x); acc.y = fmaf(bfhi(v2.x), c2, acc.y);
    acc.z = fmaf(bflo(v2.y), c2, acc.z); acc.w = fmaf(bfhi(v2.y), c2, acc.w);
    acc.x = fmaf(bflo(v3.x), c3, acc.x); acc.y = fmaf(bfhi(v3.x), c3, acc.y);
    acc.z = fmaf(bflo(v3.y), c3, acc.z); acc.w = fmaf(bfhi(v3.y), c3, acc.w);
  }
  for (; j < j1; ++j){
    int s = csr_src[j];
    float sc = dout_s[s];
    uint2 v = xp[(size_t)s * 32 + lane];
    acc.x = fmaf(bflo(v.x), sc, acc.x); acc.y = fmaf(bfhi(v.x), sc, acc.y);
    acc.z = fmaf(bflo(v.y), sc, acc.z); acc.w = fmaf(bfhi(v.y), sc, acc.w);
  }
  uint2 pk;
  pk.x = pack2(acc.x, acc.y);
  pk.y = pack2(acc.z, acc.w);
  ((uint2*)aggb)[(size_t)node * 32 + lane] = pk;
}

// ---------------- SpMM layer2 on bf16 t2: 2 nodes/wave, uint(2xbf16) lanes ----
__global__ __launch_bounds__(256) void k_spmm2(const unsigned short* __restrict__ t2,
    const int* __restrict__ offs, const int* __restrict__ csr_src,
    const float* __restrict__ din_s, const float* __restrict__ b2,
    float* __restrict__ h2, int n_nodes){
  int node = (blockIdx.x * blockDim.x + threadIdx.x) >> 5;
  int lane = threadIdx.x & 31;
  if (node >= n_nodes) return;
  int j0 = offs[node], j1 = offs[node + 1];
  const unsigned int* tp = (const unsigned int*)t2;     // row = 32 uints = 64 bf16
  float ax = 0.f, ay = 0.f;
  int j = j0;
  for (; j + 4 <= j1; j += 4){
    int s0 = csr_src[j + 0];
    int s1 = csr_src[j + 1];
    int s2 = csr_src[j + 2];
    int s3 = csr_src[j + 3];
    unsigned int v0 = tp[(size_t)s0 * 32 + lane];
    unsigned int v1 = tp[(size_t)s1 * 32 + lane];
    unsigned int v2 = tp[(size_t)s2 * 32 + lane];
    unsigned int v3 = tp[(size_t)s3 * 32 + lane];
    ax += bflo(v0) + bflo(v1) + bflo(v2) + bflo(v3);
    ay += bfhi(v0) + bfhi(v1) + bfhi(v2) + bfhi(v3);
  }
  for (; j < j1; ++j){
    unsigned int v = tp[(size_t)csr_src[j] * 32 + lane];
    ax += bflo(v);
    ay += bfhi(v);
  }
  float ds = din_s[node];
  float2 bb = ((const float2*)b2)[lane];
  float2 r;
  r.x = fmaxf(fmaf(ax, ds, bb.x), 0.f);
  r.y = fmaxf(fmaf(ay, ds, bb.y), 0.f);
  ((float2*)h2)[(size_t)node * 32 + lane] = r;
}

// ---------------- MFMA bf16 GEMM: C = epi( A @ Bt^T ) ----------------
template<bool C_BF16, bool EPI, bool EPI2>
__global__ __launch_bounds__(256) void gemm_mfma(
    const unsigned short* __restrict__ A, const unsigned short* __restrict__ Bt, void* __restrict__ Cp,
    int M, int N, int K,
    const float* __restrict__ rowScaleC, const float* __restrict__ rowScaleC2,
    const float* __restrict__ bias){
  constexpr int BM = 128, BN = 64, BK = 128, LDA = 136;
  __shared__ __align__(16) unsigned short As[BM * LDA];
  __shared__ __align__(16) unsigned short Bs[BN * LDA];
  int tid = threadIdx.x;
  int bm0 = blockIdx.x * BM;
  int bn0 = blockIdx.y * BN;
  int wid = tid >> 6, lane = tid & 63;
  int wm = (wid >> 1) * 64, wn = (wid & 1) * 32;
  int quad = lane >> 4, l16 = lane & 15;
  f32x4 acc[4][2];
#pragma unroll
  for (int t = 0; t < 4; ++t)
#pragma unroll
    for (int u = 0; u < 2; ++u) acc[t][u] = f32x4{0.f, 0.f, 0.f, 0.f};

  for (int k0 = 0; k0 < K; k0 += BK){
#pragma unroll
    for (int it = 0; it < 16; ++it){
      int i = tid + it * 256;
      int m = i >> 5, c4 = i & 31;
      int gr = bm0 + m;
      uint2 pk = make_uint2(0u, 0u);
      if (gr < M) pk = *(const uint2*)(A + (size_t)gr * K + k0 + c4 * 4);
      *(uint2*)&As[m * LDA + c4 * 4] = pk;
    }
#pragma unroll
    for (int it = 0; it < 8; ++it){
      int i = tid + it * 256;
      int n = i >> 5, c4 = i & 31;
      uint2 v = *(const uint2*)(Bt + (size_t)(bn0 + n) * K + k0 + c4 * 4);
      *(uint2*)&Bs[n * LDA + c4 * 4] = v;
    }
    __syncthreads();
#pragma unroll
    for (int kc = 0; kc < 4; ++kc){
      bf16x8 af[4], bfr[2];
#pragma unroll
      for (int t = 0; t < 4; ++t)
        af[t] = *(const bf16x8*)&As[(wm + t * 16 + l16) * LDA + kc * 32 + quad * 8];
#pragma unroll
      for (int u = 0; u < 2; ++u)
        bfr[u] = *(const bf16x8*)&Bs[(wn + u * 16 + l16) * LDA + kc * 32 + quad * 8];
#pragma unroll
      for (int t = 0; t < 4; ++t)
#pragma unroll
        for (int u = 0; u < 2; ++u)
          acc[t][u] = __builtin_amdgcn_mfma_f32_16x16x32_bf16(af[t], bfr[u], acc[t][u], 0, 0, 0);
    }
    __syncthreads();
  }
  float bv[2] = {0.f, 0.f};
  if constexpr (EPI){ bv[0] = bias[bn0 + wn + l16]; bv[1] = bias[bn0 + wn + 16 + l16]; }
#pragma unroll
  for (int t = 0; t < 4; ++t){
#pragma unroll
    for (int r = 0; r < 4; ++r){
      int gr = bm0 + wm + t * 16 + quad * 4 + r;
      if (gr < M){
        float rs = 1.f, rs2 = 1.f;
        if constexpr (EPI)  rs  = rowScaleC[gr];
        if constexpr (EPI2) rs2 = rowScaleC2[gr];
#pragma unroll
        for (int u = 0; u < 2; ++u){
          int gc = bn0 + wn + u * 16 + l16;
          float cv = acc[t][u][r];
          if constexpr (EPI)  cv = fmaxf(fmaf(cv, rs, bv[u]), 0.f);
          if constexpr (EPI2) cv *= rs2;
          if constexpr (C_BF16) ((unsigned short*)Cp)[(size_t)gr * N + gc] = f2bf(cv);
          else                  ((float*)Cp)[(size_t)gr * N + gc] = cv;
        }
      }
    }
  }
}

// ---------------- per-graph mean-pool ----------------
__global__ __launch_bounds__(256) void k_pool(const float* __restrict__ h2, const int* __restrict__ gids,
                                              float* __restrict__ sums, int* __restrict__ cnts, int n_nodes){
  int wave = (blockIdx.x * blockDim.x + threadIdx.x) >> 6;
  int lane = threadIdx.x & 63;
  int base = wave * 64;
  if (base >= n_nodes) return;
  int endn = min(base + 64, n_nodes);
  float acc = 0.f;
  int cur = -1, len = 0;
  for (int i = base; i < endn; ++i){
    int g = gids[i];
    float v = h2[(size_t)i * 64 + lane];
    if (g != cur){
      if (cur >= 0){
        atomicAdd(&sums[(size_t)cur * 64 + lane], acc);
        if (lane == 0) atomicAdd(&cnts[cur], len);
      }
      cur = g; acc = 0.f; len = 0;
    }
    acc += v; len++;
  }
  atomicAdd(&sums[(size_t)cur * 64 + lane], acc);
  if (lane == 0) atomicAdd(&cnts[cur], len);
}

// ---------------- classifier ----------------
__global__ __launch_bounds__(256) void k_classifier(const float* __restrict__ sums, const int* __restrict__ cnts,
    const float* __restrict__ Wc1, const float* __restrict__ bc1,
    const float* __restrict__ Wc2, const float* __restrict__ bc2,
    const float* __restrict__ Wc3, const float* __restrict__ bc3,
    const float* __restrict__ Wc4, const float* __restrict__ bc4,
    float* __restrict__ out){
  __shared__ float w1[64 * 18], w2[18 * 12], w3[12 * 6], w4[6 * 2];
  __shared__ float B1[18], B2[12], B3[6], B4[2];
  int tid = threadIdx.x;
  for (int i = tid; i < 64 * 18; i += 256) w1[i] = Wc1[i];
  for (int i = tid; i < 18 * 12; i += 256) w2[i] = Wc2[i];
  for (int i = tid; i < 12 * 6;  i += 256) w3[i] = Wc3[i];
  for (int i = tid; i < 6 * 2;   i += 256) w4[i] = Wc4[i];
  if (tid < 18) B1[tid] = bc1[tid];
  if (tid < 12) B2[tid] = bc2[tid];
  if (tid < 6)  B3[tid] = bc3[tid];
  if (tid < 2)  B4[tid] = bc4[tid];
  __syncthreads();
  int g = blockIdx.x * 256 + tid;
  float cnt = fmaxf((float)cnts[g], 1.0f);
  float h[64];
#pragma unroll
  for (int f = 0; f < 64; ++f) h[f] = sums[(size_t)g * 64 + f] / cnt;
  float t1[18];
#pragma unroll
  for (int j = 0; j < 18; ++j){
    float s = B1[j];
    for (int f = 0; f < 64; ++f) s = fmaf(h[f], w1[f * 18 + j], s);
    t1[j] = s;
  }
  float t2[12];
#pragma unroll
  for (int j = 0; j < 12; ++j){
    float s = B2[j];
    for (int f = 0; f < 18; ++f) s = fmaf(t1[f], w2[f * 12 + j], s);
    t2[j] = s;
  }
  float t3[6];
#pragma unroll
  for (int j = 0; j < 6; ++j){
    float s = B3[j];
    for (int f = 0; f < 12; ++f) s = fmaf(t2[f], w3[f * 6 + j], s);
    t3[j] = s;
  }
#pragma unroll
  for (int j = 0; j < 2; ++j){
    float s = B4[j];
    for (int f = 0; f < 6; ++f) s = fmaf(t3[f], w4[f * 2 + j], s);
    out[(size_t)g * 2 + j] = s;
  }
}

extern "C" void kernel_launch(void* const* d_in, const int* in_sizes, int n_in,
                              void* d_out, int out_size, void* d_ws, size_t ws_size,
                              hipStream_t stream){
  const float* x   = (const float*)d_in[0];
  const int*   src = (const int*)d_in[1];
  const int*   dst = (const int*)d_in[2];
  const int*   gid = (const int*)d_in[3];
  const float* W1  = (const float*)d_in[4];
  const float* b1  = (const float*)d_in[5];
  const float* W2  = (const float*)d_in[6];
  const float* b2  = (const float*)d_in[7];
  const float* Wc1 = (const float*)d_in[8];
  const float* bc1 = (const float*)d_in[9];
  const float* Wc2 = (const float*)d_in[10];
  const float* bc2 = (const float*)d_in[11];
  const float* Wc3 = (const float*)d_in[12];
  const float* bc3 = (const float*)d_in[13];
  const float* Wc4 = (const float*)d_in[14];
  const float* bc4 = (const float*)d_in[15];
  float* out = (float*)d_out;

  const int n_nodes = in_sizes[3];
  const int n_edges = in_sizes[1];
  const int F1 = 256, F2 = 64;
  const int NB = (n_nodes + 511) >> 9;

  char* w = (char*)d_ws;
  size_t o = 0;
  auto alloc = [&](size_t bytes) -> char* {
    char* p = w + o;
    o = align_up(o + bytes, 256);
    return p;
  };
  // ---- zero-initialized region ----
  int*   bcnt_src  = (int*)  alloc((size_t)NB * 4);
  int*   bcnt_dst  = (int*)  alloc((size_t)NB * 4);
  float* sums      = (float*)alloc((size_t)NGRAPHS * F2 * 4);
  int*   cnts      = (int*)  alloc((size_t)NGRAPHS * 4);
  size_t zero_bytes = o;
  // ---- rest ----
  int*   base_src  = (int*)  alloc((size_t)NB * 4);
  int*   cur_src   = (int*)  alloc((size_t)NB * 4);
  int*   base_dst  = (int*)  alloc((size_t)NB * 4);
  int*   cur_dst   = (int*)  alloc((size_t)NB * 4);
  int*   deg_in    = (int*)  alloc((size_t)n_nodes * 4);
  float* dout_s    = (float*)alloc((size_t)n_nodes * 4);
  float* din_s     = (float*)alloc((size_t)n_nodes * 4);
  int*   offs      = (int*)  alloc((size_t)(n_nodes + 1) * 4);
  int*   block_sums= (int*)  alloc((size_t)64 * 4);
  int*   csr_src   = (int*)  alloc((size_t)n_edges * 4);
  unsigned short* Wt1 = (unsigned short*)alloc((size_t)256 * 128 * 2);
  unsigned short* Wt2 = (unsigned short*)alloc((size_t)64 * 256 * 2);
  unsigned int*   xb  = (unsigned int*)  alloc((size_t)n_nodes * 128 * 2);
  unsigned short* aggb= (unsigned short*)alloc((size_t)n_nodes * 128 * 2);
  unsigned short* h1b = (unsigned short*)alloc((size_t)n_nodes * F1 * 2);
  // aliases inside aggb region (consumed before spmm1 writes aggb)
  int2*  pairD = (int2*)aggb;
  int*   srcS  = (int*)((char*)aggb + (size_t)n_edges * 8);
  unsigned short* t2b = aggb;
  float* h2    = (float*)h1b;

  hipMemsetAsync(d_ws, 0, zero_bytes, stream);

  // input prep (independent)
  k_prepw<<<(128 * 256 + 255) / 256, 256, 0, stream>>>(W1, Wt1, 128, 256, 128 * 256);
  k_prepw<<<(256 * 64 + 255) / 256, 256, 0, stream>>>(W2, Wt2, 256, 64, 256 * 64);
  {
    long long total4 = (long long)n_nodes * 32;
    k_prepx<<<(int)((total4 + 255) / 256), 256, 0, stream>>>(x, xb, total4);
  }

  // bucketed degree + CSR preprocessing
  k_bincount   <<<512, 256, 0, stream>>>(src, dst, bcnt_src, bcnt_dst, n_edges, NB);
  k_bucket_scan<<<1, 256, 0, stream>>>(bcnt_src, bcnt_dst, base_src, cur_src, base_dst, cur_dst, NB);
  k_binscatter <<<(n_edges + 2047) / 2048, 256, 0, stream>>>(src, dst, cur_dst, cur_src, pairD, srcS, n_edges);
  k_bucket_hist_dst<<<NB, 256, 0, stream>>>(pairD, base_dst, deg_in, din_s, NB, n_nodes, n_edges);
  k_bucket_hist_src<<<NB, 256, 0, stream>>>(srcS, base_src, dout_s, NB, n_nodes, n_edges);

  int nscan_blocks = (n_nodes + 4095) / 4096;
  k_scan_partial  <<<nscan_blocks, 256, 0, stream>>>(deg_in, block_sums, n_nodes);
  k_scan_blocksums<<<1, 64, 0, stream>>>(block_sums, nscan_blocks, offs, n_nodes);
  k_scan_write    <<<nscan_blocks, 256, 0, stream>>>(deg_in, block_sums, offs, n_nodes);

  k_csrfill<<<NB, 256, 0, stream>>>(pairD, offs, csr_src, n_nodes);

  int gx = (n_nodes + 127) / 128;
  // layer 1
  {
    long long threads = (long long)n_nodes * 32;
    k_spmm1<<<(int)((threads + 255) / 256), 256, 0, stream>>>(xb, offs, csr_src, dout_s, (unsigned int*)aggb, n_nodes);
    gemm_mfma<true, true, true><<<dim3(gx, F1 / 64), 256, 0, stream>>>(
        aggb, Wt1, h1b, n_nodes, F1, 128, din_s, dout_s, b1);
  }
  // layer 2
  {
    gemm_mfma<true, false, false><<<dim3(gx, 1), 256, 0, stream>>>(
        h1b, Wt2, t2b, n_nodes, F2, F1, nullptr, nullptr, nullptr);
    long long threads = (long long)n_nodes * 32;
    k_spmm2<<<(int)((threads + 255) / 256), 256, 0, stream>>>(t2b, offs, csr_src, din_s, b2, h2, n_nodes);
  }
  // pooling + classifier
  {
    int pool_waves = (n_nodes + 63) / 64;
    long long threads = (long long)pool_waves * 64;
    k_pool<<<(int)((threads + 255) / 256), 256, 0, stream>>>(h2, gid, sums, cnts, n_nodes);
    k_classifier<<<NGRAPHS / 256, 256, 0, stream>>>(sums, cnts, Wc1, bc1, Wc2, bc2, Wc3, bc3, Wc4, bc4, out);
  }
}

// Round 10
// 433.231 us; speedup vs baseline: 2.4698x; 1.0411x over previous
//
#include <hip/hip_runtime.h>
#include <cstdint>
#include <cstddef>

#define NGRAPHS 512

static inline size_t align_up(size_t x, size_t a){ return (x + a - 1) & ~(a - 1); }

// ---------------- bf16 helpers ----------------
__device__ __forceinline__ unsigned short f2bf(float f){
  unsigned int u = __float_as_uint(f);
  u += 0x7FFFu + ((u >> 16) & 1u);          // round-to-nearest-even
  return (unsigned short)(u >> 16);
}
__device__ __forceinline__ float bflo(unsigned int u){ return __uint_as_float(u << 16); }
__device__ __forceinline__ float bfhi(unsigned int u){ return __uint_as_float(u & 0xffff0000u); }
__device__ __forceinline__ unsigned int pack2(float a, float b){
  return (unsigned)f2bf(a) | ((unsigned)f2bf(b) << 16);
}

typedef __attribute__((ext_vector_type(8))) short bf16x8;
typedef __attribute__((ext_vector_type(4))) float f32x4;

// ================= deterministic radix partition (no global atomics) =================
// buckets = 512-node ranges (NB<=256); blocks = 4096-edge chunks (nblk<=512).

__global__ __launch_bounds__(256) void k_partcount(const int* __restrict__ src, const int* __restrict__ dst,
                                                   int* __restrict__ cntS, int* __restrict__ cntD, int n_edges){
  __shared__ int cs[256], cd[256];
  int tid = threadIdx.x;
  cs[tid] = 0; cd[tid] = 0;
  __syncthreads();
  int e0 = blockIdx.x * 4096;
  int e1 = min(e0 + 4096, n_edges);
  for (int e = e0 + tid; e < e1; e += 256){
    atomicAdd(&cs[src[e] >> 9], 1);
    atomicAdd(&cd[dst[e] >> 9], 1);
  }
  __syncthreads();
  cntS[blockIdx.x * 256 + tid] = cs[tid];
  cntD[blockIdx.x * 256 + tid] = cd[tid];
}

// per-bucket column scan over blocks (in-place exclusive) + totals
__global__ __launch_bounds__(256) void k_colscan(int* __restrict__ cntS, int* __restrict__ cntD,
                                                 int* __restrict__ totS, int* __restrict__ totD,
                                                 int nblk, int NB){
  int col = blockIdx.x;
  int* cnt; int* tot; int k;
  if (col < NB){ cnt = cntS; tot = totS; k = col; }
  else         { cnt = cntD; tot = totD; k = col - NB; }
  __shared__ int tsum[256];
  int tid = threadIdx.x;
  int i0 = 2 * tid, i1 = 2 * tid + 1;
  int a = (i0 < nblk) ? cnt[i0 * 256 + k] : 0;
  int b = (i1 < nblk) ? cnt[i1 * 256 + k] : 0;
  int s = a + b;
  tsum[tid] = s;
  __syncthreads();
  for (int off = 1; off < 256; off <<= 1){
    int t = (tid >= off) ? tsum[tid - off] : 0;
    __syncthreads();
    tsum[tid] += t;
    __syncthreads();
  }
  int pre = tsum[tid] - s;
  if (i0 < nblk) cnt[i0 * 256 + k] = pre;
  if (i1 < nblk) cnt[i1 * 256 + k] = pre + a;
  if (tid == 255) tot[k] = tsum[255];
}

// exclusive scan of bucket totals -> bases (both sides)
__global__ __launch_bounds__(256) void k_basescan(const int* __restrict__ totS, const int* __restrict__ totD,
                                                  int* __restrict__ baseS, int* __restrict__ baseD, int NB){
  __shared__ int s1[256], s2[256];
  int tid = threadIdx.x;
  int v1 = (tid < NB) ? totS[tid] : 0;
  int v2 = (tid < NB) ? totD[tid] : 0;
  s1[tid] = v1; s2[tid] = v2;
  __syncthreads();
  for (int off = 1; off < 256; off <<= 1){
    int t1 = (tid >= off) ? s1[tid - off] : 0;
    int t2 = (tid >= off) ? s2[tid - off] : 0;
    __syncthreads();
    s1[tid] += t1; s2[tid] += t2;
    __syncthreads();
  }
  if (tid < NB){ baseS[tid] = s1[tid] - v1; baseD[tid] = s2[tid] - v2; }
}

// scatter with precomputed per-(block,bucket) offsets: zero global atomics
__global__ __launch_bounds__(256) void k_scatter_det(const int* __restrict__ src, const int* __restrict__ dst,
                                                     const int* __restrict__ cntS, const int* __restrict__ cntD,
                                                     const int* __restrict__ baseS, const int* __restrict__ baseD,
                                                     int2* __restrict__ pairD, int* __restrict__ srcS,
                                                     int n_edges, int NB){
  __shared__ int curS[256], curD[256];
  int tid = threadIdx.x;
  int b = blockIdx.x;
  if (tid < NB){
    curS[tid] = baseS[tid] + cntS[b * 256 + tid];
    curD[tid] = baseD[tid] + cntD[b * 256 + tid];
  }
  __syncthreads();
  int e0 = b * 4096, e1 = min(e0 + 4096, n_edges);
  for (int e = e0 + tid; e < e1; e += 256){
    int s = src[e], d = dst[e];
    int pd = atomicAdd(&curD[d >> 9], 1);
    pairD[pd] = make_int2(s, d);
    int ps = atomicAdd(&curS[s >> 9], 1);
    srcS[ps] = s;
  }
}

// per-bucket exact histograms (both sides) -> deg_in, din_s, dout_s
__global__ __launch_bounds__(256) void k_bucket_hists(const int2* __restrict__ pairD, const int* __restrict__ baseD,
                                                      const int* __restrict__ srcS, const int* __restrict__ baseS,
                                                      int* __restrict__ deg_in, float* __restrict__ din_s,
                                                      float* __restrict__ dout_s, int NB, int n, int n_edges){
  __shared__ int cd[512], cs[512];
  int b = blockIdx.x, node0 = b << 9, tid = threadIdx.x;
  int nn = min(512, n - node0);
  for (int i = tid; i < 512; i += 256){ cd[i] = 0; cs[i] = 0; }
  __syncthreads();
  int jd0 = baseD[b], jd1 = (b + 1 < NB) ? baseD[b + 1] : n_edges;
  for (int j = jd0 + tid; j < jd1; j += 256) atomicAdd(&cd[pairD[j].y - node0], 1);
  int js0 = baseS[b], js1 = (b + 1 < NB) ? baseS[b + 1] : n_edges;
  for (int j = js0 + tid; j < js1; j += 256) atomicAdd(&cs[srcS[j] - node0], 1);
  __syncthreads();
  for (int i = tid; i < nn; i += 256){
    int c = cd[i];
    deg_in[node0 + i] = c;
    din_s[node0 + i]  = 1.0f / sqrtf((float)max(c, 1));
    dout_s[node0 + i] = 1.0f / sqrtf((float)max(cs[i], 1));
  }
}

// ---------------- 3-phase device-wide exclusive scan of deg_in -> offs ----------------
__global__ __launch_bounds__(256) void k_scan_partial(const int* __restrict__ deg,
                                                      int* __restrict__ bs, int n){
  __shared__ int sm[256];
  int base = blockIdx.x * 4096;
  int s = 0;
#pragma unroll
  for (int it = 0; it < 16; ++it){
    int i = base + it * 256 + threadIdx.x;
    if (i < n) s += deg[i];
  }
  sm[threadIdx.x] = s;
  __syncthreads();
  for (int off = 128; off > 0; off >>= 1){
    if (threadIdx.x < off) sm[threadIdx.x] += sm[threadIdx.x + off];
    __syncthreads();
  }
  if (threadIdx.x == 0) bs[blockIdx.x] = sm[0];
}

__global__ __launch_bounds__(64) void k_scan_blocksums(int* __restrict__ bs, int nb,
                                                       int* __restrict__ offs, int n){
  __shared__ int sm[64];
  int tid = threadIdx.x;
  int v = (tid < nb) ? bs[tid] : 0;
  sm[tid] = v;
  __syncthreads();
  for (int off = 1; off < 64; off <<= 1){
    int t = (tid >= off) ? sm[tid - off] : 0;
    __syncthreads();
    sm[tid] += t;
    __syncthreads();
  }
  if (tid < nb) bs[tid] = sm[tid] - v;
  if (tid == 63) offs[n] = sm[63];
}

__global__ __launch_bounds__(256) void k_scan_write(const int* __restrict__ deg,
    const int* __restrict__ bs, int* __restrict__ offs, int n){
  __shared__ int vals[4096];
  __shared__ int tsum[256];
  int base = blockIdx.x * 4096;
#pragma unroll
  for (int it = 0; it < 16; ++it){
    int i = base + it * 256 + threadIdx.x;
    vals[it * 256 + threadIdx.x] = (i < n) ? deg[i] : 0;
  }
  __syncthreads();
  int t0 = threadIdx.x * 16;
  int loc[16];
  int s = 0;
#pragma unroll
  for (int k = 0; k < 16; ++k){ loc[k] = s; s += vals[t0 + k]; }
  tsum[threadIdx.x] = s;
  __syncthreads();
  for (int off = 1; off < 256; off <<= 1){
    int t = (threadIdx.x >= off) ? tsum[threadIdx.x - off] : 0;
    __syncthreads();
    tsum[threadIdx.x] += t;
    __syncthreads();
  }
  int pre = tsum[threadIdx.x] - s + bs[blockIdx.x];
  __syncthreads();
#pragma unroll
  for (int k = 0; k < 16; ++k) vals[t0 + k] = pre + loc[k];
  __syncthreads();
#pragma unroll
  for (int it = 0; it < 16; ++it){
    int i = base + it * 256 + threadIdx.x;
    if (i < n) offs[i] = vals[it * 256 + threadIdx.x];
  }
}

__global__ __launch_bounds__(256) void k_csrfill(const int2* __restrict__ pair, const int* __restrict__ offs,
                                                 int* __restrict__ csr_src, int n){
  __shared__ int cur[512];
  int node0 = blockIdx.x << 9;
  int nn = min(512, n - node0);
  for (int i = threadIdx.x; i < nn; i += 256) cur[i] = offs[node0 + i];
  __syncthreads();
  int j0 = offs[node0];
  int j1 = offs[min(node0 + 512, n)];
  for (int j = j0 + threadIdx.x; j < j1; j += 256){
    int2 e = pair[j];
    int p = atomicAdd(&cur[e.y - node0], 1);
    csr_src[p] = e.x;
  }
}

// ---------------- merged input prep: x->bf16, W1->Wt1, W2->Wt2 ----------------
__global__ __launch_bounds__(256) void k_prep(const float* __restrict__ x, unsigned int* __restrict__ xb,
                                              long long total4,
                                              const float* __restrict__ W1, unsigned short* __restrict__ Wt1,
                                              const float* __restrict__ W2, unsigned short* __restrict__ Wt2){
  long long t = (long long)blockIdx.x * 256 + threadIdx.x;
  if (t < total4){
    float4 v = ((const float4*)x)[t];
    xb[t * 2 + 0] = pack2(v.x, v.y);
    xb[t * 2 + 1] = pack2(v.z, v.w);
    return;
  }
  long long u = t - total4;
  if (u < 128 * 256){
    int k = (int)(u / 256), n = (int)(u % 256);
    Wt1[(size_t)n * 128 + k] = f2bf(W1[u]);
    return;
  }
  u -= 128 * 256;
  if (u < 256 * 64){
    int k = (int)(u / 64), n = (int)(u % 64);
    Wt2[(size_t)n * 256 + k] = f2bf(W2[u]);
  }
}

// ---------------- SpMM layer1 on bf16 x: 2 nodes/wave, uint2 lanes ----
__global__ __launch_bounds__(256) void k_spmm1(const unsigned int* __restrict__ xb,
    const int* __restrict__ offs, const int* __restrict__ csr_src,
    const float* __restrict__ dout_s, unsigned int* __restrict__ aggb, int n_nodes){
  int node = (blockIdx.x * blockDim.x + threadIdx.x) >> 5;
  int lane = threadIdx.x & 31;
  if (node >= n_nodes) return;
  int j0 = offs[node], j1 = offs[node + 1];
  const uint2* xp = (const uint2*)xb;
  float4 acc = make_float4(0.f, 0.f, 0.f, 0.f);
  int j = j0;
  for (; j + 4 <= j1; j += 4){
    int s0 = csr_src[j + 0];
    int s1 = csr_src[j + 1];
    int s2 = csr_src[j + 2];
    int s3 = csr_src[j + 3];
    float c0 = dout_s[s0];
    float c1 = dout_s[s1];
    float c2 = dout_s[s2];
    float c3 = dout_s[s3];
    uint2 v0 = xp[(size_t)s0 * 32 + lane];
    uint2 v1 = xp[(size_t)s1 * 32 + lane];
    uint2 v2 = xp[(size_t)s2 * 32 + lane];
    uint2 v3 = xp[(size_t)s3 * 32 + lane];
    acc.x = fmaf(bflo(v0.x), c0, acc.x); acc.y = fmaf(bfhi(v0.x), c0, acc.y);
    acc.z = fmaf(bflo(v0.y), c0, acc.z); acc.w = fmaf(bfhi(v0.y), c0, acc.w);
    acc.x = fmaf(bflo(v1.x), c1, acc.x); acc.y = fmaf(bfhi(v1.x), c1, acc.y);
    acc.z = fmaf(bflo(v1.y), c1, acc.z); acc.w = fmaf(bfhi(v1.y), c1, acc.w);
    acc.x = fmaf(bflo(v2.x), c2, acc.x); acc.y = fmaf(bfhi(v2.x), c2, acc.y);
    acc.z = fmaf(bflo(v2.y), c2, acc.z); acc.w = fmaf(bfhi(v2.y), c2, acc.w);
    acc.x = fmaf(bflo(v3.x), c3, acc.x); acc.y = fmaf(bfhi(v3.x), c3, acc.y);
    acc.z = fmaf(bflo(v3.y), c3, acc.z); acc.w = fmaf(bfhi(v3.y), c3, acc.w);
  }
  for (; j < j1; ++j){
    int s = csr_src[j];
    float sc = dout_s[s];
    uint2 v = xp[(size_t)s * 32 + lane];
    acc.x = fmaf(bflo(v.x), sc, acc.x); acc.y = fmaf(bfhi(v.x), sc, acc.y);
    acc.z = fmaf(bflo(v.y), sc, acc.z); acc.w = fmaf(bfhi(v.y), sc, acc.w);
  }
  uint2 pk;
  pk.x = pack2(acc.x, acc.y);
  pk.y = pack2(acc.z, acc.w);
  ((uint2*)aggb)[(size_t)node * 32 + lane] = pk;
}

// ---------------- SpMM layer2 on bf16 t2 ----
__global__ __launch_bounds__(256) void k_spmm2(const unsigned short* __restrict__ t2,
    const int* __restrict__ offs, const int* __restrict__ csr_src,
    const float* __restrict__ din_s, const float* __restrict__ b2,
    float* __restrict__ h2, int n_nodes){
  int node = (blockIdx.x * blockDim.x + threadIdx.x) >> 5;
  int lane = threadIdx.x & 31;
  if (node >= n_nodes) return;
  int j0 = offs[node], j1 = offs[node + 1];
  const unsigned int* tp = (const unsigned int*)t2;
  float ax = 0.f, ay = 0.f;
  int j = j0;
  for (; j + 4 <= j1; j += 4){
    int s0 = csr_src[j + 0];
    int s1 = csr_src[j + 1];
    int s2 = csr_src[j + 2];
    int s3 = csr_src[j + 3];
    unsigned int v0 = tp[(size_t)s0 * 32 + lane];
    unsigned int v1 = tp[(size_t)s1 * 32 + lane];
    unsigned int v2 = tp[(size_t)s2 * 32 + lane];
    unsigned int v3 = tp[(size_t)s3 * 32 + lane];
    ax += bflo(v0) + bflo(v1) + bflo(v2) + bflo(v3);
    ay += bfhi(v0) + bfhi(v1) + bfhi(v2) + bfhi(v3);
  }
  for (; j < j1; ++j){
    unsigned int v = tp[(size_t)csr_src[j] * 32 + lane];
    ax += bflo(v);
    ay += bfhi(v);
  }
  float ds = din_s[node];
  float2 bb = ((const float2*)b2)[lane];
  float2 r;
  r.x = fmaxf(fmaf(ax, ds, bb.x), 0.f);
  r.y = fmaxf(fmaf(ay, ds, bb.y), 0.f);
  ((float2*)h2)[(size_t)node * 32 + lane] = r;
}

// ---------------- MFMA bf16 GEMM ----------------
template<bool C_BF16, bool EPI, bool EPI2>
__global__ __launch_bounds__(256) void gemm_mfma(
    const unsigned short* __restrict__ A, const unsigned short* __restrict__ Bt, void* __restrict__ Cp,
    int M, int N, int K,
    const float* __restrict__ rowScaleC, const float* __restrict__ rowScaleC2,
    const float* __restrict__ bias){
  constexpr int BM = 128, BN = 64, BK = 128, LDA = 136;
  __shared__ __align__(16) unsigned short As[BM * LDA];
  __shared__ __align__(16) unsigned short Bs[BN * LDA];
  int tid = threadIdx.x;
  int bm0 = blockIdx.x * BM;
  int bn0 = blockIdx.y * BN;
  int wid = tid >> 6, lane = tid & 63;
  int wm = (wid >> 1) * 64, wn = (wid & 1) * 32;
  int quad = lane >> 4, l16 = lane & 15;
  f32x4 acc[4][2];
#pragma unroll
  for (int t = 0; t < 4; ++t)
#pragma unroll
    for (int u = 0; u < 2; ++u) acc[t][u] = f32x4{0.f, 0.f, 0.f, 0.f};

  for (int k0 = 0; k0 < K; k0 += BK){
#pragma unroll
    for (int it = 0; it < 16; ++it){
      int i = tid + it * 256;
      int m = i >> 5, c4 = i & 31;
      int gr = bm0 + m;
      uint2 pk = make_uint2(0u, 0u);
      if (gr < M) pk = *(const uint2*)(A + (size_t)gr * K + k0 + c4 * 4);
      *(uint2*)&As[m * LDA + c4 * 4] = pk;
    }
#pragma unroll
    for (int it = 0; it < 8; ++it){
      int i = tid + it * 256;
      int n = i >> 5, c4 = i & 31;
      uint2 v = *(const uint2*)(Bt + (size_t)(bn0 + n) * K + k0 + c4 * 4);
      *(uint2*)&Bs[n * LDA + c4 * 4] = v;
    }
    __syncthreads();
#pragma unroll
    for (int kc = 0; kc < 4; ++kc){
      bf16x8 af[4], bfr[2];
#pragma unroll
      for (int t = 0; t < 4; ++t)
        af[t] = *(const bf16x8*)&As[(wm + t * 16 + l16) * LDA + kc * 32 + quad * 8];
#pragma unroll
      for (int u = 0; u < 2; ++u)
        bfr[u] = *(const bf16x8*)&Bs[(wn + u * 16 + l16) * LDA + kc * 32 + quad * 8];
#pragma unroll
      for (int t = 0; t < 4; ++t)
#pragma unroll
        for (int u = 0; u < 2; ++u)
          acc[t][u] = __builtin_amdgcn_mfma_f32_16x16x32_bf16(af[t], bfr[u], acc[t][u], 0, 0, 0);
    }
    __syncthreads();
  }
  float bv[2] = {0.f, 0.f};
  if constexpr (EPI){ bv[0] = bias[bn0 + wn + l16]; bv[1] = bias[bn0 + wn + 16 + l16]; }
#pragma unroll
  for (int t = 0; t < 4; ++t){
#pragma unroll
    for (int r = 0; r < 4; ++r){
      int gr = bm0 + wm + t * 16 + quad * 4 + r;
      if (gr < M){
        float rs = 1.f, rs2 = 1.f;
        if constexpr (EPI)  rs  = rowScaleC[gr];
        if constexpr (EPI2) rs2 = rowScaleC2[gr];
#pragma unroll
        for (int u = 0; u < 2; ++u){
          int gc = bn0 + wn + u * 16 + l16;
          float cv = acc[t][u][r];
          if constexpr (EPI)  cv = fmaxf(fmaf(cv, rs, bv[u]), 0.f);
          if constexpr (EPI2) cv *= rs2;
          if constexpr (C_BF16) ((unsigned short*)Cp)[(size_t)gr * N + gc] = f2bf(cv);
          else                  ((float*)Cp)[(size_t)gr * N + gc] = cv;
        }
      }
    }
  }
}

// ---------------- per-graph mean-pool ----------------
__global__ __launch_bounds__(256) void k_pool(const float* __restrict__ h2, const int* __restrict__ gids,
                                              float* __restrict__ sums, int* __restrict__ cnts, int n_nodes){
  int wave = (blockIdx.x * blockDim.x + threadIdx.x) >> 6;
  int lane = threadIdx.x & 63;
  int base = wave * 64;
  if (base >= n_nodes) return;
  int endn = min(base + 64, n_nodes);
  float acc = 0.f;
  int cur = -1, len = 0;
  for (int i = base; i < endn; ++i){
    int g = gids[i];
    float v = h2[(size_t)i * 64 + lane];
    if (g != cur){
      if (cur >= 0){
        atomicAdd(&sums[(size_t)cur * 64 + lane], acc);
        if (lane == 0) atomicAdd(&cnts[cur], len);
      }
      cur = g; acc = 0.f; len = 0;
    }
    acc += v; len++;
  }
  atomicAdd(&sums[(size_t)cur * 64 + lane], acc);
  if (lane == 0) atomicAdd(&cnts[cur], len);
}

// ---------------- classifier ----------------
__global__ __launch_bounds__(256) void k_classifier(const float* __restrict__ sums, const int* __restrict__ cnts,
    const float* __restrict__ Wc1, const float* __restrict__ bc1,
    const float* __restrict__ Wc2, const float* __restrict__ bc2,
    const float* __restrict__ Wc3, const float* __restrict__ bc3,
    const float* __restrict__ Wc4, const float* __restrict__ bc4,
    float* __restrict__ out){
  __shared__ float w1[64 * 18], w2[18 * 12], w3[12 * 6], w4[6 * 2];
  __shared__ float B1[18], B2[12], B3[6], B4[2];
  int tid = threadIdx.x;
  for (int i = tid; i < 64 * 18; i += 256) w1[i] = Wc1[i];
  for (int i = tid; i < 18 * 12; i += 256) w2[i] = Wc2[i];
  for (int i = tid; i < 12 * 6;  i += 256) w3[i] = Wc3[i];
  for (int i = tid; i < 6 * 2;   i += 256) w4[i] = Wc4[i];
  if (tid < 18) B1[tid] = bc1[tid];
  if (tid < 12) B2[tid] = bc2[tid];
  if (tid < 6)  B3[tid] = bc3[tid];
  if (tid < 2)  B4[tid] = bc4[tid];
  __syncthreads();
  int g = blockIdx.x * 256 + tid;
  float cnt = fmaxf((float)cnts[g], 1.0f);
  float h[64];
#pragma unroll
  for (int f = 0; f < 64; ++f) h[f] = sums[(size_t)g * 64 + f] / cnt;
  float t1[18];
#pragma unroll
  for (int j = 0; j < 18; ++j){
    float s = B1[j];
    for (int f = 0; f < 64; ++f) s = fmaf(h[f], w1[f * 18 + j], s);
    t1[j] = s;
  }
  float t2[12];
#pragma unroll
  for (int j = 0; j < 12; ++j){
    float s = B2[j];
    for (int f = 0; f < 18; ++f) s = fmaf(t1[f], w2[f * 12 + j], s);
    t2[j] = s;
  }
  float t3[6];
#pragma unroll
  for (int j = 0; j < 6; ++j){
    float s = B3[j];
    for (int f = 0; f < 12; ++f) s = fmaf(t2[f], w3[f * 6 + j], s);
    t3[j] = s;
  }
#pragma unroll
  for (int j = 0; j < 2; ++j){
    float s = B4[j];
    for (int f = 0; f < 6; ++f) s = fmaf(t3[f], w4[f * 2 + j], s);
    out[(size_t)g * 2 + j] = s;
  }
}

extern "C" void kernel_launch(void* const* d_in, const int* in_sizes, int n_in,
                              void* d_out, int out_size, void* d_ws, size_t ws_size,
                              hipStream_t stream){
  const float* x   = (const float*)d_in[0];
  const int*   src = (const int*)d_in[1];
  const int*   dst = (const int*)d_in[2];
  const int*   gid = (const int*)d_in[3];
  const float* W1  = (const float*)d_in[4];
  const float* b1  = (const float*)d_in[5];
  const float* W2  = (const float*)d_in[6];
  const float* b2  = (const float*)d_in[7];
  const float* Wc1 = (const float*)d_in[8];
  const float* bc1 = (const float*)d_in[9];
  const float* Wc2 = (const float*)d_in[10];
  const float* bc2 = (const float*)d_in[11];
  const float* Wc3 = (const float*)d_in[12];
  const float* bc3 = (const float*)d_in[13];
  const float* Wc4 = (const float*)d_in[14];
  const float* bc4 = (const float*)d_in[15];
  float* out = (float*)d_out;

  const int n_nodes = in_sizes[3];
  const int n_edges = in_sizes[1];
  const int F1 = 256, F2 = 64;
  const int NB   = (n_nodes + 511) >> 9;      // 512-node buckets (<=256)
  const int NBLK = (n_edges + 4095) / 4096;   // 4096-edge chunks (<=512)

  char* w = (char*)d_ws;
  size_t o = 0;
  auto alloc = [&](size_t bytes) -> char* {
    char* p = w + o;
    o = align_up(o + bytes, 256);
    return p;
  };
  // ---- zero-initialized region ----
  float* sums      = (float*)alloc((size_t)NGRAPHS * F2 * 4);
  int*   cnts      = (int*)  alloc((size_t)NGRAPHS * 4);
  size_t zero_bytes = o;
  // ---- rest ----
  int*   cntS      = (int*)  alloc((size_t)NBLK * 256 * 4);
  int*   cntD      = (int*)  alloc((size_t)NBLK * 256 * 4);
  int*   totS      = (int*)  alloc((size_t)256 * 4);
  int*   totD      = (int*)  alloc((size_t)256 * 4);
  int*   baseS     = (int*)  alloc((size_t)256 * 4);
  int*   baseD     = (int*)  alloc((size_t)256 * 4);
  int*   deg_in    = (int*)  alloc((size_t)n_nodes * 4);
  float* dout_s    = (float*)alloc((size_t)n_nodes * 4);
  float* din_s     = (float*)alloc((size_t)n_nodes * 4);
  int*   offs      = (int*)  alloc((size_t)(n_nodes + 1) * 4);
  int*   block_sums= (int*)  alloc((size_t)64 * 4);
  int*   csr_src   = (int*)  alloc((size_t)n_edges * 4);
  unsigned short* Wt1 = (unsigned short*)alloc((size_t)256 * 128 * 2);
  unsigned short* Wt2 = (unsigned short*)alloc((size_t)64 * 256 * 2);
  unsigned int*   xb  = (unsigned int*)  alloc((size_t)n_nodes * 128 * 2);
  unsigned short* aggb= (unsigned short*)alloc((size_t)n_nodes * 128 * 2);
  unsigned short* h1b = (unsigned short*)alloc((size_t)n_nodes * F1 * 2);
  // aliases inside aggb region (consumed before spmm1 writes aggb)
  int2*  pairD = (int2*)aggb;
  int*   srcS  = (int*)((char*)aggb + (size_t)n_edges * 8);
  unsigned short* t2b = aggb;
  float* h2    = (float*)h1b;

  hipMemsetAsync(d_ws, 0, zero_bytes, stream);

  // merged input prep
  {
    long long total4 = (long long)n_nodes * 32;
    long long totalP = total4 + 128 * 256 + 256 * 64;
    k_prep<<<(int)((totalP + 255) / 256), 256, 0, stream>>>(x, xb, total4, W1, Wt1, W2, Wt2);
  }

  // deterministic radix partition
  k_partcount  <<<NBLK, 256, 0, stream>>>(src, dst, cntS, cntD, n_edges);
  k_colscan    <<<2 * NB, 256, 0, stream>>>(cntS, cntD, totS, totD, NBLK, NB);
  k_basescan   <<<1, 256, 0, stream>>>(totS, totD, baseS, baseD, NB);
  k_scatter_det<<<NBLK, 256, 0, stream>>>(src, dst, cntS, cntD, baseS, baseD, pairD, srcS, n_edges, NB);
  k_bucket_hists<<<NB, 256, 0, stream>>>(pairD, baseD, srcS, baseS, deg_in, din_s, dout_s, NB, n_nodes, n_edges);

  int nscan_blocks = (n_nodes + 4095) / 4096;
  k_scan_partial  <<<nscan_blocks, 256, 0, stream>>>(deg_in, block_sums, n_nodes);
  k_scan_blocksums<<<1, 64, 0, stream>>>(block_sums, nscan_blocks, offs, n_nodes);
  k_scan_write    <<<nscan_blocks, 256, 0, stream>>>(deg_in, block_sums, offs, n_nodes);

  k_csrfill<<<NB, 256, 0, stream>>>(pairD, offs, csr_src, n_nodes);

  int gx = (n_nodes + 127) / 128;
  // layer 1
  {
    long long threads = (long long)n_nodes * 32;
    k_spmm1<<<(int)((threads + 255) / 256), 256, 0, stream>>>(xb, offs, csr_src, dout_s, (unsigned int*)aggb, n_nodes);
    gemm_mfma<true, true, true><<<dim3(gx, F1 / 64), 256, 0, stream>>>(
        aggb, Wt1, h1b, n_nodes, F1, 128, din_s, dout_s, b1);
  }
  // layer 2
  {
    gemm_mfma<true, false, false><<<dim3(gx, 1), 256, 0, stream>>>(
        h1b, Wt2, t2b, n_nodes, F2, F1, nullptr, nullptr, nullptr);
    long long threads = (long long)n_nodes * 32;
    k_spmm2<<<(int)((threads + 255) / 256), 256, 0, stream>>>(t2b, offs, csr_src, din_s, b2, h2, n_nodes);
  }
  // pooling + classifier
  {
    int pool_waves = (n_nodes + 63) / 64;
    long long threads = (long long)pool_waves * 64;
    k_pool<<<(int)((threads + 255) / 256), 256, 0, stream>>>(h2, gid, sums, cnts, n_nodes);
    k_classifier<<<NGRAPHS / 256, 256, 0, stream>>>(sums, cnts, Wc1, bc1, Wc2, bc2, Wc3, bc3, Wc4, bc4, out);
  }
}

// Round 11
// 404.960 us; speedup vs baseline: 2.6422x; 1.0698x over previous
//
#include <hip/hip_runtime.h>
#include <cstdint>
#include <cstddef>

#define NGRAPHS 512

static inline size_t align_up(size_t x, size_t a){ return (x + a - 1) & ~(a - 1); }

// ---------------- bf16 helpers ----------------
__device__ __forceinline__ unsigned short f2bf(float f){
  unsigned int u = __float_as_uint(f);
  u += 0x7FFFu + ((u >> 16) & 1u);          // round-to-nearest-even
  return (unsigned short)(u >> 16);
}
__device__ __forceinline__ float bflo(unsigned int u){ return __uint_as_float(u << 16); }
__device__ __forceinline__ float bfhi(unsigned int u){ return __uint_as_float(u & 0xffff0000u); }
__device__ __forceinline__ unsigned int pack2(float a, float b){
  return (unsigned)f2bf(a) | ((unsigned)f2bf(b) << 16);
}

typedef __attribute__((ext_vector_type(8))) short bf16x8;
typedef __attribute__((ext_vector_type(4))) float f32x4;

// ================= deterministic radix partition (no global atomics) =================
__global__ __launch_bounds__(256) void k_partcount(const int* __restrict__ src, const int* __restrict__ dst,
                                                   int* __restrict__ cntS, int* __restrict__ cntD, int n_edges){
  __shared__ int cs[256], cd[256];
  int tid = threadIdx.x;
  cs[tid] = 0; cd[tid] = 0;
  __syncthreads();
  int e0 = blockIdx.x * 4096;
  int e1 = min(e0 + 4096, n_edges);
  for (int e = e0 + tid; e < e1; e += 256){
    atomicAdd(&cs[src[e] >> 9], 1);
    atomicAdd(&cd[dst[e] >> 9], 1);
  }
  __syncthreads();
  cntS[blockIdx.x * 256 + tid] = cs[tid];
  cntD[blockIdx.x * 256 + tid] = cd[tid];
}

__global__ __launch_bounds__(256) void k_colscan(int* __restrict__ cntS, int* __restrict__ cntD,
                                                 int* __restrict__ totS, int* __restrict__ totD,
                                                 int nblk, int NB){
  int col = blockIdx.x;
  int* cnt; int* tot; int k;
  if (col < NB){ cnt = cntS; tot = totS; k = col; }
  else         { cnt = cntD; tot = totD; k = col - NB; }
  __shared__ int tsum[256];
  int tid = threadIdx.x;
  int i0 = 2 * tid, i1 = 2 * tid + 1;
  int a = (i0 < nblk) ? cnt[i0 * 256 + k] : 0;
  int b = (i1 < nblk) ? cnt[i1 * 256 + k] : 0;
  int s = a + b;
  tsum[tid] = s;
  __syncthreads();
  for (int off = 1; off < 256; off <<= 1){
    int t = (tid >= off) ? tsum[tid - off] : 0;
    __syncthreads();
    tsum[tid] += t;
    __syncthreads();
  }
  int pre = tsum[tid] - s;
  if (i0 < nblk) cnt[i0 * 256 + k] = pre;
  if (i1 < nblk) cnt[i1 * 256 + k] = pre + a;
  if (tid == 255) tot[k] = tsum[255];
}

__global__ __launch_bounds__(256) void k_basescan(const int* __restrict__ totS, const int* __restrict__ totD,
                                                  int* __restrict__ baseS, int* __restrict__ baseD, int NB){
  __shared__ int s1[256], s2[256];
  int tid = threadIdx.x;
  int v1 = (tid < NB) ? totS[tid] : 0;
  int v2 = (tid < NB) ? totD[tid] : 0;
  s1[tid] = v1; s2[tid] = v2;
  __syncthreads();
  for (int off = 1; off < 256; off <<= 1){
    int t1 = (tid >= off) ? s1[tid - off] : 0;
    int t2 = (tid >= off) ? s2[tid - off] : 0;
    __syncthreads();
    s1[tid] += t1; s2[tid] += t2;
    __syncthreads();
  }
  if (tid < NB){ baseS[tid] = s1[tid] - v1; baseD[tid] = s2[tid] - v2; }
}

__global__ __launch_bounds__(256) void k_scatter_det(const int* __restrict__ src, const int* __restrict__ dst,
                                                     const int* __restrict__ cntS, const int* __restrict__ cntD,
                                                     const int* __restrict__ baseS, const int* __restrict__ baseD,
                                                     int2* __restrict__ pairD, int* __restrict__ srcS,
                                                     int n_edges, int NB){
  __shared__ int curS[256], curD[256];
  int tid = threadIdx.x;
  int b = blockIdx.x;
  if (tid < NB){
    curS[tid] = baseS[tid] + cntS[b * 256 + tid];
    curD[tid] = baseD[tid] + cntD[b * 256 + tid];
  }
  __syncthreads();
  int e0 = b * 4096, e1 = min(e0 + 4096, n_edges);
  for (int e = e0 + tid; e < e1; e += 256){
    int s = src[e], d = dst[e];
    int pd = atomicAdd(&curD[d >> 9], 1);
    pairD[pd] = make_int2(s, d);
    int ps = atomicAdd(&curS[s >> 9], 1);
    srcS[ps] = s;
  }
}

__global__ __launch_bounds__(256) void k_bucket_hists(const int2* __restrict__ pairD, const int* __restrict__ baseD,
                                                      const int* __restrict__ srcS, const int* __restrict__ baseS,
                                                      int* __restrict__ deg_in, float* __restrict__ din_s,
                                                      float* __restrict__ dout_s, int NB, int n, int n_edges){
  __shared__ int cd[512], cs[512];
  int b = blockIdx.x, node0 = b << 9, tid = threadIdx.x;
  int nn = min(512, n - node0);
  for (int i = tid; i < 512; i += 256){ cd[i] = 0; cs[i] = 0; }
  __syncthreads();
  int jd0 = baseD[b], jd1 = (b + 1 < NB) ? baseD[b + 1] : n_edges;
  for (int j = jd0 + tid; j < jd1; j += 256) atomicAdd(&cd[pairD[j].y - node0], 1);
  int js0 = baseS[b], js1 = (b + 1 < NB) ? baseS[b + 1] : n_edges;
  for (int j = js0 + tid; j < js1; j += 256) atomicAdd(&cs[srcS[j] - node0], 1);
  __syncthreads();
  for (int i = tid; i < nn; i += 256){
    int c = cd[i];
    deg_in[node0 + i] = c;
    din_s[node0 + i]  = 1.0f / sqrtf((float)max(c, 1));
    dout_s[node0 + i] = 1.0f / sqrtf((float)max(cs[i], 1));
  }
}

// ---------------- 3-phase device-wide exclusive scan of deg_in -> offs ----------------
__global__ __launch_bounds__(256) void k_scan_partial(const int* __restrict__ deg,
                                                      int* __restrict__ bs, int n){
  __shared__ int sm[256];
  int base = blockIdx.x * 4096;
  int s = 0;
#pragma unroll
  for (int it = 0; it < 16; ++it){
    int i = base + it * 256 + threadIdx.x;
    if (i < n) s += deg[i];
  }
  sm[threadIdx.x] = s;
  __syncthreads();
  for (int off = 128; off > 0; off >>= 1){
    if (threadIdx.x < off) sm[threadIdx.x] += sm[threadIdx.x + off];
    __syncthreads();
  }
  if (threadIdx.x == 0) bs[blockIdx.x] = sm[0];
}

__global__ __launch_bounds__(64) void k_scan_blocksums(int* __restrict__ bs, int nb,
                                                       int* __restrict__ offs, int n){
  __shared__ int sm[64];
  int tid = threadIdx.x;
  int v = (tid < nb) ? bs[tid] : 0;
  sm[tid] = v;
  __syncthreads();
  for (int off = 1; off < 64; off <<= 1){
    int t = (tid >= off) ? sm[tid - off] : 0;
    __syncthreads();
    sm[tid] += t;
    __syncthreads();
  }
  if (tid < nb) bs[tid] = sm[tid] - v;
  if (tid == 63) offs[n] = sm[63];
}

__global__ __launch_bounds__(256) void k_scan_write(const int* __restrict__ deg,
    const int* __restrict__ bs, int* __restrict__ offs, int n){
  __shared__ int vals[4096];
  __shared__ int tsum[256];
  int base = blockIdx.x * 4096;
#pragma unroll
  for (int it = 0; it < 16; ++it){
    int i = base + it * 256 + threadIdx.x;
    vals[it * 256 + threadIdx.x] = (i < n) ? deg[i] : 0;
  }
  __syncthreads();
  int t0 = threadIdx.x * 16;
  int loc[16];
  int s = 0;
#pragma unroll
  for (int k = 0; k < 16; ++k){ loc[k] = s; s += vals[t0 + k]; }
  tsum[threadIdx.x] = s;
  __syncthreads();
  for (int off = 1; off < 256; off <<= 1){
    int t = (threadIdx.x >= off) ? tsum[threadIdx.x - off] : 0;
    __syncthreads();
    tsum[threadIdx.x] += t;
    __syncthreads();
  }
  int pre = tsum[threadIdx.x] - s + bs[blockIdx.x];
  __syncthreads();
#pragma unroll
  for (int k = 0; k < 16; ++k) vals[t0 + k] = pre + loc[k];
  __syncthreads();
#pragma unroll
  for (int it = 0; it < 16; ++it){
    int i = base + it * 256 + threadIdx.x;
    if (i < n) offs[i] = vals[it * 256 + threadIdx.x];
  }
}

__global__ __launch_bounds__(256) void k_csrfill(const int2* __restrict__ pair, const int* __restrict__ offs,
                                                 int* __restrict__ csr_src, int n){
  __shared__ int cur[512];
  int node0 = blockIdx.x << 9;
  int nn = min(512, n - node0);
  for (int i = threadIdx.x; i < nn; i += 256) cur[i] = offs[node0 + i];
  __syncthreads();
  int j0 = offs[node0];
  int j1 = offs[min(node0 + 512, n)];
  for (int j = j0 + threadIdx.x; j < j1; j += 256){
    int2 e = pair[j];
    int p = atomicAdd(&cur[e.y - node0], 1);
    csr_src[p] = e.x;
  }
}

// ---------------- merged input prep: x->bf16, W1->Wt1, W2->Wt2 ----------------
__global__ __launch_bounds__(256) void k_prep(const float* __restrict__ x, unsigned int* __restrict__ xb,
                                              long long total4,
                                              const float* __restrict__ W1, unsigned short* __restrict__ Wt1,
                                              const float* __restrict__ W2, unsigned short* __restrict__ Wt2){
  long long t = (long long)blockIdx.x * 256 + threadIdx.x;
  if (t < total4){
    float4 v = ((const float4*)x)[t];
    xb[t * 2 + 0] = pack2(v.x, v.y);
    xb[t * 2 + 1] = pack2(v.z, v.w);
    return;
  }
  long long u = t - total4;
  if (u < 128 * 256){
    int k = (int)(u / 256), n = (int)(u % 256);
    Wt1[(size_t)n * 128 + k] = f2bf(W1[u]);
    return;
  }
  u -= 128 * 256;
  if (u < 256 * 64){
    int k = (int)(u / 64), n = (int)(u % 64);
    Wt2[(size_t)n * 256 + k] = f2bf(W2[u]);
  }
}

// ---------------- SpMM layer1 on bf16 x: 2 nodes/wave, uint2 lanes ----
__global__ __launch_bounds__(256) void k_spmm1(const unsigned int* __restrict__ xb,
    const int* __restrict__ offs, const int* __restrict__ csr_src,
    const float* __restrict__ dout_s, unsigned int* __restrict__ aggb, int n_nodes){
  int node = (blockIdx.x * blockDim.x + threadIdx.x) >> 5;
  int lane = threadIdx.x & 31;
  if (node >= n_nodes) return;
  int j0 = offs[node], j1 = offs[node + 1];
  const uint2* xp = (const uint2*)xb;
  float4 acc = make_float4(0.f, 0.f, 0.f, 0.f);
  int j = j0;
  for (; j + 4 <= j1; j += 4){
    int s0 = csr_src[j + 0];
    int s1 = csr_src[j + 1];
    int s2 = csr_src[j + 2];
    int s3 = csr_src[j + 3];
    float c0 = dout_s[s0];
    float c1 = dout_s[s1];
    float c2 = dout_s[s2];
    float c3 = dout_s[s3];
    uint2 v0 = xp[(size_t)s0 * 32 + lane];
    uint2 v1 = xp[(size_t)s1 * 32 + lane];
    uint2 v2 = xp[(size_t)s2 * 32 + lane];
    uint2 v3 = xp[(size_t)s3 * 32 + lane];
    acc.x = fmaf(bflo(v0.x), c0, acc.x); acc.y = fmaf(bfhi(v0.x), c0, acc.y);
    acc.z = fmaf(bflo(v0.y), c0, acc.z); acc.w = fmaf(bfhi(v0.y), c0, acc.w);
    acc.x = fmaf(bflo(v1.x), c1, acc.x); acc.y = fmaf(bfhi(v1.x), c1, acc.y);
    acc.z = fmaf(bflo(v1.y), c1, acc.z); acc.w = fmaf(bfhi(v1.y), c1, acc.w);
    acc.x = fmaf(bflo(v2.x), c2, acc.x); acc.y = fmaf(bfhi(v2.x), c2, acc.y);
    acc.z = fmaf(bflo(v2.y), c2, acc.z); acc.w = fmaf(bfhi(v2.y), c2, acc.w);
    acc.x = fmaf(bflo(v3.x), c3, acc.x); acc.y = fmaf(bfhi(v3.x), c3, acc.y);
    acc.z = fmaf(bflo(v3.y), c3, acc.z); acc.w = fmaf(bfhi(v3.y), c3, acc.w);
  }
  for (; j < j1; ++j){
    int s = csr_src[j];
    float sc = dout_s[s];
    uint2 v = xp[(size_t)s * 32 + lane];
    acc.x = fmaf(bflo(v.x), sc, acc.x); acc.y = fmaf(bfhi(v.x), sc, acc.y);
    acc.z = fmaf(bflo(v.y), sc, acc.z); acc.w = fmaf(bfhi(v.y), sc, acc.w);
  }
  uint2 pk;
  pk.x = pack2(acc.x, acc.y);
  pk.y = pack2(acc.z, acc.w);
  ((uint2*)aggb)[(size_t)node * 32 + lane] = pk;
}

// ---------------- SpMM layer2 on bf16 t2 ----
__global__ __launch_bounds__(256) void k_spmm2(const unsigned short* __restrict__ t2,
    const int* __restrict__ offs, const int* __restrict__ csr_src,
    const float* __restrict__ din_s, const float* __restrict__ b2,
    float* __restrict__ h2, int n_nodes){
  int node = (blockIdx.x * blockDim.x + threadIdx.x) >> 5;
  int lane = threadIdx.x & 31;
  if (node >= n_nodes) return;
  int j0 = offs[node], j1 = offs[node + 1];
  const unsigned int* tp = (const unsigned int*)t2;
  float ax = 0.f, ay = 0.f;
  int j = j0;
  for (; j + 4 <= j1; j += 4){
    int s0 = csr_src[j + 0];
    int s1 = csr_src[j + 1];
    int s2 = csr_src[j + 2];
    int s3 = csr_src[j + 3];
    unsigned int v0 = tp[(size_t)s0 * 32 + lane];
    unsigned int v1 = tp[(size_t)s1 * 32 + lane];
    unsigned int v2 = tp[(size_t)s2 * 32 + lane];
    unsigned int v3 = tp[(size_t)s3 * 32 + lane];
    ax += bflo(v0) + bflo(v1) + bflo(v2) + bflo(v3);
    ay += bfhi(v0) + bfhi(v1) + bfhi(v2) + bfhi(v3);
  }
  for (; j < j1; ++j){
    unsigned int v = tp[(size_t)csr_src[j] * 32 + lane];
    ax += bflo(v);
    ay += bfhi(v);
  }
  float ds = din_s[node];
  float2 bb = ((const float2*)b2)[lane];
  float2 r;
  r.x = fmaxf(fmaf(ax, ds, bb.x), 0.f);
  r.y = fmaxf(fmaf(ay, ds, bb.y), 0.f);
  ((float2*)h2)[(size_t)node * 32 + lane] = r;
}

// ---------------- MFMA bf16 GEMM: BK=32, double-buffered LDS, register-preload pipeline ----
// A: bf16 row-major [M][K]. Bt: bf16 n-major [N][K]. Block tile 128x64, 4 waves 2x2.
template<bool C_BF16, bool EPI, bool EPI2>
__global__ __launch_bounds__(256) void gemm_mfma(
    const unsigned short* __restrict__ A, const unsigned short* __restrict__ Bt, void* __restrict__ Cp,
    int M, int N, int K,
    const float* __restrict__ rowScaleC, const float* __restrict__ rowScaleC2,
    const float* __restrict__ bias){
  constexpr int BM = 128, BN = 64, BK = 32, LDA = 40;   // 40-short stride: conflict-free rotation
  __shared__ __align__(16) unsigned short As[2][BM * LDA];
  __shared__ __align__(16) unsigned short Bs[2][BN * LDA];
  int tid = threadIdx.x;
  int bm0 = blockIdx.x * BM;
  int bn0 = blockIdx.y * BN;
  int wid = tid >> 6, lane = tid & 63;
  int wm = (wid >> 1) * 64, wn = (wid & 1) * 32;
  int quad = lane >> 4, l16 = lane & 15;
  f32x4 acc[4][2];
#pragma unroll
  for (int t = 0; t < 4; ++t)
#pragma unroll
    for (int u = 0; u < 2; ++u) acc[t][u] = f32x4{0.f, 0.f, 0.f, 0.f};

  uint2 ar[4], br[2];
  auto preload = [&](int kk){
#pragma unroll
    for (int it = 0; it < 4; ++it){
      int i = tid + it * 256;
      int m = i >> 3, c = i & 7;
      int gr = bm0 + m;
      ar[it] = (gr < M) ? *(const uint2*)(A + (size_t)gr * K + kk + c * 4) : make_uint2(0u, 0u);
    }
#pragma unroll
    for (int it = 0; it < 2; ++it){
      int i = tid + it * 256;
      int n = i >> 3, c = i & 7;
      br[it] = *(const uint2*)(Bt + (size_t)(bn0 + n) * K + kk + c * 4);
    }
  };
  auto commit = [&](int buf){
#pragma unroll
    for (int it = 0; it < 4; ++it){
      int i = tid + it * 256;
      int m = i >> 3, c = i & 7;
      *(uint2*)&As[buf][m * LDA + c * 4] = ar[it];
    }
#pragma unroll
    for (int it = 0; it < 2; ++it){
      int i = tid + it * 256;
      int n = i >> 3, c = i & 7;
      *(uint2*)&Bs[buf][n * LDA + c * 4] = br[it];
    }
  };

  preload(0);
  commit(0);
  __syncthreads();
  int nk = K / BK;
  for (int kb = 0; kb < nk; ++kb){
    int cur = kb & 1;
    if (kb + 1 < nk) preload((kb + 1) * BK);   // global->regs for next slice (latency overlapped)
    bf16x8 af[4], bfr[2];
#pragma unroll
    for (int t = 0; t < 4; ++t)
      af[t] = *(const bf16x8*)&As[cur][(wm + t * 16 + l16) * LDA + quad * 8];
#pragma unroll
    for (int u = 0; u < 2; ++u)
      bfr[u] = *(const bf16x8*)&Bs[cur][(wn + u * 16 + l16) * LDA + quad * 8];
#pragma unroll
    for (int t = 0; t < 4; ++t)
#pragma unroll
      for (int u = 0; u < 2; ++u)
        acc[t][u] = __builtin_amdgcn_mfma_f32_16x16x32_bf16(af[t], bfr[u], acc[t][u], 0, 0, 0);
    if (kb + 1 < nk){
      commit(cur ^ 1);
      __syncthreads();
    }
  }
  float bv[2] = {0.f, 0.f};
  if constexpr (EPI){ bv[0] = bias[bn0 + wn + l16]; bv[1] = bias[bn0 + wn + 16 + l16]; }
#pragma unroll
  for (int t = 0; t < 4; ++t){
#pragma unroll
    for (int r = 0; r < 4; ++r){
      int gr = bm0 + wm + t * 16 + quad * 4 + r;
      if (gr < M){
        float rs = 1.f, rs2 = 1.f;
        if constexpr (EPI)  rs  = rowScaleC[gr];
        if constexpr (EPI2) rs2 = rowScaleC2[gr];
#pragma unroll
        for (int u = 0; u < 2; ++u){
          int gc = bn0 + wn + u * 16 + l16;
          float cv = acc[t][u][r];
          if constexpr (EPI)  cv = fmaxf(fmaf(cv, rs, bv[u]), 0.f);
          if constexpr (EPI2) cv *= rs2;
          if constexpr (C_BF16) ((unsigned short*)Cp)[(size_t)gr * N + gc] = f2bf(cv);
          else                  ((float*)Cp)[(size_t)gr * N + gc] = cv;
        }
      }
    }
  }
}

// ---------------- per-graph mean-pool ----------------
__global__ __launch_bounds__(256) void k_pool(const float* __restrict__ h2, const int* __restrict__ gids,
                                              float* __restrict__ sums, int* __restrict__ cnts, int n_nodes){
  int wave = (blockIdx.x * blockDim.x + threadIdx.x) >> 6;
  int lane = threadIdx.x & 63;
  int base = wave * 64;
  if (base >= n_nodes) return;
  int endn = min(base + 64, n_nodes);
  float acc = 0.f;
  int cur = -1, len = 0;
  for (int i = base; i < endn; ++i){
    int g = gids[i];
    float v = h2[(size_t)i * 64 + lane];
    if (g != cur){
      if (cur >= 0){
        atomicAdd(&sums[(size_t)cur * 64 + lane], acc);
        if (lane == 0) atomicAdd(&cnts[cur], len);
      }
      cur = g; acc = 0.f; len = 0;
    }
    acc += v; len++;
  }
  atomicAdd(&sums[(size_t)cur * 64 + lane], acc);
  if (lane == 0) atomicAdd(&cnts[cur], len);
}

// ---------------- classifier ----------------
__global__ __launch_bounds__(256) void k_classifier(const float* __restrict__ sums, const int* __restrict__ cnts,
    const float* __restrict__ Wc1, const float* __restrict__ bc1,
    const float* __restrict__ Wc2, const float* __restrict__ bc2,
    const float* __restrict__ Wc3, const float* __restrict__ bc3,
    const float* __restrict__ Wc4, const float* __restrict__ bc4,
    float* __restrict__ out){
  __shared__ float w1[64 * 18], w2[18 * 12], w3[12 * 6], w4[6 * 2];
  __shared__ float B1[18], B2[12], B3[6], B4[2];
  int tid = threadIdx.x;
  for (int i = tid; i < 64 * 18; i += 256) w1[i] = Wc1[i];
  for (int i = tid; i < 18 * 12; i += 256) w2[i] = Wc2[i];
  for (int i = tid; i < 12 * 6;  i += 256) w3[i] = Wc3[i];
  for (int i = tid; i < 6 * 2;   i += 256) w4[i] = Wc4[i];
  if (tid < 18) B1[tid] = bc1[tid];
  if (tid < 12) B2[tid] = bc2[tid];
  if (tid < 6)  B3[tid] = bc3[tid];
  if (tid < 2)  B4[tid] = bc4[tid];
  __syncthreads();
  int g = blockIdx.x * 256 + tid;
  float cnt = fmaxf((float)cnts[g], 1.0f);
  float h[64];
#pragma unroll
  for (int f = 0; f < 64; ++f) h[f] = sums[(size_t)g * 64 + f] / cnt;
  float t1[18];
#pragma unroll
  for (int j = 0; j < 18; ++j){
    float s = B1[j];
    for (int f = 0; f < 64; ++f) s = fmaf(h[f], w1[f * 18 + j], s);
    t1[j] = s;
  }
  float t2[12];
#pragma unroll
  for (int j = 0; j < 12; ++j){
    float s = B2[j];
    for (int f = 0; f < 18; ++f) s = fmaf(t1[f], w2[f * 12 + j], s);
    t2[j] = s;
  }
  float t3[6];
#pragma unroll
  for (int j = 0; j < 6; ++j){
    float s = B3[j];
    for (int f = 0; f < 12; ++f) s = fmaf(t2[f], w3[f * 6 + j], s);
    t3[j] = s;
  }
#pragma unroll
  for (int j = 0; j < 2; ++j){
    float s = B4[j];
    for (int f = 0; f < 6; ++f) s = fmaf(t3[f], w4[f * 2 + j], s);
    out[(size_t)g * 2 + j] = s;
  }
}

extern "C" void kernel_launch(void* const* d_in, const int* in_sizes, int n_in,
                              void* d_out, int out_size, void* d_ws, size_t ws_size,
                              hipStream_t stream){
  const float* x   = (const float*)d_in[0];
  const int*   src = (const int*)d_in[1];
  const int*   dst = (const int*)d_in[2];
  const int*   gid = (const int*)d_in[3];
  const float* W1  = (const float*)d_in[4];
  const float* b1  = (const float*)d_in[5];
  const float* W2  = (const float*)d_in[6];
  const float* b2  = (const float*)d_in[7];
  const float* Wc1 = (const float*)d_in[8];
  const float* bc1 = (const float*)d_in[9];
  const float* Wc2 = (const float*)d_in[10];
  const float* bc2 = (const float*)d_in[11];
  const float* Wc3 = (const float*)d_in[12];
  const float* bc3 = (const float*)d_in[13];
  const float* Wc4 = (const float*)d_in[14];
  const float* bc4 = (const float*)d_in[15];
  float* out = (float*)d_out;

  const int n_nodes = in_sizes[3];
  const int n_edges = in_sizes[1];
  const int F1 = 256, F2 = 64;
  const int NB   = (n_nodes + 511) >> 9;
  const int NBLK = (n_edges + 4095) / 4096;

  char* w = (char*)d_ws;
  size_t o = 0;
  auto alloc = [&](size_t bytes) -> char* {
    char* p = w + o;
    o = align_up(o + bytes, 256);
    return p;
  };
  // ---- zero-initialized region ----
  float* sums      = (float*)alloc((size_t)NGRAPHS * F2 * 4);
  int*   cnts      = (int*)  alloc((size_t)NGRAPHS * 4);
  size_t zero_bytes = o;
  // ---- rest ----
  int*   cntS      = (int*)  alloc((size_t)NBLK * 256 * 4);
  int*   cntD      = (int*)  alloc((size_t)NBLK * 256 * 4);
  int*   totS      = (int*)  alloc((size_t)256 * 4);
  int*   totD      = (int*)  alloc((size_t)256 * 4);
  int*   baseS     = (int*)  alloc((size_t)256 * 4);
  int*   baseD     = (int*)  alloc((size_t)256 * 4);
  int*   deg_in    = (int*)  alloc((size_t)n_nodes * 4);
  float* dout_s    = (float*)alloc((size_t)n_nodes * 4);
  float* din_s     = (float*)alloc((size_t)n_nodes * 4);
  int*   offs      = (int*)  alloc((size_t)(n_nodes + 1) * 4);
  int*   block_sums= (int*)  alloc((size_t)64 * 4);
  int*   csr_src   = (int*)  alloc((size_t)n_edges * 4);
  unsigned short* Wt1 = (unsigned short*)alloc((size_t)256 * 128 * 2);
  unsigned short* Wt2 = (unsigned short*)alloc((size_t)64 * 256 * 2);
  unsigned int*   xb  = (unsigned int*)  alloc((size_t)n_nodes * 128 * 2);
  unsigned short* aggb= (unsigned short*)alloc((size_t)n_nodes * 128 * 2);
  unsigned short* h1b = (unsigned short*)alloc((size_t)n_nodes * F1 * 2);
  int2*  pairD = (int2*)aggb;
  int*   srcS  = (int*)((char*)aggb + (size_t)n_edges * 8);
  unsigned short* t2b = aggb;
  float* h2    = (float*)h1b;

  hipMemsetAsync(d_ws, 0, zero_bytes, stream);

  {
    long long total4 = (long long)n_nodes * 32;
    long long totalP = total4 + 128 * 256 + 256 * 64;
    k_prep<<<(int)((totalP + 255) / 256), 256, 0, stream>>>(x, xb, total4, W1, Wt1, W2, Wt2);
  }

  k_partcount  <<<NBLK, 256, 0, stream>>>(src, dst, cntS, cntD, n_edges);
  k_colscan    <<<2 * NB, 256, 0, stream>>>(cntS, cntD, totS, totD, NBLK, NB);
  k_basescan   <<<1, 256, 0, stream>>>(totS, totD, baseS, baseD, NB);
  k_scatter_det<<<NBLK, 256, 0, stream>>>(src, dst, cntS, cntD, baseS, baseD, pairD, srcS, n_edges, NB);
  k_bucket_hists<<<NB, 256, 0, stream>>>(pairD, baseD, srcS, baseS, deg_in, din_s, dout_s, NB, n_nodes, n_edges);

  int nscan_blocks = (n_nodes + 4095) / 4096;
  k_scan_partial  <<<nscan_blocks, 256, 0, stream>>>(deg_in, block_sums, n_nodes);
  k_scan_blocksums<<<1, 64, 0, stream>>>(block_sums, nscan_blocks, offs, n_nodes);
  k_scan_write    <<<nscan_blocks, 256, 0, stream>>>(deg_in, block_sums, offs, n_nodes);

  k_csrfill<<<NB, 256, 0, stream>>>(pairD, offs, csr_src, n_nodes);

  int gx = (n_nodes + 127) / 128;
  // layer 1
  {
    long long threads = (long long)n_nodes * 32;
    k_spmm1<<<(int)((threads + 255) / 256), 256, 0, stream>>>(xb, offs, csr_src, dout_s, (unsigned int*)aggb, n_nodes);
    gemm_mfma<true, true, true><<<dim3(gx, F1 / 64), 256, 0, stream>>>(
        aggb, Wt1, h1b, n_nodes, F1, 128, din_s, dout_s, b1);
  }
  // layer 2
  {
    gemm_mfma<true, false, false><<<dim3(gx, 1), 256, 0, stream>>>(
        h1b, Wt2, t2b, n_nodes, F2, F1, nullptr, nullptr, nullptr);
    long long threads = (long long)n_nodes * 32;
    k_spmm2<<<(int)((threads + 255) / 256), 256, 0, stream>>>(t2b, offs, csr_src, din_s, b2, h2, n_nodes);
  }
  // pooling + classifier
  {
    int pool_waves = (n_nodes + 63) / 64;
    long long threads = (long long)pool_waves * 64;
    k_pool<<<(int)((threads + 255) / 256), 256, 0, stream>>>(h2, gid, sums, cnts, n_nodes);
    k_classifier<<<NGRAPHS / 256, 256, 0, stream>>>(sums, cnts, Wc1, bc1, Wc2, bc2, Wc3, bc3, Wc4, bc4, out);
  }
}

// Round 12
// 381.048 us; speedup vs baseline: 2.8080x; 1.0628x over previous
//
#include <hip/hip_runtime.h>
#include <cstdint>
#include <cstddef>

#define NGRAPHS 512

static inline size_t align_up(size_t x, size_t a){ return (x + a - 1) & ~(a - 1); }

// ---------------- bf16 helpers ----------------
__device__ __forceinline__ unsigned short f2bf(float f){
  unsigned int u = __float_as_uint(f);
  u += 0x7FFFu + ((u >> 16) & 1u);          // round-to-nearest-even
  return (unsigned short)(u >> 16);
}
__device__ __forceinline__ float bflo(unsigned int u){ return __uint_as_float(u << 16); }
__device__ __forceinline__ float bfhi(unsigned int u){ return __uint_as_float(u & 0xffff0000u); }
__device__ __forceinline__ unsigned int pack2(float a, float b){
  return (unsigned)f2bf(a) | ((unsigned)f2bf(b) << 16);
}

typedef __attribute__((ext_vector_type(8))) short bf16x8;
typedef __attribute__((ext_vector_type(4))) float f32x4;

// ================= deterministic radix partition (no global atomics) =================
__global__ __launch_bounds__(256) void k_partcount(const int* __restrict__ src, const int* __restrict__ dst,
                                                   int* __restrict__ cntS, int* __restrict__ cntD, int n_edges){
  __shared__ int cs[256], cd[256];
  int tid = threadIdx.x;
  cs[tid] = 0; cd[tid] = 0;
  __syncthreads();
  int e0 = blockIdx.x * 4096;
  int e1 = min(e0 + 4096, n_edges);
  for (int e = e0 + tid; e < e1; e += 256){
    atomicAdd(&cs[src[e] >> 9], 1);
    atomicAdd(&cd[dst[e] >> 9], 1);
  }
  __syncthreads();
  cntS[blockIdx.x * 256 + tid] = cs[tid];
  cntD[blockIdx.x * 256 + tid] = cd[tid];
}

// per-bucket column scan over blocks (in-place exclusive) + totals
__global__ __launch_bounds__(256) void k_colscan(int* __restrict__ cntS, int* __restrict__ cntD,
                                                 int* __restrict__ totS, int* __restrict__ totD,
                                                 int nblk, int NB){
  int col = blockIdx.x;
  int* cnt; int* tot; int k;
  if (col < NB){ cnt = cntS; tot = totS; k = col; }
  else         { cnt = cntD; tot = totD; k = col - NB; }
  __shared__ int tsum[256];
  int tid = threadIdx.x;
  int i0 = 2 * tid, i1 = 2 * tid + 1;
  int a = (i0 < nblk) ? cnt[i0 * 256 + k] : 0;
  int b = (i1 < nblk) ? cnt[i1 * 256 + k] : 0;
  int s = a + b;
  tsum[tid] = s;
  __syncthreads();
  for (int off = 1; off < 256; off <<= 1){
    int t = (tid >= off) ? tsum[tid - off] : 0;
    __syncthreads();
    tsum[tid] += t;
    __syncthreads();
  }
  int pre = tsum[tid] - s;
  if (i0 < nblk) cnt[i0 * 256 + k] = pre;
  if (i1 < nblk) cnt[i1 * 256 + k] = pre + a;
  if (tid == 255) tot[k] = tsum[255];
}

// scatter with in-block base scan (basescan fused); block 0 persists bases for bucket_build
__global__ __launch_bounds__(256) void k_scatter_det(const int* __restrict__ src, const int* __restrict__ dst,
                                                     const int* __restrict__ cntS, const int* __restrict__ cntD,
                                                     const int* __restrict__ totS, const int* __restrict__ totD,
                                                     int* __restrict__ baseS, int* __restrict__ baseD,
                                                     int2* __restrict__ pairD, int* __restrict__ srcS,
                                                     int n_edges, int NB){
  __shared__ int s1[256], s2[256], curS[256], curD[256];
  int tid = threadIdx.x;
  int b = blockIdx.x;
  int v1 = (tid < NB) ? totS[tid] : 0;
  int v2 = (tid < NB) ? totD[tid] : 0;
  s1[tid] = v1; s2[tid] = v2;
  __syncthreads();
  for (int off = 1; off < 256; off <<= 1){
    int t1 = (tid >= off) ? s1[tid - off] : 0;
    int t2 = (tid >= off) ? s2[tid - off] : 0;
    __syncthreads();
    s1[tid] += t1; s2[tid] += t2;
    __syncthreads();
  }
  int bS = s1[tid] - v1, bD = s2[tid] - v2;
  if (b == 0 && tid < NB){ baseS[tid] = bS; baseD[tid] = bD; }
  curS[tid] = bS + cntS[b * 256 + tid];
  curD[tid] = bD + cntD[b * 256 + tid];
  __syncthreads();
  int e0 = b * 4096, e1 = min(e0 + 4096, n_edges);
  for (int e = e0 + tid; e < e1; e += 256){
    int s = src[e], d = dst[e];
    int pd = atomicAdd(&curD[d >> 9], 1);
    pairD[pd] = make_int2(s, d);
    int ps = atomicAdd(&curS[s >> 9], 1);
    srcS[ps] = s;
  }
}

// fused per-bucket: dst/src histograms -> offs (in-block scan) + din_s/dout_s + counting-sort csr fill
__global__ __launch_bounds__(256) void k_bucket_build(const int2* __restrict__ pairD, const int* __restrict__ baseD,
                                                      const int* __restrict__ srcS, const int* __restrict__ baseS,
                                                      int* __restrict__ offs, float* __restrict__ din_s,
                                                      float* __restrict__ dout_s, int* __restrict__ csr_src,
                                                      int NB, int n, int n_edges){
  __shared__ int cd[512], cs[512], cur[512];
  __shared__ int tsum[256];
  int b = blockIdx.x, node0 = b << 9, tid = threadIdx.x;
  int nn = min(512, n - node0);
  for (int i = tid; i < 512; i += 256){ cd[i] = 0; cs[i] = 0; }
  __syncthreads();
  int jd0 = baseD[b], jd1 = (b + 1 < NB) ? baseD[b + 1] : n_edges;
  for (int j = jd0 + tid; j < jd1; j += 256) atomicAdd(&cd[pairD[j].y - node0], 1);
  int js0 = baseS[b], js1 = (b + 1 < NB) ? baseS[b + 1] : n_edges;
  for (int j = js0 + tid; j < js1; j += 256) atomicAdd(&cs[srcS[j] - node0], 1);
  __syncthreads();
  // in-block exclusive scan of cd[0..511] -> cur (global CSR positions; baseD[b] == jd0)
  int a0 = cd[2 * tid], a1 = cd[2 * tid + 1];
  int s = a0 + a1;
  tsum[tid] = s;
  __syncthreads();
  for (int off = 1; off < 256; off <<= 1){
    int t = (tid >= off) ? tsum[tid - off] : 0;
    __syncthreads();
    tsum[tid] += t;
    __syncthreads();
  }
  int pre = tsum[tid] - s + jd0;
  cur[2 * tid]     = pre;
  cur[2 * tid + 1] = pre + a0;
  __syncthreads();
  for (int i = tid; i < nn; i += 256){
    offs[node0 + i]   = cur[i];
    din_s[node0 + i]  = 1.0f / sqrtf((float)max(cd[i], 1));
    dout_s[node0 + i] = 1.0f / sqrtf((float)max(cs[i], 1));
  }
  if (b == NB - 1 && tid == 0) offs[n] = n_edges;
  __syncthreads();
  // counting sort into csr (cursors in LDS; zero global atomics)
  for (int j = jd0 + tid; j < jd1; j += 256){
    int2 e = pairD[j];
    int p = atomicAdd(&cur[e.y - node0], 1);
    csr_src[p] = e.x;
  }
}

// ---------------- merged input prep: x->bf16, W1->Wt1, W2->Wt2, zero sums/cnts ----------------
__global__ __launch_bounds__(256) void k_prep(const float* __restrict__ x, unsigned int* __restrict__ xb,
                                              long long total4,
                                              const float* __restrict__ W1, unsigned short* __restrict__ Wt1,
                                              const float* __restrict__ W2, unsigned short* __restrict__ Wt2,
                                              float* __restrict__ sums, int* __restrict__ cnts){
  long long t = (long long)blockIdx.x * 256 + threadIdx.x;
  if (t < total4){
    float4 v = ((const float4*)x)[t];
    xb[t * 2 + 0] = pack2(v.x, v.y);
    xb[t * 2 + 1] = pack2(v.z, v.w);
    return;
  }
  long long u = t - total4;
  if (u < 128 * 256){
    int k = (int)(u / 256), n = (int)(u % 256);
    Wt1[(size_t)n * 128 + k] = f2bf(W1[u]);
    return;
  }
  u -= 128 * 256;
  if (u < 256 * 64){
    int k = (int)(u / 64), n = (int)(u % 64);
    Wt2[(size_t)n * 256 + k] = f2bf(W2[u]);
    return;
  }
  u -= 256 * 64;
  if (u < (long long)NGRAPHS * 64){ sums[u] = 0.f; return; }
  u -= (long long)NGRAPHS * 64;
  if (u < NGRAPHS) cnts[u] = 0;
}

// ---------------- SpMM layer1 on bf16 x: 2 nodes/wave, uint2 lanes ----
__global__ __launch_bounds__(256) void k_spmm1(const unsigned int* __restrict__ xb,
    const int* __restrict__ offs, const int* __restrict__ csr_src,
    const float* __restrict__ dout_s, unsigned int* __restrict__ aggb, int n_nodes){
  int node = (blockIdx.x * blockDim.x + threadIdx.x) >> 5;
  int lane = threadIdx.x & 31;
  if (node >= n_nodes) return;
  int j0 = offs[node], j1 = offs[node + 1];
  const uint2* xp = (const uint2*)xb;
  float4 acc = make_float4(0.f, 0.f, 0.f, 0.f);
  int j = j0;
  for (; j + 4 <= j1; j += 4){
    int s0 = csr_src[j + 0];
    int s1 = csr_src[j + 1];
    int s2 = csr_src[j + 2];
    int s3 = csr_src[j + 3];
    float c0 = dout_s[s0];
    float c1 = dout_s[s1];
    float c2 = dout_s[s2];
    float c3 = dout_s[s3];
    uint2 v0 = xp[(size_t)s0 * 32 + lane];
    uint2 v1 = xp[(size_t)s1 * 32 + lane];
    uint2 v2 = xp[(size_t)s2 * 32 + lane];
    uint2 v3 = xp[(size_t)s3 * 32 + lane];
    acc.x = fmaf(bflo(v0.x), c0, acc.x); acc.y = fmaf(bfhi(v0.x), c0, acc.y);
    acc.z = fmaf(bflo(v0.y), c0, acc.z); acc.w = fmaf(bfhi(v0.y), c0, acc.w);
    acc.x = fmaf(bflo(v1.x), c1, acc.x); acc.y = fmaf(bfhi(v1.x), c1, acc.y);
    acc.z = fmaf(bflo(v1.y), c1, acc.z); acc.w = fmaf(bfhi(v1.y), c1, acc.w);
    acc.x = fmaf(bflo(v2.x), c2, acc.x); acc.y = fmaf(bfhi(v2.x), c2, acc.y);
    acc.z = fmaf(bflo(v2.y), c2, acc.z); acc.w = fmaf(bfhi(v2.y), c2, acc.w);
    acc.x = fmaf(bflo(v3.x), c3, acc.x); acc.y = fmaf(bfhi(v3.x), c3, acc.y);
    acc.z = fmaf(bflo(v3.y), c3, acc.z); acc.w = fmaf(bfhi(v3.y), c3, acc.w);
  }
  for (; j < j1; ++j){
    int s = csr_src[j];
    float sc = dout_s[s];
    uint2 v = xp[(size_t)s * 32 + lane];
    acc.x = fmaf(bflo(v.x), sc, acc.x); acc.y = fmaf(bfhi(v.x), sc, acc.y);
    acc.z = fmaf(bflo(v.y), sc, acc.z); acc.w = fmaf(bfhi(v.y), sc, acc.w);
  }
  uint2 pk;
  pk.x = pack2(acc.x, acc.y);
  pk.y = pack2(acc.z, acc.w);
  ((uint2*)aggb)[(size_t)node * 32 + lane] = pk;
}

// ---------------- SpMM layer2 on bf16 t2 ----
__global__ __launch_bounds__(256) void k_spmm2(const unsigned short* __restrict__ t2,
    const int* __restrict__ offs, const int* __restrict__ csr_src,
    const float* __restrict__ din_s, const float* __restrict__ b2,
    float* __restrict__ h2, int n_nodes){
  int node = (blockIdx.x * blockDim.x + threadIdx.x) >> 5;
  int lane = threadIdx.x & 31;
  if (node >= n_nodes) return;
  int j0 = offs[node], j1 = offs[node + 1];
  const unsigned int* tp = (const unsigned int*)t2;
  float ax = 0.f, ay = 0.f;
  int j = j0;
  for (; j + 4 <= j1; j += 4){
    int s0 = csr_src[j + 0];
    int s1 = csr_src[j + 1];
    int s2 = csr_src[j + 2];
    int s3 = csr_src[j + 3];
    unsigned int v0 = tp[(size_t)s0 * 32 + lane];
    unsigned int v1 = tp[(size_t)s1 * 32 + lane];
    unsigned int v2 = tp[(size_t)s2 * 32 + lane];
    unsigned int v3 = tp[(size_t)s3 * 32 + lane];
    ax += bflo(v0) + bflo(v1) + bflo(v2) + bflo(v3);
    ay += bfhi(v0) + bfhi(v1) + bfhi(v2) + bfhi(v3);
  }
  for (; j < j1; ++j){
    unsigned int v = tp[(size_t)csr_src[j] * 32 + lane];
    ax += bflo(v);
    ay += bfhi(v);
  }
  float ds = din_s[node];
  float2 bb = ((const float2*)b2)[lane];
  float2 r;
  r.x = fmaxf(fmaf(ax, ds, bb.x), 0.f);
  r.y = fmaxf(fmaf(ay, ds, bb.y), 0.f);
  ((float2*)h2)[(size_t)node * 32 + lane] = r;
}

// ---------------- MFMA bf16 GEMM: BK=32, double-buffered LDS, register-preload pipeline ----
template<bool C_BF16, bool EPI, bool EPI2>
__global__ __launch_bounds__(256) void gemm_mfma(
    const unsigned short* __restrict__ A, const unsigned short* __restrict__ Bt, void* __restrict__ Cp,
    int M, int N, int K,
    const float* __restrict__ rowScaleC, const float* __restrict__ rowScaleC2,
    const float* __restrict__ bias){
  constexpr int BM = 128, BN = 64, BK = 32, LDA = 40;
  __shared__ __align__(16) unsigned short As[2][BM * LDA];
  __shared__ __align__(16) unsigned short Bs[2][BN * LDA];
  int tid = threadIdx.x;
  int bm0 = blockIdx.x * BM;
  int bn0 = blockIdx.y * BN;
  int wid = tid >> 6, lane = tid & 63;
  int wm = (wid >> 1) * 64, wn = (wid & 1) * 32;
  int quad = lane >> 4, l16 = lane & 15;
  f32x4 acc[4][2];
#pragma unroll
  for (int t = 0; t < 4; ++t)
#pragma unroll
    for (int u = 0; u < 2; ++u) acc[t][u] = f32x4{0.f, 0.f, 0.f, 0.f};

  uint2 ar[4], br[2];
  auto preload = [&](int kk){
#pragma unroll
    for (int it = 0; it < 4; ++it){
      int i = tid + it * 256;
      int m = i >> 3, c = i & 7;
      int gr = bm0 + m;
      ar[it] = (gr < M) ? *(const uint2*)(A + (size_t)gr * K + kk + c * 4) : make_uint2(0u, 0u);
    }
#pragma unroll
    for (int it = 0; it < 2; ++it){
      int i = tid + it * 256;
      int n = i >> 3, c = i & 7;
      br[it] = *(const uint2*)(Bt + (size_t)(bn0 + n) * K + kk + c * 4);
    }
  };
  auto commit = [&](int buf){
#pragma unroll
    for (int it = 0; it < 4; ++it){
      int i = tid + it * 256;
      int m = i >> 3, c = i & 7;
      *(uint2*)&As[buf][m * LDA + c * 4] = ar[it];
    }
#pragma unroll
    for (int it = 0; it < 2; ++it){
      int i = tid + it * 256;
      int n = i >> 3, c = i & 7;
      *(uint2*)&Bs[buf][n * LDA + c * 4] = br[it];
    }
  };

  preload(0);
  commit(0);
  __syncthreads();
  int nk = K / BK;
  for (int kb = 0; kb < nk; ++kb){
    int cur = kb & 1;
    if (kb + 1 < nk) preload((kb + 1) * BK);
    bf16x8 af[4], bfr[2];
#pragma unroll
    for (int t = 0; t < 4; ++t)
      af[t] = *(const bf16x8*)&As[cur][(wm + t * 16 + l16) * LDA + quad * 8];
#pragma unroll
    for (int u = 0; u < 2; ++u)
      bfr[u] = *(const bf16x8*)&Bs[cur][(wn + u * 16 + l16) * LDA + quad * 8];
#pragma unroll
    for (int t = 0; t < 4; ++t)
#pragma unroll
      for (int u = 0; u < 2; ++u)
        acc[t][u] = __builtin_amdgcn_mfma_f32_16x16x32_bf16(af[t], bfr[u], acc[t][u], 0, 0, 0);
    if (kb + 1 < nk){
      commit(cur ^ 1);
      __syncthreads();
    }
  }
  float bv[2] = {0.f, 0.f};
  if constexpr (EPI){ bv[0] = bias[bn0 + wn + l16]; bv[1] = bias[bn0 + wn + 16 + l16]; }
#pragma unroll
  for (int t = 0; t < 4; ++t){
#pragma unroll
    for (int r = 0; r < 4; ++r){
      int gr = bm0 + wm + t * 16 + quad * 4 + r;
      if (gr < M){
        float rs = 1.f, rs2 = 1.f;
        if constexpr (EPI)  rs  = rowScaleC[gr];
        if constexpr (EPI2) rs2 = rowScaleC2[gr];
#pragma unroll
        for (int u = 0; u < 2; ++u){
          int gc = bn0 + wn + u * 16 + l16;
          float cv = acc[t][u][r];
          if constexpr (EPI)  cv = fmaxf(fmaf(cv, rs, bv[u]), 0.f);
          if constexpr (EPI2) cv *= rs2;
          if constexpr (C_BF16) ((unsigned short*)Cp)[(size_t)gr * N + gc] = f2bf(cv);
          else                  ((float*)Cp)[(size_t)gr * N + gc] = cv;
        }
      }
    }
  }
}

// ---------------- per-graph mean-pool ----------------
__global__ __launch_bounds__(256) void k_pool(const float* __restrict__ h2, const int* __restrict__ gids,
                                              float* __restrict__ sums, int* __restrict__ cnts, int n_nodes){
  int wave = (blockIdx.x * blockDim.x + threadIdx.x) >> 6;
  int lane = threadIdx.x & 63;
  int base = wave * 64;
  if (base >= n_nodes) return;
  int endn = min(base + 64, n_nodes);
  float acc = 0.f;
  int cur = -1, len = 0;
  for (int i = base; i < endn; ++i){
    int g = gids[i];
    float v = h2[(size_t)i * 64 + lane];
    if (g != cur){
      if (cur >= 0){
        atomicAdd(&sums[(size_t)cur * 64 + lane], acc);
        if (lane == 0) atomicAdd(&cnts[cur], len);
      }
      cur = g; acc = 0.f; len = 0;
    }
    acc += v; len++;
  }
  atomicAdd(&sums[(size_t)cur * 64 + lane], acc);
  if (lane == 0) atomicAdd(&cnts[cur], len);
}

// ---------------- classifier ----------------
__global__ __launch_bounds__(256) void k_classifier(const float* __restrict__ sums, const int* __restrict__ cnts,
    const float* __restrict__ Wc1, const float* __restrict__ bc1,
    const float* __restrict__ Wc2, const float* __restrict__ bc2,
    const float* __restrict__ Wc3, const float* __restrict__ bc3,
    const float* __restrict__ Wc4, const float* __restrict__ bc4,
    float* __restrict__ out){
  __shared__ float w1[64 * 18], w2[18 * 12], w3[12 * 6], w4[6 * 2];
  __shared__ float B1[18], B2[12], B3[6], B4[2];
  int tid = threadIdx.x;
  for (int i = tid; i < 64 * 18; i += 256) w1[i] = Wc1[i];
  for (int i = tid; i < 18 * 12; i += 256) w2[i] = Wc2[i];
  for (int i = tid; i < 12 * 6;  i += 256) w3[i] = Wc3[i];
  for (int i = tid; i < 6 * 2;   i += 256) w4[i] = Wc4[i];
  if (tid < 18) B1[tid] = bc1[tid];
  if (tid < 12) B2[tid] = bc2[tid];
  if (tid < 6)  B3[tid] = bc3[tid];
  if (tid < 2)  B4[tid] = bc4[tid];
  __syncthreads();
  int g = blockIdx.x * 256 + tid;
  float cnt = fmaxf((float)cnts[g], 1.0f);
  float h[64];
#pragma unroll
  for (int f = 0; f < 64; ++f) h[f] = sums[(size_t)g * 64 + f] / cnt;
  float t1[18];
#pragma unroll
  for (int j = 0; j < 18; ++j){
    float s = B1[j];
    for (int f = 0; f < 64; ++f) s = fmaf(h[f], w1[f * 18 + j], s);
    t1[j] = s;
  }
  float t2[12];
#pragma unroll
  for (int j = 0; j < 12; ++j){
    float s = B2[j];
    for (int f = 0; f < 18; ++f) s = fmaf(t1[f], w2[f * 12 + j], s);
    t2[j] = s;
  }
  float t3[6];
#pragma unroll
  for (int j = 0; j < 6; ++j){
    float s = B3[j];
    for (int f = 0; f < 12; ++f) s = fmaf(t2[f], w3[f * 6 + j], s);
    t3[j] = s;
  }
#pragma unroll
  for (int j = 0; j < 2; ++j){
    float s = B4[j];
    for (int f = 0; f < 6; ++f) s = fmaf(t3[f], w4[f * 2 + j], s);
    out[(size_t)g * 2 + j] = s;
  }
}

extern "C" void kernel_launch(void* const* d_in, const int* in_sizes, int n_in,
                              void* d_out, int out_size, void* d_ws, size_t ws_size,
                              hipStream_t stream){
  const float* x   = (const float*)d_in[0];
  const int*   src = (const int*)d_in[1];
  const int*   dst = (const int*)d_in[2];
  const int*   gid = (const int*)d_in[3];
  const float* W1  = (const float*)d_in[4];
  const float* b1  = (const float*)d_in[5];
  const float* W2  = (const float*)d_in[6];
  const float* b2  = (const float*)d_in[7];
  const float* Wc1 = (const float*)d_in[8];
  const float* bc1 = (const float*)d_in[9];
  const float* Wc2 = (const float*)d_in[10];
  const float* bc2 = (const float*)d_in[11];
  const float* Wc3 = (const float*)d_in[12];
  const float* bc3 = (const float*)d_in[13];
  const float* Wc4 = (const float*)d_in[14];
  const float* bc4 = (const float*)d_in[15];
  float* out = (float*)d_out;

  const int n_nodes = in_sizes[3];
  const int n_edges = in_sizes[1];
  const int F1 = 256, F2 = 64;
  const int NB   = (n_nodes + 511) >> 9;
  const int NBLK = (n_edges + 4095) / 4096;

  char* w = (char*)d_ws;
  size_t o = 0;
  auto alloc = [&](size_t bytes) -> char* {
    char* p = w + o;
    o = align_up(o + bytes, 256);
    return p;
  };
  float* sums      = (float*)alloc((size_t)NGRAPHS * F2 * 4);
  int*   cnts      = (int*)  alloc((size_t)NGRAPHS * 4);
  int*   cntS      = (int*)  alloc((size_t)NBLK * 256 * 4);
  int*   cntD      = (int*)  alloc((size_t)NBLK * 256 * 4);
  int*   totS      = (int*)  alloc((size_t)256 * 4);
  int*   totD      = (int*)  alloc((size_t)256 * 4);
  int*   baseS     = (int*)  alloc((size_t)256 * 4);
  int*   baseD     = (int*)  alloc((size_t)256 * 4);
  float* dout_s    = (float*)alloc((size_t)n_nodes * 4);
  float* din_s     = (float*)alloc((size_t)n_nodes * 4);
  int*   offs      = (int*)  alloc((size_t)(n_nodes + 1) * 4);
  int*   csr_src   = (int*)  alloc((size_t)n_edges * 4);
  unsigned short* Wt1 = (unsigned short*)alloc((size_t)256 * 128 * 2);
  unsigned short* Wt2 = (unsigned short*)alloc((size_t)64 * 256 * 2);
  unsigned int*   xb  = (unsigned int*)  alloc((size_t)n_nodes * 128 * 2);
  unsigned short* aggb= (unsigned short*)alloc((size_t)n_nodes * 128 * 2);
  unsigned short* h1b = (unsigned short*)alloc((size_t)n_nodes * F1 * 2);
  // aliases inside aggb region (consumed before spmm1 writes aggb)
  int2*  pairD = (int2*)aggb;
  int*   srcS  = (int*)((char*)aggb + (size_t)n_edges * 8);
  unsigned short* t2b = aggb;
  float* h2    = (float*)h1b;

  // prep (also zeroes sums/cnts — replaces hipMemsetAsync)
  {
    long long total4 = (long long)n_nodes * 32;
    long long totalP = total4 + 128 * 256 + 256 * 64 + (long long)NGRAPHS * 64 + NGRAPHS;
    k_prep<<<(int)((totalP + 255) / 256), 256, 0, stream>>>(x, xb, total4, W1, Wt1, W2, Wt2, sums, cnts);
  }

  // deterministic radix partition + fused CSR build
  k_partcount   <<<NBLK, 256, 0, stream>>>(src, dst, cntS, cntD, n_edges);
  k_colscan     <<<2 * NB, 256, 0, stream>>>(cntS, cntD, totS, totD, NBLK, NB);
  k_scatter_det <<<NBLK, 256, 0, stream>>>(src, dst, cntS, cntD, totS, totD, baseS, baseD, pairD, srcS, n_edges, NB);
  k_bucket_build<<<NB, 256, 0, stream>>>(pairD, baseD, srcS, baseS, offs, din_s, dout_s, csr_src, NB, n_nodes, n_edges);

  int gx = (n_nodes + 127) / 128;
  // layer 1
  {
    long long threads = (long long)n_nodes * 32;
    k_spmm1<<<(int)((threads + 255) / 256), 256, 0, stream>>>(xb, offs, csr_src, dout_s, (unsigned int*)aggb, n_nodes);
    gemm_mfma<true, true, true><<<dim3(gx, F1 / 64), 256, 0, stream>>>(
        aggb, Wt1, h1b, n_nodes, F1, 128, din_s, dout_s, b1);
  }
  // layer 2
  {
    gemm_mfma<true, false, false><<<dim3(gx, 1), 256, 0, stream>>>(
        h1b, Wt2, t2b, n_nodes, F2, F1, nullptr, nullptr, nullptr);
    long long threads = (long long)n_nodes * 32;
    k_spmm2<<<(int)((threads + 255) / 256), 256, 0, stream>>>(t2b, offs, csr_src, din_s, b2, h2, n_nodes);
  }
  // pooling + classifier
  {
    int pool_waves = (n_nodes + 63) / 64;
    long long threads = (long long)pool_waves * 64;
    k_pool<<<(int)((threads + 255) / 256), 256, 0, stream>>>(h2, gid, sums, cnts, n_nodes);
    k_classifier<<<NGRAPHS / 256, 256, 0, stream>>>(sums, cnts, Wc1, bc1, Wc2, bc2, Wc3, bc3, Wc4, bc4, out);
  }
}

// Round 13
// 363.576 us; speedup vs baseline: 2.9430x; 1.0481x over previous
//
#include <hip/hip_runtime.h>
#include <cstdint>
#include <cstddef>

#define NGRAPHS 512

static inline size_t align_up(size_t x, size_t a){ return (x + a - 1) & ~(a - 1); }

// ---------------- bf16 helpers ----------------
__device__ __forceinline__ unsigned short f2bf(float f){
  unsigned int u = __float_as_uint(f);
  u += 0x7FFFu + ((u >> 16) & 1u);          // round-to-nearest-even
  return (unsigned short)(u >> 16);
}
__device__ __forceinline__ float bflo(unsigned int u){ return __uint_as_float(u << 16); }
__device__ __forceinline__ float bfhi(unsigned int u){ return __uint_as_float(u & 0xffff0000u); }
__device__ __forceinline__ unsigned int pack2(float a, float b){
  return (unsigned)f2bf(a) | ((unsigned)f2bf(b) << 16);
}

typedef __attribute__((ext_vector_type(8))) short bf16x8;
typedef __attribute__((ext_vector_type(4))) float f32x4;

// ================= deterministic radix partition (no global atomics) =================
__global__ __launch_bounds__(256) void k_partcount(const int* __restrict__ src, const int* __restrict__ dst,
                                                   int* __restrict__ cntS, int* __restrict__ cntD, int n_edges){
  __shared__ int cs[256], cd[256];
  int tid = threadIdx.x;
  cs[tid] = 0; cd[tid] = 0;
  __syncthreads();
  int e0 = blockIdx.x * 4096;
  int e1 = min(e0 + 4096, n_edges);
  for (int e = e0 + tid; e < e1; e += 256){
    atomicAdd(&cs[src[e] >> 9], 1);
    atomicAdd(&cd[dst[e] >> 9], 1);
  }
  __syncthreads();
  cntS[blockIdx.x * 256 + tid] = cs[tid];
  cntD[blockIdx.x * 256 + tid] = cd[tid];
}

__global__ __launch_bounds__(256) void k_colscan(int* __restrict__ cntS, int* __restrict__ cntD,
                                                 int* __restrict__ totS, int* __restrict__ totD,
                                                 int nblk, int NB){
  int col = blockIdx.x;
  int* cnt; int* tot; int k;
  if (col < NB){ cnt = cntS; tot = totS; k = col; }
  else         { cnt = cntD; tot = totD; k = col - NB; }
  __shared__ int tsum[256];
  int tid = threadIdx.x;
  int i0 = 2 * tid, i1 = 2 * tid + 1;
  int a = (i0 < nblk) ? cnt[i0 * 256 + k] : 0;
  int b = (i1 < nblk) ? cnt[i1 * 256 + k] : 0;
  int s = a + b;
  tsum[tid] = s;
  __syncthreads();
  for (int off = 1; off < 256; off <<= 1){
    int t = (tid >= off) ? tsum[tid - off] : 0;
    __syncthreads();
    tsum[tid] += t;
    __syncthreads();
  }
  int pre = tsum[tid] - s;
  if (i0 < nblk) cnt[i0 * 256 + k] = pre;
  if (i1 < nblk) cnt[i1 * 256 + k] = pre + a;
  if (tid == 255) tot[k] = tsum[255];
}

__global__ __launch_bounds__(256) void k_scatter_det(const int* __restrict__ src, const int* __restrict__ dst,
                                                     const int* __restrict__ cntS, const int* __restrict__ cntD,
                                                     const int* __restrict__ totS, const int* __restrict__ totD,
                                                     int* __restrict__ baseS, int* __restrict__ baseD,
                                                     int2* __restrict__ pairD, int* __restrict__ srcS,
                                                     int n_edges, int NB){
  __shared__ int s1[256], s2[256], curS[256], curD[256];
  int tid = threadIdx.x;
  int b = blockIdx.x;
  int v1 = (tid < NB) ? totS[tid] : 0;
  int v2 = (tid < NB) ? totD[tid] : 0;
  s1[tid] = v1; s2[tid] = v2;
  __syncthreads();
  for (int off = 1; off < 256; off <<= 1){
    int t1 = (tid >= off) ? s1[tid - off] : 0;
    int t2 = (tid >= off) ? s2[tid - off] : 0;
    __syncthreads();
    s1[tid] += t1; s2[tid] += t2;
    __syncthreads();
  }
  int bS = s1[tid] - v1, bD = s2[tid] - v2;
  if (b == 0 && tid < NB){ baseS[tid] = bS; baseD[tid] = bD; }
  curS[tid] = bS + cntS[b * 256 + tid];
  curD[tid] = bD + cntD[b * 256 + tid];
  __syncthreads();
  int e0 = b * 4096, e1 = min(e0 + 4096, n_edges);
  for (int e = e0 + tid; e < e1; e += 256){
    int s = src[e], d = dst[e];
    int pd = atomicAdd(&curD[d >> 9], 1);
    pairD[pd] = make_int2(s, d);
    int ps = atomicAdd(&curS[s >> 9], 1);
    srcS[ps] = s;
  }
}

// fused per-bucket: histograms -> offs (in-block scan) + din_s/dout_s + counting-sort csr fill
__global__ __launch_bounds__(256) void k_bucket_build(const int2* __restrict__ pairD, const int* __restrict__ baseD,
                                                      const int* __restrict__ srcS, const int* __restrict__ baseS,
                                                      int* __restrict__ offs, float* __restrict__ din_s,
                                                      float* __restrict__ dout_s, int* __restrict__ csr_src,
                                                      int NB, int n, int n_edges){
  __shared__ int cd[512], cs[512], cur[512];
  __shared__ int tsum[256];
  int b = blockIdx.x, node0 = b << 9, tid = threadIdx.x;
  int nn = min(512, n - node0);
  for (int i = tid; i < 512; i += 256){ cd[i] = 0; cs[i] = 0; }
  __syncthreads();
  int jd0 = baseD[b], jd1 = (b + 1 < NB) ? baseD[b + 1] : n_edges;
  for (int j = jd0 + tid; j < jd1; j += 256) atomicAdd(&cd[pairD[j].y - node0], 1);
  int js0 = baseS[b], js1 = (b + 1 < NB) ? baseS[b + 1] : n_edges;
  for (int j = js0 + tid; j < js1; j += 256) atomicAdd(&cs[srcS[j] - node0], 1);
  __syncthreads();
  int a0 = cd[2 * tid], a1 = cd[2 * tid + 1];
  int s = a0 + a1;
  tsum[tid] = s;
  __syncthreads();
  for (int off = 1; off < 256; off <<= 1){
    int t = (tid >= off) ? tsum[tid - off] : 0;
    __syncthreads();
    tsum[tid] += t;
    __syncthreads();
  }
  int pre = tsum[tid] - s + jd0;
  cur[2 * tid]     = pre;
  cur[2 * tid + 1] = pre + a0;
  __syncthreads();
  for (int i = tid; i < nn; i += 256){
    offs[node0 + i]   = cur[i];
    din_s[node0 + i]  = 1.0f / sqrtf((float)max(cd[i], 1));
    dout_s[node0 + i] = 1.0f / sqrtf((float)max(cs[i], 1));
  }
  if (b == NB - 1 && tid == 0) offs[n] = n_edges;
  __syncthreads();
  for (int j = jd0 + tid; j < jd1; j += 256){
    int2 e = pairD[j];
    int p = atomicAdd(&cur[e.y - node0], 1);
    csr_src[p] = e.x;
  }
}

// ---------------- merged input prep: x->bf16, W1->Wt1, W2->Wt2, zero sums, graph bounds ----------------
__global__ __launch_bounds__(256) void k_prep(const float* __restrict__ x, unsigned int* __restrict__ xb,
                                              long long total4,
                                              const float* __restrict__ W1, unsigned short* __restrict__ Wt1,
                                              const float* __restrict__ W2, unsigned short* __restrict__ Wt2,
                                              float* __restrict__ sums,
                                              const int* __restrict__ gids, int* __restrict__ gb, int n_nodes){
  long long t = (long long)blockIdx.x * 256 + threadIdx.x;
  if (t < total4){
    float4 v = ((const float4*)x)[t];
    xb[t * 2 + 0] = pack2(v.x, v.y);
    xb[t * 2 + 1] = pack2(v.z, v.w);
    return;
  }
  long long u = t - total4;
  if (u < 128 * 256){
    int k = (int)(u / 256), n = (int)(u % 256);
    Wt1[(size_t)n * 128 + k] = f2bf(W1[u]);
    return;
  }
  u -= 128 * 256;
  if (u < 256 * 64){
    int k = (int)(u / 64), n = (int)(u % 64);
    Wt2[(size_t)n * 256 + k] = f2bf(W2[u]);
    return;
  }
  u -= 256 * 64;
  if (u < (long long)NGRAPHS * 64){ sums[u] = 0.f; return; }
  u -= (long long)NGRAPHS * 64;
  if (u < n_nodes){
    int i = (int)u;
    int g  = gids[i];
    int gp = (i > 0) ? gids[i - 1] : -1;
    for (int q = gp + 1; q <= g; ++q) gb[q] = i;       // sorted ids: gb[q] = first idx with gids >= q
    if (i == n_nodes - 1)
      for (int q = g + 1; q <= NGRAPHS; ++q) gb[q] = n_nodes;
  }
}

// ---------------- SpMM layer1 on bf16 x: 2 nodes/wave, uint2 lanes ----
__global__ __launch_bounds__(256) void k_spmm1(const unsigned int* __restrict__ xb,
    const int* __restrict__ offs, const int* __restrict__ csr_src,
    const float* __restrict__ dout_s, unsigned int* __restrict__ aggb, int n_nodes){
  int node = (blockIdx.x * blockDim.x + threadIdx.x) >> 5;
  int lane = threadIdx.x & 31;
  if (node >= n_nodes) return;
  int j0 = offs[node], j1 = offs[node + 1];
  const uint2* xp = (const uint2*)xb;
  float4 acc = make_float4(0.f, 0.f, 0.f, 0.f);
  int j = j0;
  for (; j + 4 <= j1; j += 4){
    int s0 = csr_src[j + 0];
    int s1 = csr_src[j + 1];
    int s2 = csr_src[j + 2];
    int s3 = csr_src[j + 3];
    float c0 = dout_s[s0];
    float c1 = dout_s[s1];
    float c2 = dout_s[s2];
    float c3 = dout_s[s3];
    uint2 v0 = xp[(size_t)s0 * 32 + lane];
    uint2 v1 = xp[(size_t)s1 * 32 + lane];
    uint2 v2 = xp[(size_t)s2 * 32 + lane];
    uint2 v3 = xp[(size_t)s3 * 32 + lane];
    acc.x = fmaf(bflo(v0.x), c0, acc.x); acc.y = fmaf(bfhi(v0.x), c0, acc.y);
    acc.z = fmaf(bflo(v0.y), c0, acc.z); acc.w = fmaf(bfhi(v0.y), c0, acc.w);
    acc.x = fmaf(bflo(v1.x), c1, acc.x); acc.y = fmaf(bfhi(v1.x), c1, acc.y);
    acc.z = fmaf(bflo(v1.y), c1, acc.z); acc.w = fmaf(bfhi(v1.y), c1, acc.w);
    acc.x = fmaf(bflo(v2.x), c2, acc.x); acc.y = fmaf(bfhi(v2.x), c2, acc.y);
    acc.z = fmaf(bflo(v2.y), c2, acc.z); acc.w = fmaf(bfhi(v2.y), c2, acc.w);
    acc.x = fmaf(bflo(v3.x), c3, acc.x); acc.y = fmaf(bfhi(v3.x), c3, acc.y);
    acc.z = fmaf(bflo(v3.y), c3, acc.z); acc.w = fmaf(bfhi(v3.y), c3, acc.w);
  }
  for (; j < j1; ++j){
    int s = csr_src[j];
    float sc = dout_s[s];
    uint2 v = xp[(size_t)s * 32 + lane];
    acc.x = fmaf(bflo(v.x), sc, acc.x); acc.y = fmaf(bfhi(v.x), sc, acc.y);
    acc.z = fmaf(bflo(v.y), sc, acc.z); acc.w = fmaf(bfhi(v.y), sc, acc.w);
  }
  uint2 pk;
  pk.x = pack2(acc.x, acc.y);
  pk.y = pack2(acc.z, acc.w);
  ((uint2*)aggb)[(size_t)node * 32 + lane] = pk;
}

// ---------------- fused SpMM layer2 + per-graph mean-pool sums (h2 never materialized) ----
// grid = NGRAPHS * SCHUNK blocks; half-wave w of graph g handles nodes gb[g]+w, +32, ...
#define SCHUNK 4
__global__ __launch_bounds__(256) void k_spmm2_fused(const unsigned short* __restrict__ t2,
    const int* __restrict__ offs, const int* __restrict__ csr_src,
    const float* __restrict__ din_s, const float* __restrict__ b2,
    const int* __restrict__ gb, float* __restrict__ sums){
  __shared__ float bs[64];
  int tid = threadIdx.x;
  int g = blockIdx.x & (NGRAPHS - 1);
  int chunk = blockIdx.x >> 9;
  int hw = chunk * 8 + (tid >> 5);          // 0..31
  int lane = tid & 31;
  if (tid < 64) bs[tid] = 0.f;
  __syncthreads();
  int g0 = gb[g], g1 = gb[g + 1];
  const unsigned int* tp = (const unsigned int*)t2;
  float2 bb = ((const float2*)b2)[lane];
  float sx = 0.f, sy = 0.f;
  for (int node = g0 + hw; node < g1; node += 32){
    int j0 = offs[node], j1 = offs[node + 1];
    float ax = 0.f, ay = 0.f;
    int j = j0;
    for (; j + 4 <= j1; j += 4){
      int s0 = csr_src[j + 0];
      int s1 = csr_src[j + 1];
      int s2 = csr_src[j + 2];
      int s3 = csr_src[j + 3];
      unsigned int v0 = tp[(size_t)s0 * 32 + lane];
      unsigned int v1 = tp[(size_t)s1 * 32 + lane];
      unsigned int v2 = tp[(size_t)s2 * 32 + lane];
      unsigned int v3 = tp[(size_t)s3 * 32 + lane];
      ax += bflo(v0) + bflo(v1) + bflo(v2) + bflo(v3);
      ay += bfhi(v0) + bfhi(v1) + bfhi(v2) + bfhi(v3);
    }
    for (; j < j1; ++j){
      unsigned int v = tp[(size_t)csr_src[j] * 32 + lane];
      ax += bflo(v);
      ay += bfhi(v);
    }
    float ds = din_s[node];
    sx += fmaxf(fmaf(ax, ds, bb.x), 0.f);
    sy += fmaxf(fmaf(ay, ds, bb.y), 0.f);
  }
  atomicAdd(&bs[2 * lane], sx);
  atomicAdd(&bs[2 * lane + 1], sy);
  __syncthreads();
  if (tid < 64) atomicAdd(&sums[(size_t)g * 64 + tid], bs[tid]);
}

// ---------------- MFMA bf16 GEMM: BK=32, double-buffered LDS, register-preload pipeline ----
template<bool C_BF16, bool EPI, bool EPI2>
__global__ __launch_bounds__(256) void gemm_mfma(
    const unsigned short* __restrict__ A, const unsigned short* __restrict__ Bt, void* __restrict__ Cp,
    int M, int N, int K,
    const float* __restrict__ rowScaleC, const float* __restrict__ rowScaleC2,
    const float* __restrict__ bias){
  constexpr int BM = 128, BN = 64, BK = 32, LDA = 40;
  __shared__ __align__(16) unsigned short As[2][BM * LDA];
  __shared__ __align__(16) unsigned short Bs[2][BN * LDA];
  int tid = threadIdx.x;
  int bm0 = blockIdx.x * BM;
  int bn0 = blockIdx.y * BN;
  int wid = tid >> 6, lane = tid & 63;
  int wm = (wid >> 1) * 64, wn = (wid & 1) * 32;
  int quad = lane >> 4, l16 = lane & 15;
  f32x4 acc[4][2];
#pragma unroll
  for (int t = 0; t < 4; ++t)
#pragma unroll
    for (int u = 0; u < 2; ++u) acc[t][u] = f32x4{0.f, 0.f, 0.f, 0.f};

  uint2 ar[4], br[2];
  auto preload = [&](int kk){
#pragma unroll
    for (int it = 0; it < 4; ++it){
      int i = tid + it * 256;
      int m = i >> 3, c = i & 7;
      int gr = bm0 + m;
      ar[it] = (gr < M) ? *(const uint2*)(A + (size_t)gr * K + kk + c * 4) : make_uint2(0u, 0u);
    }
#pragma unroll
    for (int it = 0; it < 2; ++it){
      int i = tid + it * 256;
      int n = i >> 3, c = i & 7;
      br[it] = *(const uint2*)(Bt + (size_t)(bn0 + n) * K + kk + c * 4);
    }
  };
  auto commit = [&](int buf){
#pragma unroll
    for (int it = 0; it < 4; ++it){
      int i = tid + it * 256;
      int m = i >> 3, c = i & 7;
      *(uint2*)&As[buf][m * LDA + c * 4] = ar[it];
    }
#pragma unroll
    for (int it = 0; it < 2; ++it){
      int i = tid + it * 256;
      int n = i >> 3, c = i & 7;
      *(uint2*)&Bs[buf][n * LDA + c * 4] = br[it];
    }
  };

  preload(0);
  commit(0);
  __syncthreads();
  int nk = K / BK;
  for (int kb = 0; kb < nk; ++kb){
    int cur = kb & 1;
    if (kb + 1 < nk) preload((kb + 1) * BK);
    bf16x8 af[4], bfr[2];
#pragma unroll
    for (int t = 0; t < 4; ++t)
      af[t] = *(const bf16x8*)&As[cur][(wm + t * 16 + l16) * LDA + quad * 8];
#pragma unroll
    for (int u = 0; u < 2; ++u)
      bfr[u] = *(const bf16x8*)&Bs[cur][(wn + u * 16 + l16) * LDA + quad * 8];
#pragma unroll
    for (int t = 0; t < 4; ++t)
#pragma unroll
      for (int u = 0; u < 2; ++u)
        acc[t][u] = __builtin_amdgcn_mfma_f32_16x16x32_bf16(af[t], bfr[u], acc[t][u], 0, 0, 0);
    if (kb + 1 < nk){
      commit(cur ^ 1);
      __syncthreads();
    }
  }
  float bv[2] = {0.f, 0.f};
  if constexpr (EPI){ bv[0] = bias[bn0 + wn + l16]; bv[1] = bias[bn0 + wn + 16 + l16]; }
#pragma unroll
  for (int t = 0; t < 4; ++t){
#pragma unroll
    for (int r = 0; r < 4; ++r){
      int gr = bm0 + wm + t * 16 + quad * 4 + r;
      if (gr < M){
        float rs = 1.f, rs2 = 1.f;
        if constexpr (EPI)  rs  = rowScaleC[gr];
        if constexpr (EPI2) rs2 = rowScaleC2[gr];
#pragma unroll
        for (int u = 0; u < 2; ++u){
          int gc = bn0 + wn + u * 16 + l16;
          float cv = acc[t][u][r];
          if constexpr (EPI)  cv = fmaxf(fmaf(cv, rs, bv[u]), 0.f);
          if constexpr (EPI2) cv *= rs2;
          if constexpr (C_BF16) ((unsigned short*)Cp)[(size_t)gr * N + gc] = f2bf(cv);
          else                  ((float*)Cp)[(size_t)gr * N + gc] = cv;
        }
      }
    }
  }
}

// ---------------- classifier (counts from gb) ----------------
__global__ __launch_bounds__(256) void k_classifier(const float* __restrict__ sums, const int* __restrict__ gb,
    const float* __restrict__ Wc1, const float* __restrict__ bc1,
    const float* __restrict__ Wc2, const float* __restrict__ bc2,
    const float* __restrict__ Wc3, const float* __restrict__ bc3,
    const float* __restrict__ Wc4, const float* __restrict__ bc4,
    float* __restrict__ out){
  __shared__ float w1[64 * 18], w2[18 * 12], w3[12 * 6], w4[6 * 2];
  __shared__ float B1[18], B2[12], B3[6], B4[2];
  int tid = threadIdx.x;
  for (int i = tid; i < 64 * 18; i += 256) w1[i] = Wc1[i];
  for (int i = tid; i < 18 * 12; i += 256) w2[i] = Wc2[i];
  for (int i = tid; i < 12 * 6;  i += 256) w3[i] = Wc3[i];
  for (int i = tid; i < 6 * 2;   i += 256) w4[i] = Wc4[i];
  if (tid < 18) B1[tid] = bc1[tid];
  if (tid < 12) B2[tid] = bc2[tid];
  if (tid < 6)  B3[tid] = bc3[tid];
  if (tid < 2)  B4[tid] = bc4[tid];
  __syncthreads();
  int g = blockIdx.x * 256 + tid;
  float cnt = fmaxf((float)(gb[g + 1] - gb[g]), 1.0f);
  float h[64];
#pragma unroll
  for (int f = 0; f < 64; ++f) h[f] = sums[(size_t)g * 64 + f] / cnt;
  float t1[18];
#pragma unroll
  for (int j = 0; j < 18; ++j){
    float s = B1[j];
    for (int f = 0; f < 64; ++f) s = fmaf(h[f], w1[f * 18 + j], s);
    t1[j] = s;
  }
  float t2[12];
#pragma unroll
  for (int j = 0; j < 12; ++j){
    float s = B2[j];
    for (int f = 0; f < 18; ++f) s = fmaf(t1[f], w2[f * 12 + j], s);
    t2[j] = s;
  }
  float t3[6];
#pragma unroll
  for (int j = 0; j < 6; ++j){
    float s = B3[j];
    for (int f = 0; f < 12; ++f) s = fmaf(t2[f], w3[f * 6 + j], s);
    t3[j] = s;
  }
#pragma unroll
  for (int j = 0; j < 2; ++j){
    float s = B4[j];
    for (int f = 0; f < 6; ++f) s = fmaf(t3[f], w4[f * 2 + j], s);
    out[(size_t)g * 2 + j] = s;
  }
}

extern "C" void kernel_launch(void* const* d_in, const int* in_sizes, int n_in,
                              void* d_out, int out_size, void* d_ws, size_t ws_size,
                              hipStream_t stream){
  const float* x   = (const float*)d_in[0];
  const int*   src = (const int*)d_in[1];
  const int*   dst = (const int*)d_in[2];
  const int*   gid = (const int*)d_in[3];
  const float* W1  = (const float*)d_in[4];
  const float* b1  = (const float*)d_in[5];
  const float* W2  = (const float*)d_in[6];
  const float* b2  = (const float*)d_in[7];
  const float* Wc1 = (const float*)d_in[8];
  const float* bc1 = (const float*)d_in[9];
  const float* Wc2 = (const float*)d_in[10];
  const float* bc2 = (const float*)d_in[11];
  const float* Wc3 = (const float*)d_in[12];
  const float* bc3 = (const float*)d_in[13];
  const float* Wc4 = (const float*)d_in[14];
  const float* bc4 = (const float*)d_in[15];
  float* out = (float*)d_out;

  const int n_nodes = in_sizes[3];
  const int n_edges = in_sizes[1];
  const int F1 = 256, F2 = 64;
  const int NB   = (n_nodes + 511) >> 9;
  const int NBLK = (n_edges + 4095) / 4096;

  char* w = (char*)d_ws;
  size_t o = 0;
  auto alloc = [&](size_t bytes) -> char* {
    char* p = w + o;
    o = align_up(o + bytes, 256);
    return p;
  };
  float* sums      = (float*)alloc((size_t)NGRAPHS * F2 * 4);
  int*   gb        = (int*)  alloc((size_t)(NGRAPHS + 1) * 4);
  int*   cntS      = (int*)  alloc((size_t)NBLK * 256 * 4);
  int*   cntD      = (int*)  alloc((size_t)NBLK * 256 * 4);
  int*   totS      = (int*)  alloc((size_t)256 * 4);
  int*   totD      = (int*)  alloc((size_t)256 * 4);
  int*   baseS     = (int*)  alloc((size_t)256 * 4);
  int*   baseD     = (int*)  alloc((size_t)256 * 4);
  float* dout_s    = (float*)alloc((size_t)n_nodes * 4);
  float* din_s     = (float*)alloc((size_t)n_nodes * 4);
  int*   offs      = (int*)  alloc((size_t)(n_nodes + 1) * 4);
  int*   csr_src   = (int*)  alloc((size_t)n_edges * 4);
  unsigned short* Wt1 = (unsigned short*)alloc((size_t)256 * 128 * 2);
  unsigned short* Wt2 = (unsigned short*)alloc((size_t)64 * 256 * 2);
  unsigned int*   xb  = (unsigned int*)  alloc((size_t)n_nodes * 128 * 2);
  unsigned short* aggb= (unsigned short*)alloc((size_t)n_nodes * 128 * 2);
  unsigned short* h1b = (unsigned short*)alloc((size_t)n_nodes * F1 * 2);
  // aliases inside aggb region (consumed before spmm1 writes aggb)
  int2*  pairD = (int2*)aggb;
  int*   srcS  = (int*)((char*)aggb + (size_t)n_edges * 8);
  unsigned short* t2b = aggb;

  // prep (x->bf16, weights, zero sums, graph boundaries)
  {
    long long total4 = (long long)n_nodes * 32;
    long long totalP = total4 + 128 * 256 + 256 * 64 + (long long)NGRAPHS * 64 + n_nodes;
    k_prep<<<(int)((totalP + 255) / 256), 256, 0, stream>>>(x, xb, total4, W1, Wt1, W2, Wt2,
                                                            sums, gid, gb, n_nodes);
  }

  // deterministic radix partition + fused CSR build
  k_partcount   <<<NBLK, 256, 0, stream>>>(src, dst, cntS, cntD, n_edges);
  k_colscan     <<<2 * NB, 256, 0, stream>>>(cntS, cntD, totS, totD, NBLK, NB);
  k_scatter_det <<<NBLK, 256, 0, stream>>>(src, dst, cntS, cntD, totS, totD, baseS, baseD, pairD, srcS, n_edges, NB);
  k_bucket_build<<<NB, 256, 0, stream>>>(pairD, baseD, srcS, baseS, offs, din_s, dout_s, csr_src, NB, n_nodes, n_edges);

  int gx = (n_nodes + 127) / 128;
  // layer 1
  {
    long long threads = (long long)n_nodes * 32;
    k_spmm1<<<(int)((threads + 255) / 256), 256, 0, stream>>>(xb, offs, csr_src, dout_s, (unsigned int*)aggb, n_nodes);
    gemm_mfma<true, true, true><<<dim3(gx, F1 / 64), 256, 0, stream>>>(
        aggb, Wt1, h1b, n_nodes, F1, 128, din_s, dout_s, b1);
  }
  // layer 2: t2 = h1b @ W2; fused spmm2+pool accumulates graph sums directly
  {
    gemm_mfma<true, false, false><<<dim3(gx, 1), 256, 0, stream>>>(
        h1b, Wt2, t2b, n_nodes, F2, F1, nullptr, nullptr, nullptr);
    k_spmm2_fused<<<NGRAPHS * SCHUNK, 256, 0, stream>>>(t2b, offs, csr_src, din_s, b2, gb, sums);
  }
  // classifier
  k_classifier<<<NGRAPHS / 256, 256, 0, stream>>>(sums, gb, Wc1, bc1, Wc2, bc2, Wc3, bc3, Wc4, bc4, out);
}